// Round 4
// baseline (575.238 us; speedup 1.0000x reference)
//
#include <hip/hip_runtime.h>
#include <stdint.h>

#define B_   2
#define S_   1024
#define D_   2048
#define H_   16
#define KV_  4
#define HD_  128
#define NTOK (B_ * S_)        /* 2048 tokens */
#define QD   (H_ * HD_)       /* 2048 */
#define KD   (KV_ * HD_)      /* 512  */

using i32x4  = __attribute__((ext_vector_type(4)))  int;
using i32x16 = __attribute__((ext_vector_type(16))) int;
using f32x4  = __attribute__((ext_vector_type(4)))  float;
using bf16x8 = __attribute__((ext_vector_type(8)))  short;

#define LN1E4_OVER_64 0.14391156831212725f

// ---------------- bf16 helpers ---------------------------------------------
__device__ __forceinline__ float bf2f(uint16_t u) { return __uint_as_float((uint32_t)u << 16); }
__device__ __forceinline__ uint16_t f2bf(float f) {
    uint32_t u = __float_as_uint(f);
    return (uint16_t)((u + 0x7FFFu + ((u >> 16) & 1u)) >> 16);   // RNE
}

// ---------------------------------------------------------------------------
// Per-token joint absmax int8 quantization (dim = 2048 fixed).
// ---------------------------------------------------------------------------
__global__ __launch_bounds__(256)
void act_quant_i8_kernel(const float* __restrict__ xr, const float* __restrict__ xi,
                         int8_t* __restrict__ qr, int8_t* __restrict__ qi,
                         float* __restrict__ invs)
{
    const int tok = blockIdx.x, t = threadIdx.x;
    const float* pr = xr + (size_t)tok * 2048 + t * 8;
    const float* pi = xi + (size_t)tok * 2048 + t * 8;
    float4 r0 = *(const float4*)pr, r1 = *(const float4*)(pr + 4);
    float4 i0 = *(const float4*)pi, i1 = *(const float4*)(pi + 4);
    float am = fmaxf(fmaxf(fmaxf(fabsf(r0.x), fabsf(r0.y)), fmaxf(fabsf(r0.z), fabsf(r0.w))),
                     fmaxf(fmaxf(fabsf(r1.x), fabsf(r1.y)), fmaxf(fabsf(r1.z), fabsf(r1.w))));
    am = fmaxf(am, fmaxf(fmaxf(fmaxf(fabsf(i0.x), fabsf(i0.y)), fmaxf(fabsf(i0.z), fabsf(i0.w))),
                         fmaxf(fmaxf(fabsf(i1.x), fabsf(i1.y)), fmaxf(fabsf(i1.z), fabsf(i1.w)))));
    __shared__ float red[256];
    red[t] = am;
    __syncthreads();
    for (int st = 128; st > 0; st >>= 1) {
        if (t < st) red[t] = fmaxf(red[t], red[t + st]);
        __syncthreads();
    }
    const float s = 127.0f / fmaxf(red[0], 1e-5f);
    if (t == 0) invs[tok] = 1.0f / s;
#define Q8(x) ((uint32_t)(uint8_t)(int8_t)(int)fminf(fmaxf(rintf((x) * s), -128.f), 127.f))
    uint32_t a0 = Q8(r0.x) | (Q8(r0.y) << 8) | (Q8(r0.z) << 16) | (Q8(r0.w) << 24);
    uint32_t a1 = Q8(r1.x) | (Q8(r1.y) << 8) | (Q8(r1.z) << 16) | (Q8(r1.w) << 24);
    uint32_t b0 = Q8(i0.x) | (Q8(i0.y) << 8) | (Q8(i0.z) << 16) | (Q8(i0.w) << 24);
    uint32_t b1 = Q8(i1.x) | (Q8(i1.y) << 8) | (Q8(i1.z) << 16) | (Q8(i1.w) << 24);
#undef Q8
    *(uint32_t*)(qr + (size_t)tok * 2048 + t * 8)     = a0;
    *(uint32_t*)(qr + (size_t)tok * 2048 + t * 8 + 4) = a1;
    *(uint32_t*)(qi + (size_t)tok * 2048 + t * 8)     = b0;
    *(uint32_t*)(qi + (size_t)tok * 2048 + t * 8 + 4) = b1;
}

// ---------------------------------------------------------------------------
// Weight decode + transpose + fused mag reduction.
// ---------------------------------------------------------------------------
__global__ __launch_bounds__(256)
void decode_kernel(const float* __restrict__ wr, const float* __restrict__ wi,
                   int N, int8_t* __restrict__ psr, int8_t* __restrict__ psi,
                   int8_t* __restrict__ pnsi, int n_off, float* __restrict__ mag_out)
{
    __shared__ alignas(16) int8_t tr[3][64][80];
    __shared__ float red[256];
    const int n0 = blockIdx.x * 64, k0 = blockIdx.y * 64;
    float msum = 0.f;
    for (int idx = threadIdx.x; idx < 4096; idx += 256) {
        int j = idx & 63, i = idx >> 6;                 // j = n, i = k
        size_t g = (size_t)(k0 + i) * N + n0 + j;
        float a = wr[g], b = wi[g];
        msum += sqrtf(a * a + b * b);
        int8_t sr, si;
        if (fabsf(a) >= fabsf(b)) {
            sr = (a > 0.f) ? 1 : ((a < 0.f) ? -1 : 0);
            si = 0;
        } else {
            sr = 0;
            si = (b > 0.f) ? 1 : ((b < 0.f) ? -1 : 0);
        }
        tr[0][j][i] = sr;
        tr[1][j][i] = si;
        tr[2][j][i] = (int8_t)(-si);
    }
    red[threadIdx.x] = msum;
    __syncthreads();
    for (int st = 128; st > 0; st >>= 1) {
        if (threadIdx.x < st) red[threadIdx.x] += red[threadIdx.x + st];
        __syncthreads();
    }
    if (threadIdx.x == 0) atomicAdd(mag_out, red[0]);
    int8_t* planes[3] = { psr, psi, pnsi };
    for (int idx = threadIdx.x; idx < 768; idx += 256) {
        int p = idx >> 8, rem = idx & 255, n = rem >> 2, c = rem & 3;
        int4 v = *(const int4*)&tr[p][n][c * 16];
        *(int4*)(planes[p] + (size_t)(n_off + n0 + n) * 2048 + k0 + c * 16) = v;
    }
}

// ---------------------------------------------------------------------------
// int8 MFMA complex GEMM — double-buffered LDS pipeline with raw s_barrier +
// partial vmcnt waits. Each wave owns exactly 10 global_load_lds per tile;
// vmcnt(10) == "previous tile complete, next tile in flight". Tile k+1 DMA
// overlaps tile k MFMA — the drain-free K-loop the 2-barrier shape can't do.
// ---------------------------------------------------------------------------
__device__ __forceinline__ void async_copy16(const void* g, void* l) {
    __builtin_amdgcn_global_load_lds((const __attribute__((address_space(1))) void*)g,
                                     (__attribute__((address_space(3))) void*)l, 16, 0, 0);
}

template <int MODE>
__global__ __launch_bounds__(256)
void gemm_i8_kernel(const int8_t* __restrict__ axr, const int8_t* __restrict__ axi,
                    const int8_t* __restrict__ bsr, const int8_t* __restrict__ bsi,
                    const int8_t* __restrict__ bnsi,
                    int Nout, const float* __restrict__ invs,
                    const float* __restrict__ mag_sums,
                    float magc0, float magc1, float magc2,
                    float* o_re, float* o_im,
                    uint16_t* kbr, uint16_t* kbi, uint16_t* vbr, uint16_t* vbi)
{
    __shared__ alignas(16) int8_t smem[2][5 * 8192];   // 80 KB, 2-stage
    const int tid = threadIdx.x;
    const int wav = tid >> 6, lane = tid & 63;
    const int tileM = blockIdx.y * 128, tileN = blockIdx.x * 128;
    const int wm = wav & 1, wn = wav >> 1;
    const int K = 2048;

    const int8_t* gplane[5] = { axr, axi, bsr, bsi, bnsi };
    const int     rbase[5]  = { tileM, tileM, tileN, tileN, tileN };

    i32x16 acc_re[2][2] = {};
    i32x16 acc_im[2][2] = {};

    auto issue_tile = [&](int k0, int buf) {
#pragma unroll
        for (int i = 0; i < 10; ++i) {
            int q = wav + 4 * i;            // 40 lds-dma per tile, 10 per wave
            int pl = q >> 3, seg = q & 7;
            int c = seg >> 1, m0 = (seg & 1) << 6;
            const int8_t* g = gplane[pl] + (size_t)(rbase[pl] + m0 + lane) * K + k0 + c * 16;
            int8_t* l = &smem[buf][pl * 8192 + (c * 128 + m0) * 16];
            async_copy16(g, l);
        }
    };

    issue_tile(0, 0);
    issue_tile(64, 1);

    for (int k = 0; k < 32; ++k) {
        if (k == 31) { asm volatile("s_waitcnt vmcnt(0)" ::: "memory"); }
        else         { asm volatile("s_waitcnt vmcnt(10)" ::: "memory"); }
        asm volatile("s_barrier" ::: "memory");
        const int8_t* sb = smem[k & 1];
#pragma unroll
        for (int s = 0; s < 2; ++s) {
            const int cc = 2 * s + (lane >> 5);
            const int rA = wm * 64 + (lane & 31);
            const int rB = wn * 64 + (lane & 31);
            i32x4 fxr[2], fxi[2], fsr[2], fsi[2], fns[2];
#pragma unroll
            for (int mb = 0; mb < 2; ++mb) {
                int off = (cc * 128 + rA + mb * 32) * 16;
                fxr[mb] = *(const i32x4*)&sb[0 * 8192 + off];
                fxi[mb] = *(const i32x4*)&sb[1 * 8192 + off];
            }
#pragma unroll
            for (int nb = 0; nb < 2; ++nb) {
                int off = (cc * 128 + rB + nb * 32) * 16;
                fsr[nb] = *(const i32x4*)&sb[2 * 8192 + off];
                fsi[nb] = *(const i32x4*)&sb[3 * 8192 + off];
                fns[nb] = *(const i32x4*)&sb[4 * 8192 + off];
            }
#pragma unroll
            for (int mb = 0; mb < 2; ++mb)
#pragma unroll
                for (int nb = 0; nb < 2; ++nb) {
                    acc_re[mb][nb] = __builtin_amdgcn_mfma_i32_32x32x32_i8(fxr[mb], fsr[nb], acc_re[mb][nb], 0, 0, 0);
                    acc_re[mb][nb] = __builtin_amdgcn_mfma_i32_32x32x32_i8(fxi[mb], fns[nb], acc_re[mb][nb], 0, 0, 0);
                    acc_im[mb][nb] = __builtin_amdgcn_mfma_i32_32x32x32_i8(fxr[mb], fsi[nb], acc_im[mb][nb], 0, 0, 0);
                    acc_im[mb][nb] = __builtin_amdgcn_mfma_i32_32x32x32_i8(fxi[mb], fsr[nb], acc_im[mb][nb], 0, 0, 0);
                }
        }
        asm volatile("s_barrier" ::: "memory");       // all reads of buf done
        if (k + 2 < 32) issue_tile((k + 2) * 64, k & 1);
    }

    const int ln31 = lane & 31, lq = lane >> 5;
#pragma unroll
    for (int mb = 0; mb < 2; ++mb) {
#pragma unroll
        for (int nb = 0; nb < 2; ++nb) {
            const int gn = tileN + wn * 64 + nb * 32 + ln31;
            float mag;
            if (MODE == 0)
                mag = (gn < 2048) ? mag_sums[0] * magc0
                    : (gn < 2560) ? mag_sums[1] * magc1
                                  : mag_sums[2] * magc2;
            else
                mag = mag_sums[0] * magc0;
#pragma unroll
            for (int r = 0; r < 16; ++r) {
                const int row = (r & 3) + 8 * (r >> 2) + 4 * lq;
                const int gm = tileM + wm * 64 + mb * 32 + row;
                const float sc = mag * invs[gm];
                const float re = (float)acc_re[mb][nb][r] * sc;
                const float im = (float)acc_im[mb][nb][r] * sc;
                if (MODE == 1) {
                    o_re[(size_t)gm * Nout + gn] = re;
                    o_im[(size_t)gm * Nout + gn] = im;
                } else {
                    const int s = gm & (S_ - 1), bb = gm >> 10;
                    if (gn < 2048) {
                        o_re[(size_t)gm * 2048 + gn] = re;
                        o_im[(size_t)gm * 2048 + gn] = im;
                    } else if (gn < 2560) {
                        int c = gn - 2048, kvh = c >> 7, d = c & 127;
                        size_t off = ((size_t)(bb * KV_ + kvh) * S_ + s) * 128 + d;
                        kbr[off] = f2bf(re);
                        kbi[off] = f2bf(im);
                    } else {
                        int c = gn - 2560, kvh = c >> 7, d = c & 127;
                        size_t off = ((size_t)(bb * KV_ + kvh) * S_ + s) * 128 + d;
                        vbr[off] = f2bf(re);
                        vbi[off] = f2bf(im);
                    }
                }
            }
        }
    }
}

// ---------------------------------------------------------------------------
// RoPE + bf16 convert + head-major rearrange for Q.
// ---------------------------------------------------------------------------
__global__ __launch_bounds__(256)
void rope_q_kernel(const float* __restrict__ q_re, const float* __restrict__ q_im,
                   uint16_t* __restrict__ qb_re, uint16_t* __restrict__ qb_im)
{
    int gidx = blockIdx.x * 256 + threadIdx.x;      // tok*256 + h*16 + j
    int j = gidx & 15, h = (gidx >> 4) & 15, tok = gidx >> 8;
    int s = tok & (S_ - 1), b = tok >> 10;
    int d0 = j * 4;
    size_t ib = (size_t)tok * 2048 + h * 128;
    float4 r0 = *(const float4*)&q_re[ib + d0];
    float4 r1 = *(const float4*)&q_re[ib + d0 + 64];
    float4 i0 = *(const float4*)&q_im[ib + d0];
    float4 i1 = *(const float4*)&q_im[ib + d0 + 64];
    float ro0[4], ro1[4];
    float rv0[4] = { r0.x, r0.y, r0.z, r0.w };
    float rv1[4] = { r1.x, r1.y, r1.z, r1.w };
#pragma unroll
    for (int t = 0; t < 4; ++t) {
        float f = __expf(-(float)(d0 + t) * LN1E4_OVER_64);
        float sn, c;
        __sincosf((float)s * f, &sn, &c);
        ro0[t] = rv0[t] * c - rv1[t] * sn;
        ro1[t] = rv1[t] * c + rv0[t] * sn;
    }
    size_t ob = ((size_t)(b * H_ + h) * S_ + s) * 128;
    ushort4 w;
    w = (ushort4){ f2bf(ro0[0]), f2bf(ro0[1]), f2bf(ro0[2]), f2bf(ro0[3]) };
    *(ushort4*)&qb_re[ob + d0] = w;
    w = (ushort4){ f2bf(ro1[0]), f2bf(ro1[1]), f2bf(ro1[2]), f2bf(ro1[3]) };
    *(ushort4*)&qb_re[ob + d0 + 64] = w;
    w = (ushort4){ f2bf(i0.x), f2bf(i0.y), f2bf(i0.z), f2bf(i0.w) };
    *(ushort4*)&qb_im[ob + d0] = w;
    w = (ushort4){ f2bf(i1.x), f2bf(i1.y), f2bf(i1.z), f2bf(i1.w) };
    *(ushort4*)&qb_im[ob + d0 + 64] = w;
}

// RoPE in place on K real bf16 plane [b][kv][s][128].
__global__ __launch_bounds__(256)
void rope_k_kernel(uint16_t* __restrict__ kb_re)
{
    int gidx = blockIdx.x * 256 + threadIdx.x;
    int j = gidx & 15, kvh = (gidx >> 4) & 3;
    int rest = gidx >> 6;
    int s = rest & (S_ - 1), b = rest >> 10;
    int d0 = j * 4;
    size_t base = ((size_t)(b * KV_ + kvh) * S_ + s) * 128;
    ushort4 u0 = *(const ushort4*)&kb_re[base + d0];
    ushort4 u1 = *(const ushort4*)&kb_re[base + d0 + 64];
    float rv0[4] = { bf2f(u0.x), bf2f(u0.y), bf2f(u0.z), bf2f(u0.w) };
    float rv1[4] = { bf2f(u1.x), bf2f(u1.y), bf2f(u1.z), bf2f(u1.w) };
    float ro0[4], ro1[4];
#pragma unroll
    for (int t = 0; t < 4; ++t) {
        float f = __expf(-(float)(d0 + t) * LN1E4_OVER_64);
        float sn, c;
        __sincosf((float)s * f, &sn, &c);
        ro0[t] = rv0[t] * c - rv1[t] * sn;
        ro1[t] = rv1[t] * c + rv0[t] * sn;
    }
    *(ushort4*)&kb_re[base + d0]      = (ushort4){ f2bf(ro0[0]), f2bf(ro0[1]), f2bf(ro0[2]), f2bf(ro0[3]) };
    *(ushort4*)&kb_re[base + d0 + 64] = (ushort4){ f2bf(ro1[0]), f2bf(ro1[1]), f2bf(ro1[2]), f2bf(ro1[3]) };
}

// ---------------------------------------------------------------------------
// V transpose: vb [bk][s][128] bf16 -> vt [bk][d][1024] bf16.
// ---------------------------------------------------------------------------
__global__ __launch_bounds__(256)
void vtrans_kernel(const uint16_t* __restrict__ vbr, const uint16_t* __restrict__ vbi,
                   uint16_t* __restrict__ vtr, uint16_t* __restrict__ vti)
{
    __shared__ uint16_t t[32][36];
    const int pl = blockIdx.z & 1, bk = blockIdx.z >> 1;
    const int s0 = blockIdx.x * 32, d0 = blockIdx.y * 32;
    const uint16_t* src = (pl ? vbi : vbr) + ((size_t)bk * S_) * 128;
    uint16_t*       dst = (pl ? vti : vtr) + ((size_t)bk * 128) * S_;
    const int r = threadIdx.x >> 3, c = (threadIdx.x & 7) * 4;
    *(ushort4*)&t[r][c] = *(const ushort4*)&src[(size_t)(s0 + r) * 128 + d0 + c];
    __syncthreads();
    ushort4 o = (ushort4){ t[c][r], t[c + 1][r], t[c + 2][r], t[c + 3][r] };
    *(ushort4*)&dst[(size_t)(d0 + r) * S_ + s0 + c] = o;
}

// ---------------------------------------------------------------------------
// MFMA flash attention (bf16, fp32 accum, online softmax in registers).
// v5: round-0 structure, but V is NOT staged in LDS. m165/m169 precedent:
// at S=1024 the V tile (16 KB/iter) is L1/L2-resident and all 4 waves read
// identical fragments — LDS staging + the sv[.][.][40] bank-conflicted reads
// (row stride 80 B, gcd(20,32)=4 => 8-way) were pure overhead. PV now reads
// V fragments directly from global vt; V loads also decouple from the
// staging barrier. LDS drops 43 KB -> 22.5 KB (residency ceiling 3 -> 7).
// ---------------------------------------------------------------------------
__global__ __launch_bounds__(256)
void attn_mfma_kernel(const uint16_t* __restrict__ qb_re, const uint16_t* __restrict__ qb_im,
                      const uint16_t* __restrict__ kb_re, const uint16_t* __restrict__ kb_im,
                      const uint16_t* __restrict__ vt_re, const uint16_t* __restrict__ vt_im,
                      float* __restrict__ o_re, float* __restrict__ o_im)
{
    __shared__ alignas(16) uint16_t sk[2][32][136];
    __shared__ alignas(16) uint16_t sp[4][16][40];

    const int tid = threadIdx.x;
    const int w = tid >> 6, lane = tid & 63;
    const int r16 = lane & 15, q4 = lane >> 4;
    const int qt = gridDim.x - 1 - blockIdx.x;        // heavy blocks dispatch first
    const int h = blockIdx.y, b = blockIdx.z;
    const int kvh = h >> 2;
    const int q0 = qt * 64, qw0 = q0 + w * 16;

    bf16x8 qfr[4], qfi[4];
    {
        const size_t qbase = ((size_t)(b * H_ + h) * S_ + qw0 + r16) * 128;
#pragma unroll
        for (int ks = 0; ks < 4; ++ks) {
            const int col = ks * 32 + q4 * 8;
            qfr[ks] = *(const bf16x8*)&qb_re[qbase + col];
            qfi[ks] = *(const bf16x8*)&qb_im[qbase + col];
        }
    }

    f32x4 oa[2][8] = {};
    float m_r[4] = { -3e38f, -3e38f, -3e38f, -3e38f };
    float l_r[4] = { 0.f, 0.f, 0.f, 0.f };

    const size_t kgbase0 = (size_t)(b * KV_ + kvh) * S_ * 128;
    const uint16_t* vre = vt_re + (size_t)(b * KV_ + kvh) * 128 * (size_t)S_;
    const uint16_t* vim = vt_im + (size_t)(b * KV_ + kvh) * 128 * (size_t)S_;

    for (int c0 = 0; c0 < q0 + 64; c0 += 32) {
        // Stage K tile (both planes) into padded LDS; V is read direct.
        for (int idx = tid; idx < 1024; idx += 256) {
            int pl = idx >> 9, c = idx & 511, r = c >> 4, ch = c & 15;
            const uint16_t* src = (pl ? kb_im : kb_re) + kgbase0 + (size_t)(c0 + r) * 128 + ch * 8;
            *(uint4*)&sk[pl][r][ch * 8] = *(const uint4*)src;
        }
        __syncthreads();

        if (c0 <= qw0 + 15) {
            f32x4 sc[2] = {};
#pragma unroll
            for (int cblk = 0; cblk < 2; ++cblk) {
                const int krow = cblk * 16 + r16;
#pragma unroll
                for (int ks = 0; ks < 4; ++ks) {
                    const int kcol = ks * 32 + q4 * 8;
                    bf16x8 kr = *(const bf16x8*)&sk[0][krow][kcol];
                    bf16x8 ki = *(const bf16x8*)&sk[1][krow][kcol];
                    sc[cblk] = __builtin_amdgcn_mfma_f32_16x16x32_bf16(qfr[ks], kr, sc[cblk], 0, 0, 0);
                    sc[cblk] = __builtin_amdgcn_mfma_f32_16x16x32_bf16(qfi[ks], ki, sc[cblk], 0, 0, 0);
                }
            }
#pragma unroll
            for (int cblk = 0; cblk < 2; ++cblk)
#pragma unroll
                for (int reg = 0; reg < 4; ++reg) {
                    float sval = sc[cblk][reg] * 0.08838834764831845f;
                    const int rowg = qw0 + q4 * 4 + reg;
                    const int colg = c0 + cblk * 16 + r16;
                    if (colg > rowg) sval = -3e38f;
                    sc[cblk][reg] = sval;
                }
            float al[4];
#pragma unroll
            for (int reg = 0; reg < 4; ++reg) {
                float mx = fmaxf(sc[0][reg], sc[1][reg]);
#pragma unroll
                for (int msk = 1; msk < 16; msk <<= 1) mx = fmaxf(mx, __shfl_xor(mx, msk));
                const float mn = fmaxf(m_r[reg], mx);
                al[reg] = __expf(m_r[reg] - mn);
                const float p0 = __expf(sc[0][reg] - mn);
                const float p1 = __expf(sc[1][reg] - mn);
                sc[0][reg] = p0; sc[1][reg] = p1;
                float rs = p0 + p1;
#pragma unroll
                for (int msk = 1; msk < 16; msk <<= 1) rs += __shfl_xor(rs, msk);
                l_r[reg] = l_r[reg] * al[reg] + rs;
                m_r[reg] = mn;
            }
#pragma unroll
            for (int cblk = 0; cblk < 2; ++cblk)
#pragma unroll
                for (int reg = 0; reg < 4; ++reg)
                    sp[w][q4 * 4 + reg][cblk * 16 + r16] = f2bf(sc[cblk][reg]);
#pragma unroll
            for (int dblk = 0; dblk < 8; ++dblk)
#pragma unroll
                for (int reg = 0; reg < 4; ++reg) {
                    oa[0][dblk][reg] *= al[reg];
                    oa[1][dblk][reg] *= al[reg];
                }
            bf16x8 pf = *(const bf16x8*)&sp[w][r16][q4 * 8];
#pragma unroll
            for (int dblk = 0; dblk < 8; ++dblk) {
                const int vrow = dblk * 16 + r16;
                const size_t voff = (size_t)vrow * S_ + c0 + q4 * 8;
                bf16x8 vr = *(const bf16x8*)&vre[voff];
                bf16x8 vi = *(const bf16x8*)&vim[voff];
                oa[0][dblk] = __builtin_amdgcn_mfma_f32_16x16x32_bf16(pf, vr, oa[0][dblk], 0, 0, 0);
                oa[1][dblk] = __builtin_amdgcn_mfma_f32_16x16x32_bf16(pf, vi, oa[1][dblk], 0, 0, 0);
            }
        }
        __syncthreads();
    }

    float inv[4];
#pragma unroll
    for (int reg = 0; reg < 4; ++reg) inv[reg] = 1.f / l_r[reg];
#pragma unroll
    for (int dblk = 0; dblk < 8; ++dblk) {
        const int col = h * 128 + dblk * 16 + r16;
#pragma unroll
        for (int reg = 0; reg < 4; ++reg) {
            const size_t tok = (size_t)b * S_ + qw0 + q4 * 4 + reg;
            o_re[tok * 2048 + col] = oa[0][dblk][reg] * inv[reg];
            o_im[tok * 2048 + col] = oa[1][dblk][reg] * inv[reg];
        }
    }
}

// ---------------------------------------------------------------------------
extern "C" void kernel_launch(void* const* d_in, const int* in_sizes, int n_in,
                              void* d_out, int out_size, void* d_ws, size_t ws_size,
                              hipStream_t stream)
{
    const float* hr    = (const float*)d_in[0];
    const float* hi    = (const float*)d_in[1];
    const float* wq_re = (const float*)d_in[2];
    const float* wq_im = (const float*)d_in[3];
    const float* wk_re = (const float*)d_in[4];
    const float* wk_im = (const float*)d_in[5];
    const float* wv_re = (const float*)d_in[6];
    const float* wv_im = (const float*)d_in[7];
    const float* wo_re = (const float*)d_in[8];
    const float* wo_im = (const float*)d_in[9];
    float* out = (float*)d_out;
    char*  base = (char*)d_ws;

    const size_t MB4  = (size_t)2048 * 2048;
    const size_t QKVP = (size_t)3072 * 2048;
    const size_t KVE  = (size_t)B_ * KV_ * S_ * 128;

    float*   mags   = (float*)(base);
    float*   invs1  = (float*)(base + 1024);
    float*   invs2  = (float*)(base + 9216);
    int8_t*  xr_q   = (int8_t*)(base + 32768);
    int8_t*  xi_q   = xr_q + MB4;
    int8_t*  qkv_sr = xi_q + MB4;
    int8_t*  qkv_si = qkv_sr + QKVP;
    int8_t*  qkv_ns = qkv_si + QKVP;
    int8_t*  wo_sr  = qkv_ns + QKVP;
    int8_t*  wo_si  = wo_sr + MB4;
    int8_t*  wo_ns  = wo_si + MB4;
    float*   q_re   = (float*)(wo_ns + MB4);
    float*   q_im   = q_re + MB4;
    uint16_t* kb_re = (uint16_t*)(q_im + MB4);
    uint16_t* kb_im = kb_re + KVE;
    uint16_t* vb_re = kb_im + KVE;
    uint16_t* vb_im = vb_re + KVE;
    uint16_t* vt_re = (uint16_t*)xr_q;
    uint16_t* vt_im = (uint16_t*)xi_q;
    uint16_t* qb_re = (uint16_t*)qkv_sr;
    uint16_t* qb_im = (uint16_t*)(qkv_sr + 8388608);

    hipMemsetAsync(mags, 0, 16, stream);

    decode_kernel<<<dim3(32, 32), 256, 0, stream>>>(wq_re, wq_im, 2048, qkv_sr, qkv_si, qkv_ns, 0,    mags + 0);
    decode_kernel<<<dim3(8, 32),  256, 0, stream>>>(wk_re, wk_im, 512,  qkv_sr, qkv_si, qkv_ns, 2048, mags + 1);
    decode_kernel<<<dim3(8, 32),  256, 0, stream>>>(wv_re, wv_im, 512,  qkv_sr, qkv_si, qkv_ns, 2560, mags + 2);
    decode_kernel<<<dim3(32, 32), 256, 0, stream>>>(wo_re, wo_im, 2048, wo_sr, wo_si, wo_ns, 0,       mags + 3);

    act_quant_i8_kernel<<<NTOK, 256, 0, stream>>>(hr, hi, xr_q, xi_q, invs1);

    gemm_i8_kernel<0><<<dim3(24, 16), 256, 0, stream>>>(
        xr_q, xi_q, qkv_sr, qkv_si, qkv_ns, 0, invs1, mags,
        1.0f / (float)((size_t)D_ * QD), 1.0f / (float)((size_t)D_ * KD), 1.0f / (float)((size_t)D_ * KD),
        q_re, q_im, kb_re, kb_im, vb_re, vb_im);

    rope_q_kernel<<<NTOK * H_ * 16 / 256, 256, 0, stream>>>(q_re, q_im, qb_re, qb_im);
    rope_k_kernel<<<NTOK * KV_ * 16 / 256, 256, 0, stream>>>(kb_re);
    vtrans_kernel<<<dim3(S_ / 32, 128 / 32, B_ * KV_ * 2), 256, 0, stream>>>(vb_re, vb_im, vt_re, vt_im);

    attn_mfma_kernel<<<dim3(S_ / 64, H_, B_), 256, 0, stream>>>(
        qb_re, qb_im, kb_re, kb_im, vt_re, vt_im, q_re, q_im);

    act_quant_i8_kernel<<<NTOK, 256, 0, stream>>>(q_re, q_im, xr_q, xi_q, invs2);

    gemm_i8_kernel<1><<<dim3(16, 16), 256, 0, stream>>>(
        xr_q, xi_q, wo_sr, wo_si, wo_ns, 2048, invs2, mags + 3,
        1.0f / (float)((size_t)QD * D_), 0.f, 0.f,
        out, out + MB4, nullptr, nullptr, nullptr, nullptr);
}

// Round 5
// 495.050 us; speedup vs baseline: 1.1620x; 1.1620x over previous
//
#include <hip/hip_runtime.h>
#include <stdint.h>

#define B_   2
#define S_   1024
#define D_   2048
#define H_   16
#define KV_  4
#define HD_  128
#define NTOK (B_ * S_)        /* 2048 tokens */
#define QD   (H_ * HD_)       /* 2048 */
#define KD   (KV_ * HD_)      /* 512  */

using i32x4  = __attribute__((ext_vector_type(4)))  int;
using i32x16 = __attribute__((ext_vector_type(16))) int;
using f32x4  = __attribute__((ext_vector_type(4)))  float;
using bf16x8 = __attribute__((ext_vector_type(8)))  short;

#define LN1E4_OVER_64 0.14391156831212725f

// ---------------- bf16 helpers ---------------------------------------------
__device__ __forceinline__ float bf2f(uint16_t u) { return __uint_as_float((uint32_t)u << 16); }
__device__ __forceinline__ uint16_t f2bf(float f) {
    uint32_t u = __float_as_uint(f);
    return (uint16_t)((u + 0x7FFFu + ((u >> 16) & 1u)) >> 16);   // RNE
}

// ---------------------------------------------------------------------------
// Per-token joint absmax int8 quantization (dim = 2048 fixed).
// ---------------------------------------------------------------------------
__global__ __launch_bounds__(256)
void act_quant_i8_kernel(const float* __restrict__ xr, const float* __restrict__ xi,
                         int8_t* __restrict__ qr, int8_t* __restrict__ qi,
                         float* __restrict__ invs)
{
    const int tok = blockIdx.x, t = threadIdx.x;
    const float* pr = xr + (size_t)tok * 2048 + t * 8;
    const float* pi = xi + (size_t)tok * 2048 + t * 8;
    float4 r0 = *(const float4*)pr, r1 = *(const float4*)(pr + 4);
    float4 i0 = *(const float4*)pi, i1 = *(const float4*)(pi + 4);
    float am = fmaxf(fmaxf(fmaxf(fabsf(r0.x), fabsf(r0.y)), fmaxf(fabsf(r0.z), fabsf(r0.w))),
                     fmaxf(fmaxf(fabsf(r1.x), fabsf(r1.y)), fmaxf(fabsf(r1.z), fabsf(r1.w))));
    am = fmaxf(am, fmaxf(fmaxf(fmaxf(fabsf(i0.x), fabsf(i0.y)), fmaxf(fabsf(i0.z), fabsf(i0.w))),
                         fmaxf(fmaxf(fabsf(i1.x), fabsf(i1.y)), fmaxf(fabsf(i1.z), fabsf(i1.w)))));
    __shared__ float red[256];
    red[t] = am;
    __syncthreads();
    for (int st = 128; st > 0; st >>= 1) {
        if (t < st) red[t] = fmaxf(red[t], red[t + st]);
        __syncthreads();
    }
    const float s = 127.0f / fmaxf(red[0], 1e-5f);
    if (t == 0) invs[tok] = 1.0f / s;
#define Q8(x) ((uint32_t)(uint8_t)(int8_t)(int)fminf(fmaxf(rintf((x) * s), -128.f), 127.f))
    uint32_t a0 = Q8(r0.x) | (Q8(r0.y) << 8) | (Q8(r0.z) << 16) | (Q8(r0.w) << 24);
    uint32_t a1 = Q8(r1.x) | (Q8(r1.y) << 8) | (Q8(r1.z) << 16) | (Q8(r1.w) << 24);
    uint32_t b0 = Q8(i0.x) | (Q8(i0.y) << 8) | (Q8(i0.z) << 16) | (Q8(i0.w) << 24);
    uint32_t b1 = Q8(i1.x) | (Q8(i1.y) << 8) | (Q8(i1.z) << 16) | (Q8(i1.w) << 24);
#undef Q8
    *(uint32_t*)(qr + (size_t)tok * 2048 + t * 8)     = a0;
    *(uint32_t*)(qr + (size_t)tok * 2048 + t * 8 + 4) = a1;
    *(uint32_t*)(qi + (size_t)tok * 2048 + t * 8)     = b0;
    *(uint32_t*)(qi + (size_t)tok * 2048 + t * 8 + 4) = b1;
}

// ---------------------------------------------------------------------------
// Weight decode + transpose + fused mag reduction.
// ---------------------------------------------------------------------------
__global__ __launch_bounds__(256)
void decode_kernel(const float* __restrict__ wr, const float* __restrict__ wi,
                   int N, int8_t* __restrict__ psr, int8_t* __restrict__ psi,
                   int8_t* __restrict__ pnsi, int n_off, float* __restrict__ mag_out)
{
    __shared__ alignas(16) int8_t tr[3][64][80];
    __shared__ float red[256];
    const int n0 = blockIdx.x * 64, k0 = blockIdx.y * 64;
    float msum = 0.f;
    for (int idx = threadIdx.x; idx < 4096; idx += 256) {
        int j = idx & 63, i = idx >> 6;                 // j = n, i = k
        size_t g = (size_t)(k0 + i) * N + n0 + j;
        float a = wr[g], b = wi[g];
        msum += sqrtf(a * a + b * b);
        int8_t sr, si;
        if (fabsf(a) >= fabsf(b)) {
            sr = (a > 0.f) ? 1 : ((a < 0.f) ? -1 : 0);
            si = 0;
        } else {
            sr = 0;
            si = (b > 0.f) ? 1 : ((b < 0.f) ? -1 : 0);
        }
        tr[0][j][i] = sr;
        tr[1][j][i] = si;
        tr[2][j][i] = (int8_t)(-si);
    }
    red[threadIdx.x] = msum;
    __syncthreads();
    for (int st = 128; st > 0; st >>= 1) {
        if (threadIdx.x < st) red[threadIdx.x] += red[threadIdx.x + st];
        __syncthreads();
    }
    if (threadIdx.x == 0) atomicAdd(mag_out, red[0]);
    int8_t* planes[3] = { psr, psi, pnsi };
    for (int idx = threadIdx.x; idx < 768; idx += 256) {
        int p = idx >> 8, rem = idx & 255, n = rem >> 2, c = rem & 3;
        int4 v = *(const int4*)&tr[p][n][c * 16];
        *(int4*)(planes[p] + (size_t)(n_off + n0 + n) * 2048 + k0 + c * 16) = v;
    }
}

// ---------------------------------------------------------------------------
// int8 MFMA complex GEMM — double-buffered LDS pipeline with raw s_barrier +
// partial vmcnt waits. Each wave owns exactly 10 global_load_lds per tile;
// vmcnt(10) == "previous tile complete, next tile in flight". Tile k+1 DMA
// overlaps tile k MFMA — the drain-free K-loop the 2-barrier shape can't do.
// ---------------------------------------------------------------------------
__device__ __forceinline__ void async_copy16(const void* g, void* l) {
    __builtin_amdgcn_global_load_lds((const __attribute__((address_space(1))) void*)g,
                                     (__attribute__((address_space(3))) void*)l, 16, 0, 0);
}

template <int MODE>
__global__ __launch_bounds__(256)
void gemm_i8_kernel(const int8_t* __restrict__ axr, const int8_t* __restrict__ axi,
                    const int8_t* __restrict__ bsr, const int8_t* __restrict__ bsi,
                    const int8_t* __restrict__ bnsi,
                    int Nout, const float* __restrict__ invs,
                    const float* __restrict__ mag_sums,
                    float magc0, float magc1, float magc2,
                    float* o_re, float* o_im,
                    uint16_t* kbr, uint16_t* kbi, uint16_t* vbr, uint16_t* vbi)
{
    __shared__ alignas(16) int8_t smem[2][5 * 8192];   // 80 KB, 2-stage
    const int tid = threadIdx.x;
    const int wav = tid >> 6, lane = tid & 63;
    const int tileM = blockIdx.y * 128, tileN = blockIdx.x * 128;
    const int wm = wav & 1, wn = wav >> 1;
    const int K = 2048;

    const int8_t* gplane[5] = { axr, axi, bsr, bsi, bnsi };
    const int     rbase[5]  = { tileM, tileM, tileN, tileN, tileN };

    i32x16 acc_re[2][2] = {};
    i32x16 acc_im[2][2] = {};

    auto issue_tile = [&](int k0, int buf) {
#pragma unroll
        for (int i = 0; i < 10; ++i) {
            int q = wav + 4 * i;            // 40 lds-dma per tile, 10 per wave
            int pl = q >> 3, seg = q & 7;
            int c = seg >> 1, m0 = (seg & 1) << 6;
            const int8_t* g = gplane[pl] + (size_t)(rbase[pl] + m0 + lane) * K + k0 + c * 16;
            int8_t* l = &smem[buf][pl * 8192 + (c * 128 + m0) * 16];
            async_copy16(g, l);
        }
    };

    issue_tile(0, 0);
    issue_tile(64, 1);

    for (int k = 0; k < 32; ++k) {
        if (k == 31) { asm volatile("s_waitcnt vmcnt(0)" ::: "memory"); }
        else         { asm volatile("s_waitcnt vmcnt(10)" ::: "memory"); }
        asm volatile("s_barrier" ::: "memory");
        const int8_t* sb = smem[k & 1];
#pragma unroll
        for (int s = 0; s < 2; ++s) {
            const int cc = 2 * s + (lane >> 5);
            const int rA = wm * 64 + (lane & 31);
            const int rB = wn * 64 + (lane & 31);
            i32x4 fxr[2], fxi[2], fsr[2], fsi[2], fns[2];
#pragma unroll
            for (int mb = 0; mb < 2; ++mb) {
                int off = (cc * 128 + rA + mb * 32) * 16;
                fxr[mb] = *(const i32x4*)&sb[0 * 8192 + off];
                fxi[mb] = *(const i32x4*)&sb[1 * 8192 + off];
            }
#pragma unroll
            for (int nb = 0; nb < 2; ++nb) {
                int off = (cc * 128 + rB + nb * 32) * 16;
                fsr[nb] = *(const i32x4*)&sb[2 * 8192 + off];
                fsi[nb] = *(const i32x4*)&sb[3 * 8192 + off];
                fns[nb] = *(const i32x4*)&sb[4 * 8192 + off];
            }
#pragma unroll
            for (int mb = 0; mb < 2; ++mb)
#pragma unroll
                for (int nb = 0; nb < 2; ++nb) {
                    acc_re[mb][nb] = __builtin_amdgcn_mfma_i32_32x32x32_i8(fxr[mb], fsr[nb], acc_re[mb][nb], 0, 0, 0);
                    acc_re[mb][nb] = __builtin_amdgcn_mfma_i32_32x32x32_i8(fxi[mb], fns[nb], acc_re[mb][nb], 0, 0, 0);
                    acc_im[mb][nb] = __builtin_amdgcn_mfma_i32_32x32x32_i8(fxr[mb], fsi[nb], acc_im[mb][nb], 0, 0, 0);
                    acc_im[mb][nb] = __builtin_amdgcn_mfma_i32_32x32x32_i8(fxi[mb], fsr[nb], acc_im[mb][nb], 0, 0, 0);
                }
        }
        asm volatile("s_barrier" ::: "memory");       // all reads of buf done
        if (k + 2 < 32) issue_tile((k + 2) * 64, k & 1);
    }

    const int ln31 = lane & 31, lq = lane >> 5;
#pragma unroll
    for (int mb = 0; mb < 2; ++mb) {
#pragma unroll
        for (int nb = 0; nb < 2; ++nb) {
            const int gn = tileN + wn * 64 + nb * 32 + ln31;
            float mag;
            if (MODE == 0)
                mag = (gn < 2048) ? mag_sums[0] * magc0
                    : (gn < 2560) ? mag_sums[1] * magc1
                                  : mag_sums[2] * magc2;
            else
                mag = mag_sums[0] * magc0;
#pragma unroll
            for (int r = 0; r < 16; ++r) {
                const int row = (r & 3) + 8 * (r >> 2) + 4 * lq;
                const int gm = tileM + wm * 64 + mb * 32 + row;
                const float sc = mag * invs[gm];
                const float re = (float)acc_re[mb][nb][r] * sc;
                const float im = (float)acc_im[mb][nb][r] * sc;
                if (MODE == 1) {
                    o_re[(size_t)gm * Nout + gn] = re;
                    o_im[(size_t)gm * Nout + gn] = im;
                } else {
                    const int s = gm & (S_ - 1), bb = gm >> 10;
                    if (gn < 2048) {
                        o_re[(size_t)gm * 2048 + gn] = re;
                        o_im[(size_t)gm * 2048 + gn] = im;
                    } else if (gn < 2560) {
                        int c = gn - 2048, kvh = c >> 7, d = c & 127;
                        size_t off = ((size_t)(bb * KV_ + kvh) * S_ + s) * 128 + d;
                        kbr[off] = f2bf(re);
                        kbi[off] = f2bf(im);
                    } else {
                        int c = gn - 2560, kvh = c >> 7, d = c & 127;
                        size_t off = ((size_t)(bb * KV_ + kvh) * S_ + s) * 128 + d;
                        vbr[off] = f2bf(re);
                        vbi[off] = f2bf(im);
                    }
                }
            }
        }
    }
}

// ---------------------------------------------------------------------------
// RoPE + bf16 convert + head-major rearrange for Q.
// ---------------------------------------------------------------------------
__global__ __launch_bounds__(256)
void rope_q_kernel(const float* __restrict__ q_re, const float* __restrict__ q_im,
                   uint16_t* __restrict__ qb_re, uint16_t* __restrict__ qb_im)
{
    int gidx = blockIdx.x * 256 + threadIdx.x;      // tok*256 + h*16 + j
    int j = gidx & 15, h = (gidx >> 4) & 15, tok = gidx >> 8;
    int s = tok & (S_ - 1), b = tok >> 10;
    int d0 = j * 4;
    size_t ib = (size_t)tok * 2048 + h * 128;
    float4 r0 = *(const float4*)&q_re[ib + d0];
    float4 r1 = *(const float4*)&q_re[ib + d0 + 64];
    float4 i0 = *(const float4*)&q_im[ib + d0];
    float4 i1 = *(const float4*)&q_im[ib + d0 + 64];
    float ro0[4], ro1[4];
    float rv0[4] = { r0.x, r0.y, r0.z, r0.w };
    float rv1[4] = { r1.x, r1.y, r1.z, r1.w };
#pragma unroll
    for (int t = 0; t < 4; ++t) {
        float f = __expf(-(float)(d0 + t) * LN1E4_OVER_64);
        float sn, c;
        __sincosf((float)s * f, &sn, &c);
        ro0[t] = rv0[t] * c - rv1[t] * sn;
        ro1[t] = rv1[t] * c + rv0[t] * sn;
    }
    size_t ob = ((size_t)(b * H_ + h) * S_ + s) * 128;
    ushort4 w;
    w = (ushort4){ f2bf(ro0[0]), f2bf(ro0[1]), f2bf(ro0[2]), f2bf(ro0[3]) };
    *(ushort4*)&qb_re[ob + d0] = w;
    w = (ushort4){ f2bf(ro1[0]), f2bf(ro1[1]), f2bf(ro1[2]), f2bf(ro1[3]) };
    *(ushort4*)&qb_re[ob + d0 + 64] = w;
    w = (ushort4){ f2bf(i0.x), f2bf(i0.y), f2bf(i0.z), f2bf(i0.w) };
    *(ushort4*)&qb_im[ob + d0] = w;
    w = (ushort4){ f2bf(i1.x), f2bf(i1.y), f2bf(i1.z), f2bf(i1.w) };
    *(ushort4*)&qb_im[ob + d0 + 64] = w;
}

// RoPE in place on K real bf16 plane [b][kv][s][128].
__global__ __launch_bounds__(256)
void rope_k_kernel(uint16_t* __restrict__ kb_re)
{
    int gidx = blockIdx.x * 256 + threadIdx.x;
    int j = gidx & 15, kvh = (gidx >> 4) & 3;
    int rest = gidx >> 6;
    int s = rest & (S_ - 1), b = rest >> 10;
    int d0 = j * 4;
    size_t base = ((size_t)(b * KV_ + kvh) * S_ + s) * 128;
    ushort4 u0 = *(const ushort4*)&kb_re[base + d0];
    ushort4 u1 = *(const ushort4*)&kb_re[base + d0 + 64];
    float rv0[4] = { bf2f(u0.x), bf2f(u0.y), bf2f(u0.z), bf2f(u0.w) };
    float rv1[4] = { bf2f(u1.x), bf2f(u1.y), bf2f(u1.z), bf2f(u1.w) };
    float ro0[4], ro1[4];
#pragma unroll
    for (int t = 0; t < 4; ++t) {
        float f = __expf(-(float)(d0 + t) * LN1E4_OVER_64);
        float sn, c;
        __sincosf((float)s * f, &sn, &c);
        ro0[t] = rv0[t] * c - rv1[t] * sn;
        ro1[t] = rv1[t] * c + rv0[t] * sn;
    }
    *(ushort4*)&kb_re[base + d0]      = (ushort4){ f2bf(ro0[0]), f2bf(ro0[1]), f2bf(ro0[2]), f2bf(ro0[3]) };
    *(ushort4*)&kb_re[base + d0 + 64] = (ushort4){ f2bf(ro1[0]), f2bf(ro1[1]), f2bf(ro1[2]), f2bf(ro1[3]) };
}

// ---------------------------------------------------------------------------
// V transpose: vb [bk][s][128] bf16 -> vt [bk][d][1024] bf16.
// ---------------------------------------------------------------------------
__global__ __launch_bounds__(256)
void vtrans_kernel(const uint16_t* __restrict__ vbr, const uint16_t* __restrict__ vbi,
                   uint16_t* __restrict__ vtr, uint16_t* __restrict__ vti)
{
    __shared__ uint16_t t[32][36];
    const int pl = blockIdx.z & 1, bk = blockIdx.z >> 1;
    const int s0 = blockIdx.x * 32, d0 = blockIdx.y * 32;
    const uint16_t* src = (pl ? vbi : vbr) + ((size_t)bk * S_) * 128;
    uint16_t*       dst = (pl ? vti : vtr) + ((size_t)bk * 128) * S_;
    const int r = threadIdx.x >> 3, c = (threadIdx.x & 7) * 4;
    *(ushort4*)&t[r][c] = *(const ushort4*)&src[(size_t)(s0 + r) * 128 + d0 + c];
    __syncthreads();
    ushort4 o = (ushort4){ t[c][r], t[c + 1][r], t[c + 2][r], t[c + 3][r] };
    *(ushort4*)&dst[(size_t)(d0 + r) * S_ + s0 + c] = o;
}

// ---------------------------------------------------------------------------
// MFMA flash attention (bf16, fp32 accum, online softmax in registers).
// v6: the gemm_i8 pipeline ported to attention. K and V tiles staged by
// global_load_lds DMA (zero VGPR data path, no ds_writes) into LINEAR
// chunk-major LDS layouts ([ch][row] so fragment reads are 64 distinct
// contiguous 16B slots = conflict-free without padding, satisfying the
// DMA's wave-uniform-base+lane*16 dest constraint). Double-buffered with
// counted vmcnt: vmcnt(8) = "tile k landed, tile k+1 in flight"; raw
// s_barrier keeps the prefetch DMA alive across the barrier (no drain).
// Each wave issues exactly 8 DMA / tile: K 2pl*32r*256B + V 2pl*128d*64B
// = 32KB / (64 lanes * 16B) / 4 waves.
// LDS: 2*32KB + 5KB sp = 69KB -> 2 blocks/CU (grid-limited to 2 anyway).
// ---------------------------------------------------------------------------
__global__ __launch_bounds__(256)
void attn_mfma_kernel(const uint16_t* __restrict__ qb_re, const uint16_t* __restrict__ qb_im,
                      const uint16_t* __restrict__ kb_re, const uint16_t* __restrict__ kb_im,
                      const uint16_t* __restrict__ vt_re, const uint16_t* __restrict__ vt_im,
                      float* __restrict__ o_re, float* __restrict__ o_im)
{
    __shared__ alignas(16) uint16_t sbuf[2][16384];   // 2 x 32KB: K [pl][ch16][row32]x8, V [pl][ch4][d128]x8
    __shared__ alignas(16) uint16_t sp[4][16][40];

    const int tid = threadIdx.x;
    const int w = tid >> 6, lane = tid & 63;
    const int r16 = lane & 15, q4 = lane >> 4;
    const int qt = gridDim.x - 1 - blockIdx.x;        // heavy blocks dispatch first
    const int h = blockIdx.y, b = blockIdx.z;
    const int kvh = h >> 2;
    const int q0 = qt * 64, qw0 = q0 + w * 16;

    bf16x8 qfr[4], qfi[4];
    {
        const size_t qbase = ((size_t)(b * H_ + h) * S_ + qw0 + r16) * 128;
#pragma unroll
        for (int ks = 0; ks < 4; ++ks) {
            const int col = ks * 32 + q4 * 8;
            qfr[ks] = *(const bf16x8*)&qb_re[qbase + col];
            qfi[ks] = *(const bf16x8*)&qb_im[qbase + col];
        }
    }

    f32x4 oa[2][8] = {};
    float m_r[4] = { -3e38f, -3e38f, -3e38f, -3e38f };
    float l_r[4] = { 0.f, 0.f, 0.f, 0.f };

    const size_t kgbase0 = (size_t)(b * KV_ + kvh) * S_ * 128;
    const uint16_t* vre = vt_re + (size_t)(b * KV_ + kvh) * 128 * (size_t)S_;
    const uint16_t* vim = vt_im + (size_t)(b * KV_ + kvh) * 128 * (size_t)S_;

    // Per-lane DMA source bases (tile 0). LDS dest for inst i of wave w is
    // elems [w*512 + i*2048 + lane*8] -> byte a = w*1024 + lane*16 + i*4096.
    // K region (a<16384): pl=a>>13 (=i>>1), ch=bits12:9 = (i&1)*8+w*2+(lane>>5),
    //                     row=bits8:4 = lane&31.  elem = row*128 + ch*8.
    // V region:           pl=i>>1, ch=bits12:11 = (i&1)*2+(w>>1),
    //                     d = bits10:4 = (w&1)*64+lane. elem = d*S + ch*8.
    const uint16_t* kp[4];
    const uint16_t* vp[4];
#pragma unroll
    for (int i = 0; i < 4; ++i) {
        const int kch = (i & 1) * 8 + w * 2 + (lane >> 5);
        kp[i] = ((i >> 1) ? kb_im : kb_re) + kgbase0 + (size_t)(lane & 31) * 128 + kch * 8;
        const int vch = (i & 1) * 2 + (w >> 1);
        const int vd  = ((w & 1) << 6) | lane;
        vp[i] = ((i >> 1) ? vim : vre) + (size_t)vd * S_ + vch * 8;
    }

    auto issue_tile = [&](int kt, int buf) {
#pragma unroll
        for (int i = 0; i < 4; ++i)
            async_copy16(kp[i] + (size_t)kt * 4096, &sbuf[buf][w * 512 + i * 2048]);
#pragma unroll
        for (int i = 0; i < 4; ++i)
            async_copy16(vp[i] + (size_t)kt * 32, &sbuf[buf][8192 + w * 512 + i * 2048]);
    };

    const int nk = (q0 + 64) >> 5;                    // kv tiles of 32, nk >= 2

    issue_tile(0, 0);
    issue_tile(1, 1);

    for (int k = 0; k < nk; ++k) {
        if (k == nk - 1) { asm volatile("s_waitcnt vmcnt(0)" ::: "memory"); }
        else             { asm volatile("s_waitcnt vmcnt(8)" ::: "memory"); }
        asm volatile("s_barrier" ::: "memory");
        const uint16_t* sb = sbuf[k & 1];
        const int c0 = k << 5;

        if (c0 <= qw0 + 15) {
            f32x4 sc[2] = {};
#pragma unroll
            for (int cblk = 0; cblk < 2; ++cblk) {
                const int krow = cblk * 16 + r16;
#pragma unroll
                for (int ks = 0; ks < 4; ++ks) {
                    const int koff = (ks * 4 + q4) * 256 + krow * 8;
                    bf16x8 kr = *(const bf16x8*)&sb[koff];
                    bf16x8 ki = *(const bf16x8*)&sb[4096 + koff];
                    sc[cblk] = __builtin_amdgcn_mfma_f32_16x16x32_bf16(qfr[ks], kr, sc[cblk], 0, 0, 0);
                    sc[cblk] = __builtin_amdgcn_mfma_f32_16x16x32_bf16(qfi[ks], ki, sc[cblk], 0, 0, 0);
                }
            }
#pragma unroll
            for (int cblk = 0; cblk < 2; ++cblk)
#pragma unroll
                for (int reg = 0; reg < 4; ++reg) {
                    float sval = sc[cblk][reg] * 0.08838834764831845f;
                    const int rowg = qw0 + q4 * 4 + reg;
                    const int colg = c0 + cblk * 16 + r16;
                    if (colg > rowg) sval = -3e38f;
                    sc[cblk][reg] = sval;
                }
            float al[4];
#pragma unroll
            for (int reg = 0; reg < 4; ++reg) {
                float mx = fmaxf(sc[0][reg], sc[1][reg]);
#pragma unroll
                for (int msk = 1; msk < 16; msk <<= 1) mx = fmaxf(mx, __shfl_xor(mx, msk));
                const float mn = fmaxf(m_r[reg], mx);
                al[reg] = __expf(m_r[reg] - mn);
                const float p0 = __expf(sc[0][reg] - mn);
                const float p1 = __expf(sc[1][reg] - mn);
                sc[0][reg] = p0; sc[1][reg] = p1;
                float rs = p0 + p1;
#pragma unroll
                for (int msk = 1; msk < 16; msk <<= 1) rs += __shfl_xor(rs, msk);
                l_r[reg] = l_r[reg] * al[reg] + rs;
                m_r[reg] = mn;
            }
#pragma unroll
            for (int cblk = 0; cblk < 2; ++cblk)
#pragma unroll
                for (int reg = 0; reg < 4; ++reg)
                    sp[w][q4 * 4 + reg][cblk * 16 + r16] = f2bf(sc[cblk][reg]);
#pragma unroll
            for (int dblk = 0; dblk < 8; ++dblk)
#pragma unroll
                for (int reg = 0; reg < 4; ++reg) {
                    oa[0][dblk][reg] *= al[reg];
                    oa[1][dblk][reg] *= al[reg];
                }
            bf16x8 pf = *(const bf16x8*)&sp[w][r16][q4 * 8];
#pragma unroll
            for (int dblk = 0; dblk < 8; ++dblk) {
                const int voff = 8192 + q4 * 1024 + (dblk * 16 + r16) * 8;
                bf16x8 vr = *(const bf16x8*)&sb[voff];
                bf16x8 vi = *(const bf16x8*)&sb[4096 + voff];
                oa[0][dblk] = __builtin_amdgcn_mfma_f32_16x16x32_bf16(pf, vr, oa[0][dblk], 0, 0, 0);
                oa[1][dblk] = __builtin_amdgcn_mfma_f32_16x16x32_bf16(pf, vi, oa[1][dblk], 0, 0, 0);
            }
        }

        asm volatile("s_barrier" ::: "memory");       // all reads of buf done
        if (k + 2 < nk) issue_tile(k + 2, k & 1);
    }

    float inv[4];
#pragma unroll
    for (int reg = 0; reg < 4; ++reg) inv[reg] = 1.f / l_r[reg];
#pragma unroll
    for (int dblk = 0; dblk < 8; ++dblk) {
        const int col = h * 128 + dblk * 16 + r16;
#pragma unroll
        for (int reg = 0; reg < 4; ++reg) {
            const size_t tok = (size_t)b * S_ + qw0 + q4 * 4 + reg;
            o_re[tok * 2048 + col] = oa[0][dblk][reg] * inv[reg];
            o_im[tok * 2048 + col] = oa[1][dblk][reg] * inv[reg];
        }
    }
}

// ---------------------------------------------------------------------------
extern "C" void kernel_launch(void* const* d_in, const int* in_sizes, int n_in,
                              void* d_out, int out_size, void* d_ws, size_t ws_size,
                              hipStream_t stream)
{
    const float* hr    = (const float*)d_in[0];
    const float* hi    = (const float*)d_in[1];
    const float* wq_re = (const float*)d_in[2];
    const float* wq_im = (const float*)d_in[3];
    const float* wk_re = (const float*)d_in[4];
    const float* wk_im = (const float*)d_in[5];
    const float* wv_re = (const float*)d_in[6];
    const float* wv_im = (const float*)d_in[7];
    const float* wo_re = (const float*)d_in[8];
    const float* wo_im = (const float*)d_in[9];
    float* out = (float*)d_out;
    char*  base = (char*)d_ws;

    const size_t MB4  = (size_t)2048 * 2048;
    const size_t QKVP = (size_t)3072 * 2048;
    const size_t KVE  = (size_t)B_ * KV_ * S_ * 128;

    float*   mags   = (float*)(base);
    float*   invs1  = (float*)(base + 1024);
    float*   invs2  = (float*)(base + 9216);
    int8_t*  xr_q   = (int8_t*)(base + 32768);
    int8_t*  xi_q   = xr_q + MB4;
    int8_t*  qkv_sr = xi_q + MB4;
    int8_t*  qkv_si = qkv_sr + QKVP;
    int8_t*  qkv_ns = qkv_si + QKVP;
    int8_t*  wo_sr  = qkv_ns + QKVP;
    int8_t*  wo_si  = wo_sr + MB4;
    int8_t*  wo_ns  = wo_si + MB4;
    float*   q_re   = (float*)(wo_ns + MB4);
    float*   q_im   = q_re + MB4;
    uint16_t* kb_re = (uint16_t*)(q_im + MB4);
    uint16_t* kb_im = kb_re + KVE;
    uint16_t* vb_re = kb_im + KVE;
    uint16_t* vb_im = vb_re + KVE;
    uint16_t* vt_re = (uint16_t*)xr_q;
    uint16_t* vt_im = (uint16_t*)xi_q;
    uint16_t* qb_re = (uint16_t*)qkv_sr;
    uint16_t* qb_im = (uint16_t*)(qkv_sr + 8388608);

    hipMemsetAsync(mags, 0, 16, stream);

    decode_kernel<<<dim3(32, 32), 256, 0, stream>>>(wq_re, wq_im, 2048, qkv_sr, qkv_si, qkv_ns, 0,    mags + 0);
    decode_kernel<<<dim3(8, 32),  256, 0, stream>>>(wk_re, wk_im, 512,  qkv_sr, qkv_si, qkv_ns, 2048, mags + 1);
    decode_kernel<<<dim3(8, 32),  256, 0, stream>>>(wv_re, wv_im, 512,  qkv_sr, qkv_si, qkv_ns, 2560, mags + 2);
    decode_kernel<<<dim3(32, 32), 256, 0, stream>>>(wo_re, wo_im, 2048, wo_sr, wo_si, wo_ns, 0,       mags + 3);

    act_quant_i8_kernel<<<NTOK, 256, 0, stream>>>(hr, hi, xr_q, xi_q, invs1);

    gemm_i8_kernel<0><<<dim3(24, 16), 256, 0, stream>>>(
        xr_q, xi_q, qkv_sr, qkv_si, qkv_ns, 0, invs1, mags,
        1.0f / (float)((size_t)D_ * QD), 1.0f / (float)((size_t)D_ * KD), 1.0f / (float)((size_t)D_ * KD),
        q_re, q_im, kb_re, kb_im, vb_re, vb_im);

    rope_q_kernel<<<NTOK * H_ * 16 / 256, 256, 0, stream>>>(q_re, q_im, qb_re, qb_im);
    rope_k_kernel<<<NTOK * KV_ * 16 / 256, 256, 0, stream>>>(kb_re);
    vtrans_kernel<<<dim3(S_ / 32, 128 / 32, B_ * KV_ * 2), 256, 0, stream>>>(vb_re, vb_im, vt_re, vt_im);

    attn_mfma_kernel<<<dim3(S_ / 64, H_, B_), 256, 0, stream>>>(
        qb_re, qb_im, kb_re, kb_im, vt_re, vt_im, q_re, q_im);

    act_quant_i8_kernel<<<NTOK, 256, 0, stream>>>(q_re, q_im, xr_q, xi_q, invs2);

    gemm_i8_kernel<1><<<dim3(16, 16), 256, 0, stream>>>(
        xr_q, xi_q, wo_sr, wo_si, wo_ns, 2048, invs2, mags + 3,
        1.0f / (float)((size_t)QD * D_), 0.f, 0.f,
        out, out + MB4, nullptr, nullptr, nullptr, nullptr);
}

// Round 6
// 486.516 us; speedup vs baseline: 1.1824x; 1.0175x over previous
//
#include <hip/hip_runtime.h>
#include <stdint.h>

#define B_   2
#define S_   1024
#define D_   2048
#define H_   16
#define KV_  4
#define HD_  128
#define NTOK (B_ * S_)        /* 2048 tokens */
#define QD   (H_ * HD_)       /* 2048 */
#define KD   (KV_ * HD_)      /* 512  */

using i32x4  = __attribute__((ext_vector_type(4)))  int;
using i32x16 = __attribute__((ext_vector_type(16))) int;
using f32x4  = __attribute__((ext_vector_type(4)))  float;
using bf16x8 = __attribute__((ext_vector_type(8)))  short;

#define LN1E4_OVER_64 0.14391156831212725f

// ---------------- bf16 helpers ---------------------------------------------
__device__ __forceinline__ float bf2f(uint16_t u) { return __uint_as_float((uint32_t)u << 16); }
__device__ __forceinline__ uint16_t f2bf(float f) {
    uint32_t u = __float_as_uint(f);
    return (uint16_t)((u + 0x7FFFu + ((u >> 16) & 1u)) >> 16);   // RNE
}

// ---------------------------------------------------------------------------
// Per-token joint absmax int8 quantization (dim = 2048 fixed).
// ---------------------------------------------------------------------------
__global__ __launch_bounds__(256)
void act_quant_i8_kernel(const float* __restrict__ xr, const float* __restrict__ xi,
                         int8_t* __restrict__ qr, int8_t* __restrict__ qi,
                         float* __restrict__ invs)
{
    const int tok = blockIdx.x, t = threadIdx.x;
    const float* pr = xr + (size_t)tok * 2048 + t * 8;
    const float* pi = xi + (size_t)tok * 2048 + t * 8;
    float4 r0 = *(const float4*)pr, r1 = *(const float4*)(pr + 4);
    float4 i0 = *(const float4*)pi, i1 = *(const float4*)(pi + 4);
    float am = fmaxf(fmaxf(fmaxf(fabsf(r0.x), fabsf(r0.y)), fmaxf(fabsf(r0.z), fabsf(r0.w))),
                     fmaxf(fmaxf(fabsf(r1.x), fabsf(r1.y)), fmaxf(fabsf(r1.z), fabsf(r1.w))));
    am = fmaxf(am, fmaxf(fmaxf(fmaxf(fabsf(i0.x), fabsf(i0.y)), fmaxf(fabsf(i0.z), fabsf(i0.w))),
                         fmaxf(fmaxf(fabsf(i1.x), fabsf(i1.y)), fmaxf(fabsf(i1.z), fabsf(i1.w)))));
    __shared__ float red[256];
    red[t] = am;
    __syncthreads();
    for (int st = 128; st > 0; st >>= 1) {
        if (t < st) red[t] = fmaxf(red[t], red[t + st]);
        __syncthreads();
    }
    const float s = 127.0f / fmaxf(red[0], 1e-5f);
    if (t == 0) invs[tok] = 1.0f / s;
#define Q8(x) ((uint32_t)(uint8_t)(int8_t)(int)fminf(fmaxf(rintf((x) * s), -128.f), 127.f))
    uint32_t a0 = Q8(r0.x) | (Q8(r0.y) << 8) | (Q8(r0.z) << 16) | (Q8(r0.w) << 24);
    uint32_t a1 = Q8(r1.x) | (Q8(r1.y) << 8) | (Q8(r1.z) << 16) | (Q8(r1.w) << 24);
    uint32_t b0 = Q8(i0.x) | (Q8(i0.y) << 8) | (Q8(i0.z) << 16) | (Q8(i0.w) << 24);
    uint32_t b1 = Q8(i1.x) | (Q8(i1.y) << 8) | (Q8(i1.z) << 16) | (Q8(i1.w) << 24);
#undef Q8
    *(uint32_t*)(qr + (size_t)tok * 2048 + t * 8)     = a0;
    *(uint32_t*)(qr + (size_t)tok * 2048 + t * 8 + 4) = a1;
    *(uint32_t*)(qi + (size_t)tok * 2048 + t * 8)     = b0;
    *(uint32_t*)(qi + (size_t)tok * 2048 + t * 8 + 4) = b1;
}

// ---------------------------------------------------------------------------
// Weight decode + transpose + fused mag reduction.
// ---------------------------------------------------------------------------
__global__ __launch_bounds__(256)
void decode_kernel(const float* __restrict__ wr, const float* __restrict__ wi,
                   int N, int8_t* __restrict__ psr, int8_t* __restrict__ psi,
                   int8_t* __restrict__ pnsi, int n_off, float* __restrict__ mag_out)
{
    __shared__ alignas(16) int8_t tr[3][64][80];
    __shared__ float red[256];
    const int n0 = blockIdx.x * 64, k0 = blockIdx.y * 64;
    float msum = 0.f;
    for (int idx = threadIdx.x; idx < 4096; idx += 256) {
        int j = idx & 63, i = idx >> 6;                 // j = n, i = k
        size_t g = (size_t)(k0 + i) * N + n0 + j;
        float a = wr[g], b = wi[g];
        msum += sqrtf(a * a + b * b);
        int8_t sr, si;
        if (fabsf(a) >= fabsf(b)) {
            sr = (a > 0.f) ? 1 : ((a < 0.f) ? -1 : 0);
            si = 0;
        } else {
            sr = 0;
            si = (b > 0.f) ? 1 : ((b < 0.f) ? -1 : 0);
        }
        tr[0][j][i] = sr;
        tr[1][j][i] = si;
        tr[2][j][i] = (int8_t)(-si);
    }
    red[threadIdx.x] = msum;
    __syncthreads();
    for (int st = 128; st > 0; st >>= 1) {
        if (threadIdx.x < st) red[threadIdx.x] += red[threadIdx.x + st];
        __syncthreads();
    }
    if (threadIdx.x == 0) atomicAdd(mag_out, red[0]);
    int8_t* planes[3] = { psr, psi, pnsi };
    for (int idx = threadIdx.x; idx < 768; idx += 256) {
        int p = idx >> 8, rem = idx & 255, n = rem >> 2, c = rem & 3;
        int4 v = *(const int4*)&tr[p][n][c * 16];
        *(int4*)(planes[p] + (size_t)(n_off + n0 + n) * 2048 + k0 + c * 16) = v;
    }
}

// ---------------------------------------------------------------------------
// int8 MFMA complex GEMM — double-buffered LDS DMA pipeline, 512 threads.
// v2: 8 waves (2M x 4N map), __launch_bounds__(512,4) caps VGPR at 128 so
// 2 blocks/CU = 4 waves/SIMD (was 2) — doubles TLP to hide ds_read/barrier
// latency (r5 counters: MfmaUtil 17.5%, Occ 8.2% => latency-starved).
// Each wave owns exactly 5 global_load_lds per tile; vmcnt(5) == "previous
// tile complete, next tile in flight".
// ---------------------------------------------------------------------------
__device__ __forceinline__ void async_copy16(const void* g, void* l) {
    __builtin_amdgcn_global_load_lds((const __attribute__((address_space(1))) void*)g,
                                     (__attribute__((address_space(3))) void*)l, 16, 0, 0);
}

template <int MODE>
__global__ __launch_bounds__(512, 4)
void gemm_i8_kernel(const int8_t* __restrict__ axr, const int8_t* __restrict__ axi,
                    const int8_t* __restrict__ bsr, const int8_t* __restrict__ bsi,
                    const int8_t* __restrict__ bnsi,
                    int Nout, const float* __restrict__ invs,
                    const float* __restrict__ mag_sums,
                    float magc0, float magc1, float magc2,
                    float* o_re, float* o_im,
                    uint16_t* kbr, uint16_t* kbi, uint16_t* vbr, uint16_t* vbi)
{
    __shared__ alignas(16) int8_t smem[2][5 * 8192];   // 80 KB, 2-stage
    const int tid = threadIdx.x;
    const int wav = tid >> 6, lane = tid & 63;         // wav 0..7
    const int tileM = blockIdx.y * 128, tileN = blockIdx.x * 128;
    const int wm = wav & 1, wn = wav >> 1;             // 2M x 4N wave map
    const int K = 2048;

    const int8_t* gplane[5] = { axr, axi, bsr, bsi, bnsi };
    const int     rbase[5]  = { tileM, tileM, tileN, tileN, tileN };

    i32x16 acc_re[2] = {};
    i32x16 acc_im[2] = {};

    auto issue_tile = [&](int k0, int buf) {
#pragma unroll
        for (int i = 0; i < 5; ++i) {
            int q = wav + 8 * i;            // 40 lds-dma per tile, 5 per wave
            int pl = q >> 3, seg = q & 7;
            int c = seg >> 1, m0 = (seg & 1) << 6;
            const int8_t* g = gplane[pl] + (size_t)(rbase[pl] + m0 + lane) * K + k0 + c * 16;
            int8_t* l = &smem[buf][pl * 8192 + (c * 128 + m0) * 16];
            async_copy16(g, l);
        }
    };

    issue_tile(0, 0);
    issue_tile(64, 1);

    for (int k = 0; k < 32; ++k) {
        if (k == 31) { asm volatile("s_waitcnt vmcnt(0)" ::: "memory"); }
        else         { asm volatile("s_waitcnt vmcnt(5)" ::: "memory"); }
        asm volatile("s_barrier" ::: "memory");
        const int8_t* sb = smem[k & 1];
#pragma unroll
        for (int s = 0; s < 2; ++s) {
            const int cc = 2 * s + (lane >> 5);
            const int rA = wm * 64 + (lane & 31);
            const int rB = wn * 32 + (lane & 31);
            i32x4 fxr[2], fxi[2], fsr, fsi, fns;
#pragma unroll
            for (int mb = 0; mb < 2; ++mb) {
                int off = (cc * 128 + rA + mb * 32) * 16;
                fxr[mb] = *(const i32x4*)&sb[0 * 8192 + off];
                fxi[mb] = *(const i32x4*)&sb[1 * 8192 + off];
            }
            {
                int off = (cc * 128 + rB) * 16;
                fsr = *(const i32x4*)&sb[2 * 8192 + off];
                fsi = *(const i32x4*)&sb[3 * 8192 + off];
                fns = *(const i32x4*)&sb[4 * 8192 + off];
            }
#pragma unroll
            for (int mb = 0; mb < 2; ++mb) {
                acc_re[mb] = __builtin_amdgcn_mfma_i32_32x32x32_i8(fxr[mb], fsr, acc_re[mb], 0, 0, 0);
                acc_re[mb] = __builtin_amdgcn_mfma_i32_32x32x32_i8(fxi[mb], fns, acc_re[mb], 0, 0, 0);
                acc_im[mb] = __builtin_amdgcn_mfma_i32_32x32x32_i8(fxr[mb], fsi, acc_im[mb], 0, 0, 0);
                acc_im[mb] = __builtin_amdgcn_mfma_i32_32x32x32_i8(fxi[mb], fsr, acc_im[mb], 0, 0, 0);
            }
        }
        asm volatile("s_barrier" ::: "memory");       // all reads of buf done
        if (k + 2 < 32) issue_tile((k + 2) * 64, k & 1);
    }

    const int ln31 = lane & 31, lq = lane >> 5;
    const int gn = tileN + wn * 32 + ln31;
    float mag;
    if (MODE == 0)
        mag = (gn < 2048) ? mag_sums[0] * magc0
            : (gn < 2560) ? mag_sums[1] * magc1
                          : mag_sums[2] * magc2;
    else
        mag = mag_sums[0] * magc0;
#pragma unroll
    for (int mb = 0; mb < 2; ++mb) {
#pragma unroll
        for (int r = 0; r < 16; ++r) {
            const int row = (r & 3) + 8 * (r >> 2) + 4 * lq;
            const int gm = tileM + wm * 64 + mb * 32 + row;
            const float sc = mag * invs[gm];
            const float re = (float)acc_re[mb][r] * sc;
            const float im = (float)acc_im[mb][r] * sc;
            if (MODE == 1) {
                o_re[(size_t)gm * Nout + gn] = re;
                o_im[(size_t)gm * Nout + gn] = im;
            } else {
                const int s = gm & (S_ - 1), bb = gm >> 10;
                if (gn < 2048) {
                    o_re[(size_t)gm * 2048 + gn] = re;
                    o_im[(size_t)gm * 2048 + gn] = im;
                } else if (gn < 2560) {
                    int c = gn - 2048, kvh = c >> 7, d = c & 127;
                    size_t off = ((size_t)(bb * KV_ + kvh) * S_ + s) * 128 + d;
                    kbr[off] = f2bf(re);
                    kbi[off] = f2bf(im);
                } else {
                    int c = gn - 2560, kvh = c >> 7, d = c & 127;
                    size_t off = ((size_t)(bb * KV_ + kvh) * S_ + s) * 128 + d;
                    vbr[off] = f2bf(re);
                    vbi[off] = f2bf(im);
                }
            }
        }
    }
}

// ---------------------------------------------------------------------------
// RoPE + bf16 convert + head-major rearrange for Q.
// ---------------------------------------------------------------------------
__global__ __launch_bounds__(256)
void rope_q_kernel(const float* __restrict__ q_re, const float* __restrict__ q_im,
                   uint16_t* __restrict__ qb_re, uint16_t* __restrict__ qb_im)
{
    int gidx = blockIdx.x * 256 + threadIdx.x;      // tok*256 + h*16 + j
    int j = gidx & 15, h = (gidx >> 4) & 15, tok = gidx >> 8;
    int s = tok & (S_ - 1), b = tok >> 10;
    int d0 = j * 4;
    size_t ib = (size_t)tok * 2048 + h * 128;
    float4 r0 = *(const float4*)&q_re[ib + d0];
    float4 r1 = *(const float4*)&q_re[ib + d0 + 64];
    float4 i0 = *(const float4*)&q_im[ib + d0];
    float4 i1 = *(const float4*)&q_im[ib + d0 + 64];
    float ro0[4], ro1[4];
    float rv0[4] = { r0.x, r0.y, r0.z, r0.w };
    float rv1[4] = { r1.x, r1.y, r1.z, r1.w };
#pragma unroll
    for (int t = 0; t < 4; ++t) {
        float f = __expf(-(float)(d0 + t) * LN1E4_OVER_64);
        float sn, c;
        __sincosf((float)s * f, &sn, &c);
        ro0[t] = rv0[t] * c - rv1[t] * sn;
        ro1[t] = rv1[t] * c + rv0[t] * sn;
    }
    size_t ob = ((size_t)(b * H_ + h) * S_ + s) * 128;
    ushort4 w;
    w = (ushort4){ f2bf(ro0[0]), f2bf(ro0[1]), f2bf(ro0[2]), f2bf(ro0[3]) };
    *(ushort4*)&qb_re[ob + d0] = w;
    w = (ushort4){ f2bf(ro1[0]), f2bf(ro1[1]), f2bf(ro1[2]), f2bf(ro1[3]) };
    *(ushort4*)&qb_re[ob + d0 + 64] = w;
    w = (ushort4){ f2bf(i0.x), f2bf(i0.y), f2bf(i0.z), f2bf(i0.w) };
    *(ushort4*)&qb_im[ob + d0] = w;
    w = (ushort4){ f2bf(i1.x), f2bf(i1.y), f2bf(i1.z), f2bf(i1.w) };
    *(ushort4*)&qb_im[ob + d0 + 64] = w;
}

// RoPE in place on K real bf16 plane [b][kv][s][128].
__global__ __launch_bounds__(256)
void rope_k_kernel(uint16_t* __restrict__ kb_re)
{
    int gidx = blockIdx.x * 256 + threadIdx.x;
    int j = gidx & 15, kvh = (gidx >> 4) & 3;
    int rest = gidx >> 6;
    int s = rest & (S_ - 1), b = rest >> 10;
    int d0 = j * 4;
    size_t base = ((size_t)(b * KV_ + kvh) * S_ + s) * 128;
    ushort4 u0 = *(const ushort4*)&kb_re[base + d0];
    ushort4 u1 = *(const ushort4*)&kb_re[base + d0 + 64];
    float rv0[4] = { bf2f(u0.x), bf2f(u0.y), bf2f(u0.z), bf2f(u0.w) };
    float rv1[4] = { bf2f(u1.x), bf2f(u1.y), bf2f(u1.z), bf2f(u1.w) };
    float ro0[4], ro1[4];
#pragma unroll
    for (int t = 0; t < 4; ++t) {
        float f = __expf(-(float)(d0 + t) * LN1E4_OVER_64);
        float sn, c;
        __sincosf((float)s * f, &sn, &c);
        ro0[t] = rv0[t] * c - rv1[t] * sn;
        ro1[t] = rv1[t] * c + rv0[t] * sn;
    }
    *(ushort4*)&kb_re[base + d0]      = (ushort4){ f2bf(ro0[0]), f2bf(ro0[1]), f2bf(ro0[2]), f2bf(ro0[3]) };
    *(ushort4*)&kb_re[base + d0 + 64] = (ushort4){ f2bf(ro1[0]), f2bf(ro1[1]), f2bf(ro1[2]), f2bf(ro1[3]) };
}

// ---------------------------------------------------------------------------
// V transpose: vb [bk][s][128] bf16 -> vt [bk][d][1024] bf16.
// ---------------------------------------------------------------------------
__global__ __launch_bounds__(256)
void vtrans_kernel(const uint16_t* __restrict__ vbr, const uint16_t* __restrict__ vbi,
                   uint16_t* __restrict__ vtr, uint16_t* __restrict__ vti)
{
    __shared__ uint16_t t[32][36];
    const int pl = blockIdx.z & 1, bk = blockIdx.z >> 1;
    const int s0 = blockIdx.x * 32, d0 = blockIdx.y * 32;
    const uint16_t* src = (pl ? vbi : vbr) + ((size_t)bk * S_) * 128;
    uint16_t*       dst = (pl ? vti : vtr) + ((size_t)bk * 128) * S_;
    const int r = threadIdx.x >> 3, c = (threadIdx.x & 7) * 4;
    *(ushort4*)&t[r][c] = *(const ushort4*)&src[(size_t)(s0 + r) * 128 + d0 + c];
    __syncthreads();
    ushort4 o = (ushort4){ t[c][r], t[c + 1][r], t[c + 2][r], t[c + 3][r] };
    *(ushort4*)&dst[(size_t)(d0 + r) * S_ + s0 + c] = o;
}

// ---------------------------------------------------------------------------
// MFMA flash attention (bf16, fp32 accum, online softmax in registers).
// v6: the gemm_i8 pipeline ported to attention. K and V tiles staged by
// global_load_lds DMA (zero VGPR data path, no ds_writes) into LINEAR
// chunk-major LDS layouts ([ch][row] so fragment reads are 64 distinct
// contiguous 16B slots = conflict-free without padding, satisfying the
// DMA's wave-uniform-base+lane*16 dest constraint). Double-buffered with
// counted vmcnt: vmcnt(8) = "tile k landed, tile k+1 in flight"; raw
// s_barrier keeps the prefetch DMA alive across the barrier (no drain).
// Each wave issues exactly 8 DMA / tile: K 2pl*32r*256B + V 2pl*128d*64B
// = 32KB / (64 lanes * 16B) / 4 waves.
// LDS: 2*32KB + 5KB sp = 69KB -> 2 blocks/CU (grid-limited to 2 anyway).
// ---------------------------------------------------------------------------
__global__ __launch_bounds__(256)
void attn_mfma_kernel(const uint16_t* __restrict__ qb_re, const uint16_t* __restrict__ qb_im,
                      const uint16_t* __restrict__ kb_re, const uint16_t* __restrict__ kb_im,
                      const uint16_t* __restrict__ vt_re, const uint16_t* __restrict__ vt_im,
                      float* __restrict__ o_re, float* __restrict__ o_im)
{
    __shared__ alignas(16) uint16_t sbuf[2][16384];   // 2 x 32KB: K [pl][ch16][row32]x8, V [pl][ch4][d128]x8
    __shared__ alignas(16) uint16_t sp[4][16][40];

    const int tid = threadIdx.x;
    const int w = tid >> 6, lane = tid & 63;
    const int r16 = lane & 15, q4 = lane >> 4;
    const int qt = gridDim.x - 1 - blockIdx.x;        // heavy blocks dispatch first
    const int h = blockIdx.y, b = blockIdx.z;
    const int kvh = h >> 2;
    const int q0 = qt * 64, qw0 = q0 + w * 16;

    bf16x8 qfr[4], qfi[4];
    {
        const size_t qbase = ((size_t)(b * H_ + h) * S_ + qw0 + r16) * 128;
#pragma unroll
        for (int ks = 0; ks < 4; ++ks) {
            const int col = ks * 32 + q4 * 8;
            qfr[ks] = *(const bf16x8*)&qb_re[qbase + col];
            qfi[ks] = *(const bf16x8*)&qb_im[qbase + col];
        }
    }

    f32x4 oa[2][8] = {};
    float m_r[4] = { -3e38f, -3e38f, -3e38f, -3e38f };
    float l_r[4] = { 0.f, 0.f, 0.f, 0.f };

    const size_t kgbase0 = (size_t)(b * KV_ + kvh) * S_ * 128;
    const uint16_t* vre = vt_re + (size_t)(b * KV_ + kvh) * 128 * (size_t)S_;
    const uint16_t* vim = vt_im + (size_t)(b * KV_ + kvh) * 128 * (size_t)S_;

    // Per-lane DMA source bases (tile 0). LDS dest for inst i of wave w is
    // elems [w*512 + i*2048 + lane*8] -> byte a = w*1024 + lane*16 + i*4096.
    // K region (a<16384): pl=a>>13 (=i>>1), ch=bits12:9 = (i&1)*8+w*2+(lane>>5),
    //                     row=bits8:4 = lane&31.  elem = row*128 + ch*8.
    // V region:           pl=i>>1, ch=bits12:11 = (i&1)*2+(w>>1),
    //                     d = bits10:4 = (w&1)*64+lane. elem = d*S + ch*8.
    const uint16_t* kp[4];
    const uint16_t* vp[4];
#pragma unroll
    for (int i = 0; i < 4; ++i) {
        const int kch = (i & 1) * 8 + w * 2 + (lane >> 5);
        kp[i] = ((i >> 1) ? kb_im : kb_re) + kgbase0 + (size_t)(lane & 31) * 128 + kch * 8;
        const int vch = (i & 1) * 2 + (w >> 1);
        const int vd  = ((w & 1) << 6) | lane;
        vp[i] = ((i >> 1) ? vim : vre) + (size_t)vd * S_ + vch * 8;
    }

    auto issue_tile = [&](int kt, int buf) {
#pragma unroll
        for (int i = 0; i < 4; ++i)
            async_copy16(kp[i] + (size_t)kt * 4096, &sbuf[buf][w * 512 + i * 2048]);
#pragma unroll
        for (int i = 0; i < 4; ++i)
            async_copy16(vp[i] + (size_t)kt * 32, &sbuf[buf][8192 + w * 512 + i * 2048]);
    };

    const int nk = (q0 + 64) >> 5;                    // kv tiles of 32, nk >= 2

    issue_tile(0, 0);
    issue_tile(1, 1);

    for (int k = 0; k < nk; ++k) {
        if (k == nk - 1) { asm volatile("s_waitcnt vmcnt(0)" ::: "memory"); }
        else             { asm volatile("s_waitcnt vmcnt(8)" ::: "memory"); }
        asm volatile("s_barrier" ::: "memory");
        const uint16_t* sb = sbuf[k & 1];
        const int c0 = k << 5;

        if (c0 <= qw0 + 15) {
            f32x4 sc[2] = {};
#pragma unroll
            for (int cblk = 0; cblk < 2; ++cblk) {
                const int krow = cblk * 16 + r16;
#pragma unroll
                for (int ks = 0; ks < 4; ++ks) {
                    const int koff = (ks * 4 + q4) * 256 + krow * 8;
                    bf16x8 kr = *(const bf16x8*)&sb[koff];
                    bf16x8 ki = *(const bf16x8*)&sb[4096 + koff];
                    sc[cblk] = __builtin_amdgcn_mfma_f32_16x16x32_bf16(qfr[ks], kr, sc[cblk], 0, 0, 0);
                    sc[cblk] = __builtin_amdgcn_mfma_f32_16x16x32_bf16(qfi[ks], ki, sc[cblk], 0, 0, 0);
                }
            }
#pragma unroll
            for (int cblk = 0; cblk < 2; ++cblk)
#pragma unroll
                for (int reg = 0; reg < 4; ++reg) {
                    float sval = sc[cblk][reg] * 0.08838834764831845f;
                    const int rowg = qw0 + q4 * 4 + reg;
                    const int colg = c0 + cblk * 16 + r16;
                    if (colg > rowg) sval = -3e38f;
                    sc[cblk][reg] = sval;
                }
            float al[4];
#pragma unroll
            for (int reg = 0; reg < 4; ++reg) {
                float mx = fmaxf(sc[0][reg], sc[1][reg]);
#pragma unroll
                for (int msk = 1; msk < 16; msk <<= 1) mx = fmaxf(mx, __shfl_xor(mx, msk));
                const float mn = fmaxf(m_r[reg], mx);
                al[reg] = __expf(m_r[reg] - mn);
                const float p0 = __expf(sc[0][reg] - mn);
                const float p1 = __expf(sc[1][reg] - mn);
                sc[0][reg] = p0; sc[1][reg] = p1;
                float rs = p0 + p1;
#pragma unroll
                for (int msk = 1; msk < 16; msk <<= 1) rs += __shfl_xor(rs, msk);
                l_r[reg] = l_r[reg] * al[reg] + rs;
                m_r[reg] = mn;
            }
#pragma unroll
            for (int cblk = 0; cblk < 2; ++cblk)
#pragma unroll
                for (int reg = 0; reg < 4; ++reg)
                    sp[w][q4 * 4 + reg][cblk * 16 + r16] = f2bf(sc[cblk][reg]);
#pragma unroll
            for (int dblk = 0; dblk < 8; ++dblk)
#pragma unroll
                for (int reg = 0; reg < 4; ++reg) {
                    oa[0][dblk][reg] *= al[reg];
                    oa[1][dblk][reg] *= al[reg];
                }
            bf16x8 pf = *(const bf16x8*)&sp[w][r16][q4 * 8];
#pragma unroll
            for (int dblk = 0; dblk < 8; ++dblk) {
                const int voff = 8192 + q4 * 1024 + (dblk * 16 + r16) * 8;
                bf16x8 vr = *(const bf16x8*)&sb[voff];
                bf16x8 vi = *(const bf16x8*)&sb[4096 + voff];
                oa[0][dblk] = __builtin_amdgcn_mfma_f32_16x16x32_bf16(pf, vr, oa[0][dblk], 0, 0, 0);
                oa[1][dblk] = __builtin_amdgcn_mfma_f32_16x16x32_bf16(pf, vi, oa[1][dblk], 0, 0, 0);
            }
        }

        asm volatile("s_barrier" ::: "memory");       // all reads of buf done
        if (k + 2 < nk) issue_tile(k + 2, k & 1);
    }

    float inv[4];
#pragma unroll
    for (int reg = 0; reg < 4; ++reg) inv[reg] = 1.f / l_r[reg];
#pragma unroll
    for (int dblk = 0; dblk < 8; ++dblk) {
        const int col = h * 128 + dblk * 16 + r16;
#pragma unroll
        for (int reg = 0; reg < 4; ++reg) {
            const size_t tok = (size_t)b * S_ + qw0 + q4 * 4 + reg;
            o_re[tok * 2048 + col] = oa[0][dblk][reg] * inv[reg];
            o_im[tok * 2048 + col] = oa[1][dblk][reg] * inv[reg];
        }
    }
}

// ---------------------------------------------------------------------------
extern "C" void kernel_launch(void* const* d_in, const int* in_sizes, int n_in,
                              void* d_out, int out_size, void* d_ws, size_t ws_size,
                              hipStream_t stream)
{
    const float* hr    = (const float*)d_in[0];
    const float* hi    = (const float*)d_in[1];
    const float* wq_re = (const float*)d_in[2];
    const float* wq_im = (const float*)d_in[3];
    const float* wk_re = (const float*)d_in[4];
    const float* wk_im = (const float*)d_in[5];
    const float* wv_re = (const float*)d_in[6];
    const float* wv_im = (const float*)d_in[7];
    const float* wo_re = (const float*)d_in[8];
    const float* wo_im = (const float*)d_in[9];
    float* out = (float*)d_out;
    char*  base = (char*)d_ws;

    const size_t MB4  = (size_t)2048 * 2048;
    const size_t QKVP = (size_t)3072 * 2048;
    const size_t KVE  = (size_t)B_ * KV_ * S_ * 128;

    float*   mags   = (float*)(base);
    float*   invs1  = (float*)(base + 1024);
    float*   invs2  = (float*)(base + 9216);
    int8_t*  xr_q   = (int8_t*)(base + 32768);
    int8_t*  xi_q   = xr_q + MB4;
    int8_t*  qkv_sr = xi_q + MB4;
    int8_t*  qkv_si = qkv_sr + QKVP;
    int8_t*  qkv_ns = qkv_si + QKVP;
    int8_t*  wo_sr  = qkv_ns + QKVP;
    int8_t*  wo_si  = wo_sr + MB4;
    int8_t*  wo_ns  = wo_si + MB4;
    float*   q_re   = (float*)(wo_ns + MB4);
    float*   q_im   = q_re + MB4;
    uint16_t* kb_re = (uint16_t*)(q_im + MB4);
    uint16_t* kb_im = kb_re + KVE;
    uint16_t* vb_re = kb_im + KVE;
    uint16_t* vb_im = vb_re + KVE;
    uint16_t* vt_re = (uint16_t*)xr_q;
    uint16_t* vt_im = (uint16_t*)xi_q;
    uint16_t* qb_re = (uint16_t*)qkv_sr;
    uint16_t* qb_im = (uint16_t*)(qkv_sr + 8388608);

    hipMemsetAsync(mags, 0, 16, stream);

    decode_kernel<<<dim3(32, 32), 256, 0, stream>>>(wq_re, wq_im, 2048, qkv_sr, qkv_si, qkv_ns, 0,    mags + 0);
    decode_kernel<<<dim3(8, 32),  256, 0, stream>>>(wk_re, wk_im, 512,  qkv_sr, qkv_si, qkv_ns, 2048, mags + 1);
    decode_kernel<<<dim3(8, 32),  256, 0, stream>>>(wv_re, wv_im, 512,  qkv_sr, qkv_si, qkv_ns, 2560, mags + 2);
    decode_kernel<<<dim3(32, 32), 256, 0, stream>>>(wo_re, wo_im, 2048, wo_sr, wo_si, wo_ns, 0,       mags + 3);

    act_quant_i8_kernel<<<NTOK, 256, 0, stream>>>(hr, hi, xr_q, xi_q, invs1);

    gemm_i8_kernel<0><<<dim3(24, 16), 512, 0, stream>>>(
        xr_q, xi_q, qkv_sr, qkv_si, qkv_ns, 0, invs1, mags,
        1.0f / (float)((size_t)D_ * QD), 1.0f / (float)((size_t)D_ * KD), 1.0f / (float)((size_t)D_ * KD),
        q_re, q_im, kb_re, kb_im, vb_re, vb_im);

    rope_q_kernel<<<NTOK * H_ * 16 / 256, 256, 0, stream>>>(q_re, q_im, qb_re, qb_im);
    rope_k_kernel<<<NTOK * KV_ * 16 / 256, 256, 0, stream>>>(kb_re);
    vtrans_kernel<<<dim3(S_ / 32, 128 / 32, B_ * KV_ * 2), 256, 0, stream>>>(vb_re, vb_im, vt_re, vt_im);

    attn_mfma_kernel<<<dim3(S_ / 64, H_, B_), 256, 0, stream>>>(
        qb_re, qb_im, kb_re, kb_im, vt_re, vt_im, q_re, q_im);

    act_quant_i8_kernel<<<NTOK, 256, 0, stream>>>(q_re, q_im, xr_q, xi_q, invs2);

    gemm_i8_kernel<1><<<dim3(16, 16), 512, 0, stream>>>(
        xr_q, xi_q, wo_sr, wo_si, wo_ns, 2048, invs2, mags + 3,
        1.0f / (float)((size_t)QD * D_), 0.f, 0.f,
        out, out + MB4, nullptr, nullptr, nullptr, nullptr);
}

// Round 7
// 469.751 us; speedup vs baseline: 1.2246x; 1.0357x over previous
//
#include <hip/hip_runtime.h>
#include <stdint.h>

#define B_   2
#define S_   1024
#define D_   2048
#define H_   16
#define KV_  4
#define HD_  128
#define NTOK (B_ * S_)        /* 2048 tokens */
#define QD   (H_ * HD_)       /* 2048 */
#define KD   (KV_ * HD_)      /* 512  */

using i32x4  = __attribute__((ext_vector_type(4)))  int;
using i32x16 = __attribute__((ext_vector_type(16))) int;
using f32x4  = __attribute__((ext_vector_type(4)))  float;
using bf16x8 = __attribute__((ext_vector_type(8)))  short;

#define LN1E4_OVER_64 0.14391156831212725f

// ---------------- bf16 helpers ---------------------------------------------
__device__ __forceinline__ float bf2f(uint16_t u) { return __uint_as_float((uint32_t)u << 16); }
__device__ __forceinline__ uint16_t f2bf(float f) {
    uint32_t u = __float_as_uint(f);
    return (uint16_t)((u + 0x7FFFu + ((u >> 16) & 1u)) >> 16);   // RNE
}

// ---------------------------------------------------------------------------
// Per-token joint absmax int8 quantization (dim = 2048 fixed).
// ---------------------------------------------------------------------------
__global__ __launch_bounds__(256)
void act_quant_i8_kernel(const float* __restrict__ xr, const float* __restrict__ xi,
                         int8_t* __restrict__ qr, int8_t* __restrict__ qi,
                         float* __restrict__ invs)
{
    const int tok = blockIdx.x, t = threadIdx.x;
    const float* pr = xr + (size_t)tok * 2048 + t * 8;
    const float* pi = xi + (size_t)tok * 2048 + t * 8;
    float4 r0 = *(const float4*)pr, r1 = *(const float4*)(pr + 4);
    float4 i0 = *(const float4*)pi, i1 = *(const float4*)(pi + 4);
    float am = fmaxf(fmaxf(fmaxf(fabsf(r0.x), fabsf(r0.y)), fmaxf(fabsf(r0.z), fabsf(r0.w))),
                     fmaxf(fmaxf(fabsf(r1.x), fabsf(r1.y)), fmaxf(fabsf(r1.z), fabsf(r1.w))));
    am = fmaxf(am, fmaxf(fmaxf(fmaxf(fabsf(i0.x), fabsf(i0.y)), fmaxf(fabsf(i0.z), fabsf(i0.w))),
                         fmaxf(fmaxf(fabsf(i1.x), fabsf(i1.y)), fmaxf(fabsf(i1.z), fabsf(i1.w)))));
    __shared__ float red[256];
    red[t] = am;
    __syncthreads();
    for (int st = 128; st > 0; st >>= 1) {
        if (t < st) red[t] = fmaxf(red[t], red[t + st]);
        __syncthreads();
    }
    const float s = 127.0f / fmaxf(red[0], 1e-5f);
    if (t == 0) invs[tok] = 1.0f / s;
#define Q8(x) ((uint32_t)(uint8_t)(int8_t)(int)fminf(fmaxf(rintf((x) * s), -128.f), 127.f))
    uint32_t a0 = Q8(r0.x) | (Q8(r0.y) << 8) | (Q8(r0.z) << 16) | (Q8(r0.w) << 24);
    uint32_t a1 = Q8(r1.x) | (Q8(r1.y) << 8) | (Q8(r1.z) << 16) | (Q8(r1.w) << 24);
    uint32_t b0 = Q8(i0.x) | (Q8(i0.y) << 8) | (Q8(i0.z) << 16) | (Q8(i0.w) << 24);
    uint32_t b1 = Q8(i1.x) | (Q8(i1.y) << 8) | (Q8(i1.z) << 16) | (Q8(i1.w) << 24);
#undef Q8
    *(uint32_t*)(qr + (size_t)tok * 2048 + t * 8)     = a0;
    *(uint32_t*)(qr + (size_t)tok * 2048 + t * 8 + 4) = a1;
    *(uint32_t*)(qi + (size_t)tok * 2048 + t * 8)     = b0;
    *(uint32_t*)(qi + (size_t)tok * 2048 + t * 8 + 4) = b1;
}

// ---------------------------------------------------------------------------
// Weight decode + transpose + fused mag reduction. (2 planes: sr, si)
// ---------------------------------------------------------------------------
__global__ __launch_bounds__(256)
void decode_kernel(const float* __restrict__ wr, const float* __restrict__ wi,
                   int N, int8_t* __restrict__ psr, int8_t* __restrict__ psi,
                   int n_off, float* __restrict__ mag_out)
{
    __shared__ alignas(16) int8_t tr[2][64][80];
    __shared__ float red[256];
    const int n0 = blockIdx.x * 64, k0 = blockIdx.y * 64;
    float msum = 0.f;
    for (int idx = threadIdx.x; idx < 4096; idx += 256) {
        int j = idx & 63, i = idx >> 6;                 // j = n, i = k
        size_t g = (size_t)(k0 + i) * N + n0 + j;
        float a = wr[g], b = wi[g];
        msum += sqrtf(a * a + b * b);
        int8_t sr, si;
        if (fabsf(a) >= fabsf(b)) {
            sr = (a > 0.f) ? 1 : ((a < 0.f) ? -1 : 0);
            si = 0;
        } else {
            sr = 0;
            si = (b > 0.f) ? 1 : ((b < 0.f) ? -1 : 0);
        }
        tr[0][j][i] = sr;
        tr[1][j][i] = si;
    }
    red[threadIdx.x] = msum;
    __syncthreads();
    for (int st = 128; st > 0; st >>= 1) {
        if (threadIdx.x < st) red[threadIdx.x] += red[threadIdx.x + st];
        __syncthreads();
    }
    if (threadIdx.x == 0) atomicAdd(mag_out, red[0]);
    int8_t* planes[2] = { psr, psi };
    for (int idx = threadIdx.x; idx < 512; idx += 256) {
        int p = idx >> 8, rem = idx & 255, n = rem >> 2, c = rem & 3;
        int4 v = *(const int4*)&tr[p][n][c * 16];
        *(int4*)(planes[p] + (size_t)(n_off + n0 + n) * 2048 + k0 + c * 16) = v;
    }
}

// ---------------------------------------------------------------------------
// int8 MFMA complex GEMM — DMA double-buffer pipeline, v3.
// Tile 64M x 128N, 256 threads (4 waves, 1M x 4N: each wave 64x32 out).
// 4 planes only (bnsi dropped): p2 = sum(xi*bsi) gets its own accumulator,
// re = p1 - p2 in the epilogue (exact int32). Saves 20% DMA bytes, 1/7 of
// ds_reads, 16 KB LDS/stage.
// Stage = 24 KB -> dbuf 48 KB -> 3 blocks/CU. MODE0 grid = 32x24 = 768 =
// 256 CU x 3 EXACT fill (r6: 384@1.5/CU left the machine ~1 block/CU).
// 6 DMA/wave/tile; vmcnt(6) = "tile k landed, k+1 in flight".
// ---------------------------------------------------------------------------
__device__ __forceinline__ void async_copy16(const void* g, void* l) {
    __builtin_amdgcn_global_load_lds((const __attribute__((address_space(1))) void*)g,
                                     (__attribute__((address_space(3))) void*)l, 16, 0, 0);
}

template <int MODE>
__global__ __launch_bounds__(256, 3)
void gemm_i8_kernel(const int8_t* __restrict__ axr, const int8_t* __restrict__ axi,
                    const int8_t* __restrict__ bsr, const int8_t* __restrict__ bsi,
                    int Nout, const float* __restrict__ invs,
                    const float* __restrict__ mag_sums,
                    float magc0, float magc1, float magc2,
                    float* o_re, float* o_im,
                    uint16_t* kbr, uint16_t* kbi, uint16_t* vbr, uint16_t* vbi)
{
    // Stage layout (bytes): A0 [c4][row64][16] @0, A1 @4096,
    //                       B0 [c4][row128][16] @8192, B1 @16384. 24 KB.
    __shared__ alignas(16) int8_t smem[2][24576];
    const int tid = threadIdx.x;
    const int wav = tid >> 6, lane = tid & 63;         // wav 0..3 = N-block
    const int tileM = blockIdx.y * 64, tileN = blockIdx.x * 128;
    const int K = 2048;

    i32x16 p1[2] = {};    // xr*bsr
    i32x16 p2[2] = {};    // xi*bsi
    i32x16 pim[2] = {};   // xr*bsi + xi*bsr

    auto issue_tile = [&](int k0, int buf) {
#pragma unroll
        for (int i = 0; i < 6; ++i) {
            int q = wav + 4 * i;            // 24 lds-dma per tile, 6 per wave
            const int8_t* g;
            int8_t* l;
            if (q < 8) {                    // A planes: 2 x 4 chunks x 64 rows
                int pl = q >> 2, c = q & 3;
                g = (pl ? axi : axr) + (size_t)(tileM + lane) * K + k0 + c * 16;
                l = &smem[buf][pl * 4096 + (c * 64 + lane) * 16];
            } else {                        // B planes: 2 x 4 chunks x 128 rows
                int r = q - 8;
                int pl = r >> 3, s = r & 7, c = s >> 1, m0 = (s & 1) << 6;
                g = (pl ? bsi : bsr) + (size_t)(tileN + m0 + lane) * K + k0 + c * 16;
                l = &smem[buf][8192 + pl * 8192 + (c * 128 + m0 + lane) * 16];
            }
            async_copy16(g, l);
        }
    };

    issue_tile(0, 0);
    issue_tile(64, 1);

    for (int k = 0; k < 32; ++k) {
        if (k == 31) { asm volatile("s_waitcnt vmcnt(0)" ::: "memory"); }
        else         { asm volatile("s_waitcnt vmcnt(6)" ::: "memory"); }
        asm volatile("s_barrier" ::: "memory");
        const int8_t* sb = smem[k & 1];
#pragma unroll
        for (int s = 0; s < 2; ++s) {
            const int cc = 2 * s + (lane >> 5);
            const int rA = lane & 31;
            const int rB = wav * 32 + (lane & 31);
            i32x4 fxr[2], fxi[2];
#pragma unroll
            for (int mb = 0; mb < 2; ++mb) {
                int off = (cc * 64 + rA + mb * 32) * 16;
                fxr[mb] = *(const i32x4*)&sb[off];
                fxi[mb] = *(const i32x4*)&sb[4096 + off];
            }
            i32x4 fbr, fbi;
            {
                int off = (cc * 128 + rB) * 16;
                fbr = *(const i32x4*)&sb[8192 + off];
                fbi = *(const i32x4*)&sb[16384 + off];
            }
#pragma unroll
            for (int mb = 0; mb < 2; ++mb) {
                p1[mb]  = __builtin_amdgcn_mfma_i32_32x32x32_i8(fxr[mb], fbr, p1[mb], 0, 0, 0);
                p2[mb]  = __builtin_amdgcn_mfma_i32_32x32x32_i8(fxi[mb], fbi, p2[mb], 0, 0, 0);
                pim[mb] = __builtin_amdgcn_mfma_i32_32x32x32_i8(fxr[mb], fbi, pim[mb], 0, 0, 0);
                pim[mb] = __builtin_amdgcn_mfma_i32_32x32x32_i8(fxi[mb], fbr, pim[mb], 0, 0, 0);
            }
        }
        asm volatile("s_barrier" ::: "memory");       // all reads of buf done
        if (k + 2 < 32) issue_tile((k + 2) * 64, k & 1);
    }

    const int ln31 = lane & 31, lq = lane >> 5;
    const int gn = tileN + wav * 32 + ln31;
    float mag;
    if (MODE == 0)
        mag = (gn < 2048) ? mag_sums[0] * magc0
            : (gn < 2560) ? mag_sums[1] * magc1
                          : mag_sums[2] * magc2;
    else
        mag = mag_sums[0] * magc0;
#pragma unroll
    for (int mb = 0; mb < 2; ++mb) {
#pragma unroll
        for (int r = 0; r < 16; ++r) {
            const int row = (r & 3) + 8 * (r >> 2) + 4 * lq;
            const int gm = tileM + mb * 32 + row;
            const float sc = mag * invs[gm];
            const float re = (float)(p1[mb][r] - p2[mb][r]) * sc;
            const float im = (float)pim[mb][r] * sc;
            if (MODE == 1) {
                o_re[(size_t)gm * Nout + gn] = re;
                o_im[(size_t)gm * Nout + gn] = im;
            } else {
                const int s = gm & (S_ - 1), bb = gm >> 10;
                if (gn < 2048) {
                    o_re[(size_t)gm * 2048 + gn] = re;
                    o_im[(size_t)gm * 2048 + gn] = im;
                } else if (gn < 2560) {
                    int c = gn - 2048, kvh = c >> 7, d = c & 127;
                    size_t off = ((size_t)(bb * KV_ + kvh) * S_ + s) * 128 + d;
                    kbr[off] = f2bf(re);
                    kbi[off] = f2bf(im);
                } else {
                    int c = gn - 2560, kvh = c >> 7, d = c & 127;
                    size_t off = ((size_t)(bb * KV_ + kvh) * S_ + s) * 128 + d;
                    vbr[off] = f2bf(re);
                    vbi[off] = f2bf(im);
                }
            }
        }
    }
}

// ---------------------------------------------------------------------------
// RoPE + bf16 convert + head-major rearrange for Q.
// ---------------------------------------------------------------------------
__global__ __launch_bounds__(256)
void rope_q_kernel(const float* __restrict__ q_re, const float* __restrict__ q_im,
                   uint16_t* __restrict__ qb_re, uint16_t* __restrict__ qb_im)
{
    int gidx = blockIdx.x * 256 + threadIdx.x;      // tok*256 + h*16 + j
    int j = gidx & 15, h = (gidx >> 4) & 15, tok = gidx >> 8;
    int s = tok & (S_ - 1), b = tok >> 10;
    int d0 = j * 4;
    size_t ib = (size_t)tok * 2048 + h * 128;
    float4 r0 = *(const float4*)&q_re[ib + d0];
    float4 r1 = *(const float4*)&q_re[ib + d0 + 64];
    float4 i0 = *(const float4*)&q_im[ib + d0];
    float4 i1 = *(const float4*)&q_im[ib + d0 + 64];
    float ro0[4], ro1[4];
    float rv0[4] = { r0.x, r0.y, r0.z, r0.w };
    float rv1[4] = { r1.x, r1.y, r1.z, r1.w };
#pragma unroll
    for (int t = 0; t < 4; ++t) {
        float f = __expf(-(float)(d0 + t) * LN1E4_OVER_64);
        float sn, c;
        __sincosf((float)s * f, &sn, &c);
        ro0[t] = rv0[t] * c - rv1[t] * sn;
        ro1[t] = rv1[t] * c + rv0[t] * sn;
    }
    size_t ob = ((size_t)(b * H_ + h) * S_ + s) * 128;
    ushort4 w;
    w = (ushort4){ f2bf(ro0[0]), f2bf(ro0[1]), f2bf(ro0[2]), f2bf(ro0[3]) };
    *(ushort4*)&qb_re[ob + d0] = w;
    w = (ushort4){ f2bf(ro1[0]), f2bf(ro1[1]), f2bf(ro1[2]), f2bf(ro1[3]) };
    *(ushort4*)&qb_re[ob + d0 + 64] = w;
    w = (ushort4){ f2bf(i0.x), f2bf(i0.y), f2bf(i0.z), f2bf(i0.w) };
    *(ushort4*)&qb_im[ob + d0] = w;
    w = (ushort4){ f2bf(i1.x), f2bf(i1.y), f2bf(i1.z), f2bf(i1.w) };
    *(ushort4*)&qb_im[ob + d0 + 64] = w;
}

// RoPE in place on K real bf16 plane [b][kv][s][128].
__global__ __launch_bounds__(256)
void rope_k_kernel(uint16_t* __restrict__ kb_re)
{
    int gidx = blockIdx.x * 256 + threadIdx.x;
    int j = gidx & 15, kvh = (gidx >> 4) & 3;
    int rest = gidx >> 6;
    int s = rest & (S_ - 1), b = rest >> 10;
    int d0 = j * 4;
    size_t base = ((size_t)(b * KV_ + kvh) * S_ + s) * 128;
    ushort4 u0 = *(const ushort4*)&kb_re[base + d0];
    ushort4 u1 = *(const ushort4*)&kb_re[base + d0 + 64];
    float rv0[4] = { bf2f(u0.x), bf2f(u0.y), bf2f(u0.z), bf2f(u0.w) };
    float rv1[4] = { bf2f(u1.x), bf2f(u1.y), bf2f(u1.z), bf2f(u1.w) };
    float ro0[4], ro1[4];
#pragma unroll
    for (int t = 0; t < 4; ++t) {
        float f = __expf(-(float)(d0 + t) * LN1E4_OVER_64);
        float sn, c;
        __sincosf((float)s * f, &sn, &c);
        ro0[t] = rv0[t] * c - rv1[t] * sn;
        ro1[t] = rv1[t] * c + rv0[t] * sn;
    }
    *(ushort4*)&kb_re[base + d0]      = (ushort4){ f2bf(ro0[0]), f2bf(ro0[1]), f2bf(ro0[2]), f2bf(ro0[3]) };
    *(ushort4*)&kb_re[base + d0 + 64] = (ushort4){ f2bf(ro1[0]), f2bf(ro1[1]), f2bf(ro1[2]), f2bf(ro1[3]) };
}

// ---------------------------------------------------------------------------
// V transpose: vb [bk][s][128] bf16 -> vt [bk][d][1024] bf16.
// ---------------------------------------------------------------------------
__global__ __launch_bounds__(256)
void vtrans_kernel(const uint16_t* __restrict__ vbr, const uint16_t* __restrict__ vbi,
                   uint16_t* __restrict__ vtr, uint16_t* __restrict__ vti)
{
    __shared__ uint16_t t[32][36];
    const int pl = blockIdx.z & 1, bk = blockIdx.z >> 1;
    const int s0 = blockIdx.x * 32, d0 = blockIdx.y * 32;
    const uint16_t* src = (pl ? vbi : vbr) + ((size_t)bk * S_) * 128;
    uint16_t*       dst = (pl ? vti : vtr) + ((size_t)bk * 128) * S_;
    const int r = threadIdx.x >> 3, c = (threadIdx.x & 7) * 4;
    *(ushort4*)&t[r][c] = *(const ushort4*)&src[(size_t)(s0 + r) * 128 + d0 + c];
    __syncthreads();
    ushort4 o = (ushort4){ t[c][r], t[c + 1][r], t[c + 2][r], t[c + 3][r] };
    *(ushort4*)&dst[(size_t)(d0 + r) * S_ + s0 + c] = o;
}

// ---------------------------------------------------------------------------
// MFMA flash attention (bf16, fp32 accum, online softmax in registers).
// v6: gemm-style DMA double-buffer pipeline (see r5 notes). Unchanged.
// ---------------------------------------------------------------------------
__global__ __launch_bounds__(256)
void attn_mfma_kernel(const uint16_t* __restrict__ qb_re, const uint16_t* __restrict__ qb_im,
                      const uint16_t* __restrict__ kb_re, const uint16_t* __restrict__ kb_im,
                      const uint16_t* __restrict__ vt_re, const uint16_t* __restrict__ vt_im,
                      float* __restrict__ o_re, float* __restrict__ o_im)
{
    __shared__ alignas(16) uint16_t sbuf[2][16384];   // 2 x 32KB: K [pl][ch16][row32]x8, V [pl][ch4][d128]x8
    __shared__ alignas(16) uint16_t sp[4][16][40];

    const int tid = threadIdx.x;
    const int w = tid >> 6, lane = tid & 63;
    const int r16 = lane & 15, q4 = lane >> 4;
    const int qt = gridDim.x - 1 - blockIdx.x;        // heavy blocks dispatch first
    const int h = blockIdx.y, b = blockIdx.z;
    const int kvh = h >> 2;
    const int q0 = qt * 64, qw0 = q0 + w * 16;

    bf16x8 qfr[4], qfi[4];
    {
        const size_t qbase = ((size_t)(b * H_ + h) * S_ + qw0 + r16) * 128;
#pragma unroll
        for (int ks = 0; ks < 4; ++ks) {
            const int col = ks * 32 + q4 * 8;
            qfr[ks] = *(const bf16x8*)&qb_re[qbase + col];
            qfi[ks] = *(const bf16x8*)&qb_im[qbase + col];
        }
    }

    f32x4 oa[2][8] = {};
    float m_r[4] = { -3e38f, -3e38f, -3e38f, -3e38f };
    float l_r[4] = { 0.f, 0.f, 0.f, 0.f };

    const size_t kgbase0 = (size_t)(b * KV_ + kvh) * S_ * 128;
    const uint16_t* vre = vt_re + (size_t)(b * KV_ + kvh) * 128 * (size_t)S_;
    const uint16_t* vim = vt_im + (size_t)(b * KV_ + kvh) * 128 * (size_t)S_;

    const uint16_t* kp[4];
    const uint16_t* vp[4];
#pragma unroll
    for (int i = 0; i < 4; ++i) {
        const int kch = (i & 1) * 8 + w * 2 + (lane >> 5);
        kp[i] = ((i >> 1) ? kb_im : kb_re) + kgbase0 + (size_t)(lane & 31) * 128 + kch * 8;
        const int vch = (i & 1) * 2 + (w >> 1);
        const int vd  = ((w & 1) << 6) | lane;
        vp[i] = ((i >> 1) ? vim : vre) + (size_t)vd * S_ + vch * 8;
    }

    auto issue_tile = [&](int kt, int buf) {
#pragma unroll
        for (int i = 0; i < 4; ++i)
            async_copy16(kp[i] + (size_t)kt * 4096, &sbuf[buf][w * 512 + i * 2048]);
#pragma unroll
        for (int i = 0; i < 4; ++i)
            async_copy16(vp[i] + (size_t)kt * 32, &sbuf[buf][8192 + w * 512 + i * 2048]);
    };

    const int nk = (q0 + 64) >> 5;                    // kv tiles of 32, nk >= 2

    issue_tile(0, 0);
    issue_tile(1, 1);

    for (int k = 0; k < nk; ++k) {
        if (k == nk - 1) { asm volatile("s_waitcnt vmcnt(0)" ::: "memory"); }
        else             { asm volatile("s_waitcnt vmcnt(8)" ::: "memory"); }
        asm volatile("s_barrier" ::: "memory");
        const uint16_t* sb = sbuf[k & 1];
        const int c0 = k << 5;

        if (c0 <= qw0 + 15) {
            f32x4 sc[2] = {};
#pragma unroll
            for (int cblk = 0; cblk < 2; ++cblk) {
                const int krow = cblk * 16 + r16;
#pragma unroll
                for (int ks = 0; ks < 4; ++ks) {
                    const int koff = (ks * 4 + q4) * 256 + krow * 8;
                    bf16x8 kr = *(const bf16x8*)&sb[koff];
                    bf16x8 ki = *(const bf16x8*)&sb[4096 + koff];
                    sc[cblk] = __builtin_amdgcn_mfma_f32_16x16x32_bf16(qfr[ks], kr, sc[cblk], 0, 0, 0);
                    sc[cblk] = __builtin_amdgcn_mfma_f32_16x16x32_bf16(qfi[ks], ki, sc[cblk], 0, 0, 0);
                }
            }
#pragma unroll
            for (int cblk = 0; cblk < 2; ++cblk)
#pragma unroll
                for (int reg = 0; reg < 4; ++reg) {
                    float sval = sc[cblk][reg] * 0.08838834764831845f;
                    const int rowg = qw0 + q4 * 4 + reg;
                    const int colg = c0 + cblk * 16 + r16;
                    if (colg > rowg) sval = -3e38f;
                    sc[cblk][reg] = sval;
                }
            float al[4];
#pragma unroll
            for (int reg = 0; reg < 4; ++reg) {
                float mx = fmaxf(sc[0][reg], sc[1][reg]);
#pragma unroll
                for (int msk = 1; msk < 16; msk <<= 1) mx = fmaxf(mx, __shfl_xor(mx, msk));
                const float mn = fmaxf(m_r[reg], mx);
                al[reg] = __expf(m_r[reg] - mn);
                const float p0 = __expf(sc[0][reg] - mn);
                const float p1 = __expf(sc[1][reg] - mn);
                sc[0][reg] = p0; sc[1][reg] = p1;
                float rs = p0 + p1;
#pragma unroll
                for (int msk = 1; msk < 16; msk <<= 1) rs += __shfl_xor(rs, msk);
                l_r[reg] = l_r[reg] * al[reg] + rs;
                m_r[reg] = mn;
            }
#pragma unroll
            for (int cblk = 0; cblk < 2; ++cblk)
#pragma unroll
                for (int reg = 0; reg < 4; ++reg)
                    sp[w][q4 * 4 + reg][cblk * 16 + r16] = f2bf(sc[cblk][reg]);
#pragma unroll
            for (int dblk = 0; dblk < 8; ++dblk)
#pragma unroll
                for (int reg = 0; reg < 4; ++reg) {
                    oa[0][dblk][reg] *= al[reg];
                    oa[1][dblk][reg] *= al[reg];
                }
            bf16x8 pf = *(const bf16x8*)&sp[w][r16][q4 * 8];
#pragma unroll
            for (int dblk = 0; dblk < 8; ++dblk) {
                const int voff = 8192 + q4 * 1024 + (dblk * 16 + r16) * 8;
                bf16x8 vr = *(const bf16x8*)&sb[voff];
                bf16x8 vi = *(const bf16x8*)&sb[4096 + voff];
                oa[0][dblk] = __builtin_amdgcn_mfma_f32_16x16x32_bf16(pf, vr, oa[0][dblk], 0, 0, 0);
                oa[1][dblk] = __builtin_amdgcn_mfma_f32_16x16x32_bf16(pf, vi, oa[1][dblk], 0, 0, 0);
            }
        }

        asm volatile("s_barrier" ::: "memory");       // all reads of buf done
        if (k + 2 < nk) issue_tile(k + 2, k & 1);
    }

    float inv[4];
#pragma unroll
    for (int reg = 0; reg < 4; ++reg) inv[reg] = 1.f / l_r[reg];
#pragma unroll
    for (int dblk = 0; dblk < 8; ++dblk) {
        const int col = h * 128 + dblk * 16 + r16;
#pragma unroll
        for (int reg = 0; reg < 4; ++reg) {
            const size_t tok = (size_t)b * S_ + qw0 + q4 * 4 + reg;
            o_re[tok * 2048 + col] = oa[0][dblk][reg] * inv[reg];
            o_im[tok * 2048 + col] = oa[1][dblk][reg] * inv[reg];
        }
    }
}

// ---------------------------------------------------------------------------
extern "C" void kernel_launch(void* const* d_in, const int* in_sizes, int n_in,
                              void* d_out, int out_size, void* d_ws, size_t ws_size,
                              hipStream_t stream)
{
    const float* hr    = (const float*)d_in[0];
    const float* hi    = (const float*)d_in[1];
    const float* wq_re = (const float*)d_in[2];
    const float* wq_im = (const float*)d_in[3];
    const float* wk_re = (const float*)d_in[4];
    const float* wk_im = (const float*)d_in[5];
    const float* wv_re = (const float*)d_in[6];
    const float* wv_im = (const float*)d_in[7];
    const float* wo_re = (const float*)d_in[8];
    const float* wo_im = (const float*)d_in[9];
    float* out = (float*)d_out;
    char*  base = (char*)d_ws;

    const size_t MB4  = (size_t)2048 * 2048;
    const size_t QKVP = (size_t)3072 * 2048;
    const size_t KVE  = (size_t)B_ * KV_ * S_ * 128;

    float*   mags   = (float*)(base);
    float*   invs1  = (float*)(base + 1024);
    float*   invs2  = (float*)(base + 9216);
    int8_t*  xr_q   = (int8_t*)(base + 32768);
    int8_t*  xi_q   = xr_q + MB4;
    int8_t*  qkv_sr = xi_q + MB4;
    int8_t*  qkv_si = qkv_sr + QKVP;
    int8_t*  qkv_ns = qkv_si + QKVP;     // (unused in v3 — bnsi plane dropped)
    int8_t*  wo_sr  = qkv_ns + QKVP;
    int8_t*  wo_si  = wo_sr + MB4;
    int8_t*  wo_ns  = wo_si + MB4;       // (unused)
    float*   q_re   = (float*)(wo_ns + MB4);
    float*   q_im   = q_re + MB4;
    uint16_t* kb_re = (uint16_t*)(q_im + MB4);
    uint16_t* kb_im = kb_re + KVE;
    uint16_t* vb_re = kb_im + KVE;
    uint16_t* vb_im = vb_re + KVE;
    uint16_t* vt_re = (uint16_t*)xr_q;
    uint16_t* vt_im = (uint16_t*)xi_q;
    uint16_t* qb_re = (uint16_t*)qkv_sr;
    uint16_t* qb_im = (uint16_t*)(qkv_sr + 8388608);

    hipMemsetAsync(mags, 0, 16, stream);

    decode_kernel<<<dim3(32, 32), 256, 0, stream>>>(wq_re, wq_im, 2048, qkv_sr, qkv_si, 0,    mags + 0);
    decode_kernel<<<dim3(8, 32),  256, 0, stream>>>(wk_re, wk_im, 512,  qkv_sr, qkv_si, 2048, mags + 1);
    decode_kernel<<<dim3(8, 32),  256, 0, stream>>>(wv_re, wv_im, 512,  qkv_sr, qkv_si, 2560, mags + 2);
    decode_kernel<<<dim3(32, 32), 256, 0, stream>>>(wo_re, wo_im, 2048, wo_sr, wo_si, 0,      mags + 3);

    act_quant_i8_kernel<<<NTOK, 256, 0, stream>>>(hr, hi, xr_q, xi_q, invs1);

    gemm_i8_kernel<0><<<dim3(24, 32), 256, 0, stream>>>(
        xr_q, xi_q, qkv_sr, qkv_si, 0, invs1, mags,
        1.0f / (float)((size_t)D_ * QD), 1.0f / (float)((size_t)D_ * KD), 1.0f / (float)((size_t)D_ * KD),
        q_re, q_im, kb_re, kb_im, vb_re, vb_im);

    rope_q_kernel<<<NTOK * H_ * 16 / 256, 256, 0, stream>>>(q_re, q_im, qb_re, qb_im);
    rope_k_kernel<<<NTOK * KV_ * 16 / 256, 256, 0, stream>>>(kb_re);
    vtrans_kernel<<<dim3(S_ / 32, 128 / 32, B_ * KV_ * 2), 256, 0, stream>>>(vb_re, vb_im, vt_re, vt_im);

    attn_mfma_kernel<<<dim3(S_ / 64, H_, B_), 256, 0, stream>>>(
        qb_re, qb_im, kb_re, kb_im, vt_re, vt_im, q_re, q_im);

    act_quant_i8_kernel<<<NTOK, 256, 0, stream>>>(q_re, q_im, xr_q, xi_q, invs2);

    gemm_i8_kernel<1><<<dim3(16, 32), 256, 0, stream>>>(
        xr_q, xi_q, wo_sr, wo_si, 2048, invs2, mags + 3,
        1.0f / (float)((size_t)QD * D_), 0.f, 0.f,
        out, out + MB4, nullptr, nullptr, nullptr, nullptr);
}

// Round 8
// 467.235 us; speedup vs baseline: 1.2312x; 1.0054x over previous
//
#include <hip/hip_runtime.h>
#include <stdint.h>

#define B_   2
#define S_   1024
#define D_   2048
#define H_   16
#define KV_  4
#define HD_  128
#define NTOK (B_ * S_)        /* 2048 tokens */
#define QD   (H_ * HD_)       /* 2048 */
#define KD   (KV_ * HD_)      /* 512  */

using i32x4  = __attribute__((ext_vector_type(4)))  int;
using i32x16 = __attribute__((ext_vector_type(16))) int;
using f32x4  = __attribute__((ext_vector_type(4)))  float;
using bf16x8 = __attribute__((ext_vector_type(8)))  short;

#define LN1E4_OVER_64 0.14391156831212725f

// ---------------- bf16 helpers ---------------------------------------------
__device__ __forceinline__ float bf2f(uint16_t u) { return __uint_as_float((uint32_t)u << 16); }
__device__ __forceinline__ uint16_t f2bf(float f) {
    uint32_t u = __float_as_uint(f);
    return (uint16_t)((u + 0x7FFFu + ((u >> 16) & 1u)) >> 16);   // RNE
}

// ---------------------------------------------------------------------------
// Per-token joint absmax int8 quantization (dim = 2048 fixed).
// ---------------------------------------------------------------------------
__global__ __launch_bounds__(256)
void act_quant_i8_kernel(const float* __restrict__ xr, const float* __restrict__ xi,
                         int8_t* __restrict__ qr, int8_t* __restrict__ qi,
                         float* __restrict__ invs)
{
    const int tok = blockIdx.x, t = threadIdx.x;
    const float* pr = xr + (size_t)tok * 2048 + t * 8;
    const float* pi = xi + (size_t)tok * 2048 + t * 8;
    float4 r0 = *(const float4*)pr, r1 = *(const float4*)(pr + 4);
    float4 i0 = *(const float4*)pi, i1 = *(const float4*)(pi + 4);
    float am = fmaxf(fmaxf(fmaxf(fabsf(r0.x), fabsf(r0.y)), fmaxf(fabsf(r0.z), fabsf(r0.w))),
                     fmaxf(fmaxf(fabsf(r1.x), fabsf(r1.y)), fmaxf(fabsf(r1.z), fabsf(r1.w))));
    am = fmaxf(am, fmaxf(fmaxf(fmaxf(fabsf(i0.x), fabsf(i0.y)), fmaxf(fabsf(i0.z), fabsf(i0.w))),
                         fmaxf(fmaxf(fabsf(i1.x), fabsf(i1.y)), fmaxf(fabsf(i1.z), fabsf(i1.w)))));
    __shared__ float red[256];
    red[t] = am;
    __syncthreads();
    for (int st = 128; st > 0; st >>= 1) {
        if (t < st) red[t] = fmaxf(red[t], red[t + st]);
        __syncthreads();
    }
    const float s = 127.0f / fmaxf(red[0], 1e-5f);
    if (t == 0) invs[tok] = 1.0f / s;
#define Q8(x) ((uint32_t)(uint8_t)(int8_t)(int)fminf(fmaxf(rintf((x) * s), -128.f), 127.f))
    uint32_t a0 = Q8(r0.x) | (Q8(r0.y) << 8) | (Q8(r0.z) << 16) | (Q8(r0.w) << 24);
    uint32_t a1 = Q8(r1.x) | (Q8(r1.y) << 8) | (Q8(r1.z) << 16) | (Q8(r1.w) << 24);
    uint32_t b0 = Q8(i0.x) | (Q8(i0.y) << 8) | (Q8(i0.z) << 16) | (Q8(i0.w) << 24);
    uint32_t b1 = Q8(i1.x) | (Q8(i1.y) << 8) | (Q8(i1.z) << 16) | (Q8(i1.w) << 24);
#undef Q8
    *(uint32_t*)(qr + (size_t)tok * 2048 + t * 8)     = a0;
    *(uint32_t*)(qr + (size_t)tok * 2048 + t * 8 + 4) = a1;
    *(uint32_t*)(qi + (size_t)tok * 2048 + t * 8)     = b0;
    *(uint32_t*)(qi + (size_t)tok * 2048 + t * 8 + 4) = b1;
}

// ---------------------------------------------------------------------------
// Weight decode + transpose + fused mag reduction. (2 planes: sr, si)
// ---------------------------------------------------------------------------
__global__ __launch_bounds__(256)
void decode_kernel(const float* __restrict__ wr, const float* __restrict__ wi,
                   int N, int8_t* __restrict__ psr, int8_t* __restrict__ psi,
                   int n_off, float* __restrict__ mag_out)
{
    __shared__ alignas(16) int8_t tr[2][64][80];
    __shared__ float red[256];
    const int n0 = blockIdx.x * 64, k0 = blockIdx.y * 64;
    float msum = 0.f;
    for (int idx = threadIdx.x; idx < 4096; idx += 256) {
        int j = idx & 63, i = idx >> 6;                 // j = n, i = k
        size_t g = (size_t)(k0 + i) * N + n0 + j;
        float a = wr[g], b = wi[g];
        msum += sqrtf(a * a + b * b);
        int8_t sr, si;
        if (fabsf(a) >= fabsf(b)) {
            sr = (a > 0.f) ? 1 : ((a < 0.f) ? -1 : 0);
            si = 0;
        } else {
            sr = 0;
            si = (b > 0.f) ? 1 : ((b < 0.f) ? -1 : 0);
        }
        tr[0][j][i] = sr;
        tr[1][j][i] = si;
    }
    red[threadIdx.x] = msum;
    __syncthreads();
    for (int st = 128; st > 0; st >>= 1) {
        if (threadIdx.x < st) red[threadIdx.x] += red[threadIdx.x + st];
        __syncthreads();
    }
    if (threadIdx.x == 0) atomicAdd(mag_out, red[0]);
    int8_t* planes[2] = { psr, psi };
    for (int idx = threadIdx.x; idx < 512; idx += 256) {
        int p = idx >> 8, rem = idx & 255, n = rem >> 2, c = rem & 3;
        int4 v = *(const int4*)&tr[p][n][c * 16];
        *(int4*)(planes[p] + (size_t)(n_off + n0 + n) * 2048 + k0 + c * 16) = v;
    }
}

// ---------------------------------------------------------------------------
// int8 MFMA complex GEMM — DMA double-buffer pipeline, v3 (see r6 notes).
// ---------------------------------------------------------------------------
__device__ __forceinline__ void async_copy16(const void* g, void* l) {
    __builtin_amdgcn_global_load_lds((const __attribute__((address_space(1))) void*)g,
                                     (__attribute__((address_space(3))) void*)l, 16, 0, 0);
}

template <int MODE>
__global__ __launch_bounds__(256, 3)
void gemm_i8_kernel(const int8_t* __restrict__ axr, const int8_t* __restrict__ axi,
                    const int8_t* __restrict__ bsr, const int8_t* __restrict__ bsi,
                    int Nout, const float* __restrict__ invs,
                    const float* __restrict__ mag_sums,
                    float magc0, float magc1, float magc2,
                    float* o_re, float* o_im,
                    uint16_t* kbr, uint16_t* kbi, uint16_t* vbr, uint16_t* vbi)
{
    // Stage layout (bytes): A0 [c4][row64][16] @0, A1 @4096,
    //                       B0 [c4][row128][16] @8192, B1 @16384. 24 KB.
    __shared__ alignas(16) int8_t smem[2][24576];
    const int tid = threadIdx.x;
    const int wav = tid >> 6, lane = tid & 63;         // wav 0..3 = N-block
    const int tileM = blockIdx.y * 64, tileN = blockIdx.x * 128;
    const int K = 2048;

    i32x16 p1[2] = {};    // xr*bsr
    i32x16 p2[2] = {};    // xi*bsi
    i32x16 pim[2] = {};   // xr*bsi + xi*bsr

    auto issue_tile = [&](int k0, int buf) {
#pragma unroll
        for (int i = 0; i < 6; ++i) {
            int q = wav + 4 * i;            // 24 lds-dma per tile, 6 per wave
            const int8_t* g;
            int8_t* l;
            if (q < 8) {                    // A planes: 2 x 4 chunks x 64 rows
                int pl = q >> 2, c = q & 3;
                g = (pl ? axi : axr) + (size_t)(tileM + lane) * K + k0 + c * 16;
                l = &smem[buf][pl * 4096 + (c * 64 + lane) * 16];
            } else {                        // B planes: 2 x 4 chunks x 128 rows
                int r = q - 8;
                int pl = r >> 3, s = r & 7, c = s >> 1, m0 = (s & 1) << 6;
                g = (pl ? bsi : bsr) + (size_t)(tileN + m0 + lane) * K + k0 + c * 16;
                l = &smem[buf][8192 + pl * 8192 + (c * 128 + m0 + lane) * 16];
            }
            async_copy16(g, l);
        }
    };

    issue_tile(0, 0);
    issue_tile(64, 1);

    for (int k = 0; k < 32; ++k) {
        if (k == 31) { asm volatile("s_waitcnt vmcnt(0)" ::: "memory"); }
        else         { asm volatile("s_waitcnt vmcnt(6)" ::: "memory"); }
        asm volatile("s_barrier" ::: "memory");
        const int8_t* sb = smem[k & 1];
#pragma unroll
        for (int s = 0; s < 2; ++s) {
            const int cc = 2 * s + (lane >> 5);
            const int rA = lane & 31;
            const int rB = wav * 32 + (lane & 31);
            i32x4 fxr[2], fxi[2];
#pragma unroll
            for (int mb = 0; mb < 2; ++mb) {
                int off = (cc * 64 + rA + mb * 32) * 16;
                fxr[mb] = *(const i32x4*)&sb[off];
                fxi[mb] = *(const i32x4*)&sb[4096 + off];
            }
            i32x4 fbr, fbi;
            {
                int off = (cc * 128 + rB) * 16;
                fbr = *(const i32x4*)&sb[8192 + off];
                fbi = *(const i32x4*)&sb[16384 + off];
            }
#pragma unroll
            for (int mb = 0; mb < 2; ++mb) {
                p1[mb]  = __builtin_amdgcn_mfma_i32_32x32x32_i8(fxr[mb], fbr, p1[mb], 0, 0, 0);
                p2[mb]  = __builtin_amdgcn_mfma_i32_32x32x32_i8(fxi[mb], fbi, p2[mb], 0, 0, 0);
                pim[mb] = __builtin_amdgcn_mfma_i32_32x32x32_i8(fxr[mb], fbi, pim[mb], 0, 0, 0);
                pim[mb] = __builtin_amdgcn_mfma_i32_32x32x32_i8(fxi[mb], fbr, pim[mb], 0, 0, 0);
            }
        }
        asm volatile("s_barrier" ::: "memory");       // all reads of buf done
        if (k + 2 < 32) issue_tile((k + 2) * 64, k & 1);
    }

    const int ln31 = lane & 31, lq = lane >> 5;
    const int gn = tileN + wav * 32 + ln31;
    float mag;
    if (MODE == 0)
        mag = (gn < 2048) ? mag_sums[0] * magc0
            : (gn < 2560) ? mag_sums[1] * magc1
                          : mag_sums[2] * magc2;
    else
        mag = mag_sums[0] * magc0;
#pragma unroll
    for (int mb = 0; mb < 2; ++mb) {
#pragma unroll
        for (int r = 0; r < 16; ++r) {
            const int row = (r & 3) + 8 * (r >> 2) + 4 * lq;
            const int gm = tileM + mb * 32 + row;
            const float sc = mag * invs[gm];
            const float re = (float)(p1[mb][r] - p2[mb][r]) * sc;
            const float im = (float)pim[mb][r] * sc;
            if (MODE == 1) {
                o_re[(size_t)gm * Nout + gn] = re;
                o_im[(size_t)gm * Nout + gn] = im;
            } else {
                const int s = gm & (S_ - 1), bb = gm >> 10;
                if (gn < 2048) {
                    o_re[(size_t)gm * 2048 + gn] = re;
                    o_im[(size_t)gm * 2048 + gn] = im;
                } else if (gn < 2560) {
                    int c = gn - 2048, kvh = c >> 7, d = c & 127;
                    size_t off = ((size_t)(bb * KV_ + kvh) * S_ + s) * 128 + d;
                    kbr[off] = f2bf(re);
                    kbi[off] = f2bf(im);
                } else {
                    int c = gn - 2560, kvh = c >> 7, d = c & 127;
                    size_t off = ((size_t)(bb * KV_ + kvh) * S_ + s) * 128 + d;
                    vbr[off] = f2bf(re);
                    vbi[off] = f2bf(im);
                }
            }
        }
    }
}

// ---------------------------------------------------------------------------
// RoPE + bf16 convert + head-major rearrange for Q.
// ---------------------------------------------------------------------------
__global__ __launch_bounds__(256)
void rope_q_kernel(const float* __restrict__ q_re, const float* __restrict__ q_im,
                   uint16_t* __restrict__ qb_re, uint16_t* __restrict__ qb_im)
{
    int gidx = blockIdx.x * 256 + threadIdx.x;      // tok*256 + h*16 + j
    int j = gidx & 15, h = (gidx >> 4) & 15, tok = gidx >> 8;
    int s = tok & (S_ - 1), b = tok >> 10;
    int d0 = j * 4;
    size_t ib = (size_t)tok * 2048 + h * 128;
    float4 r0 = *(const float4*)&q_re[ib + d0];
    float4 r1 = *(const float4*)&q_re[ib + d0 + 64];
    float4 i0 = *(const float4*)&q_im[ib + d0];
    float4 i1 = *(const float4*)&q_im[ib + d0 + 64];
    float ro0[4], ro1[4];
    float rv0[4] = { r0.x, r0.y, r0.z, r0.w };
    float rv1[4] = { r1.x, r1.y, r1.z, r1.w };
#pragma unroll
    for (int t = 0; t < 4; ++t) {
        float f = __expf(-(float)(d0 + t) * LN1E4_OVER_64);
        float sn, c;
        __sincosf((float)s * f, &sn, &c);
        ro0[t] = rv0[t] * c - rv1[t] * sn;
        ro1[t] = rv1[t] * c + rv0[t] * sn;
    }
    size_t ob = ((size_t)(b * H_ + h) * S_ + s) * 128;
    ushort4 w;
    w = (ushort4){ f2bf(ro0[0]), f2bf(ro0[1]), f2bf(ro0[2]), f2bf(ro0[3]) };
    *(ushort4*)&qb_re[ob + d0] = w;
    w = (ushort4){ f2bf(ro1[0]), f2bf(ro1[1]), f2bf(ro1[2]), f2bf(ro1[3]) };
    *(ushort4*)&qb_re[ob + d0 + 64] = w;
    w = (ushort4){ f2bf(i0.x), f2bf(i0.y), f2bf(i0.z), f2bf(i0.w) };
    *(ushort4*)&qb_im[ob + d0] = w;
    w = (ushort4){ f2bf(i1.x), f2bf(i1.y), f2bf(i1.z), f2bf(i1.w) };
    *(ushort4*)&qb_im[ob + d0 + 64] = w;
}

// RoPE in place on K real bf16 plane [b][kv][s][128].
__global__ __launch_bounds__(256)
void rope_k_kernel(uint16_t* __restrict__ kb_re)
{
    int gidx = blockIdx.x * 256 + threadIdx.x;
    int j = gidx & 15, kvh = (gidx >> 4) & 3;
    int rest = gidx >> 6;
    int s = rest & (S_ - 1), b = rest >> 10;
    int d0 = j * 4;
    size_t base = ((size_t)(b * KV_ + kvh) * S_ + s) * 128;
    ushort4 u0 = *(const ushort4*)&kb_re[base + d0];
    ushort4 u1 = *(const ushort4*)&kb_re[base + d0 + 64];
    float rv0[4] = { bf2f(u0.x), bf2f(u0.y), bf2f(u0.z), bf2f(u0.w) };
    float rv1[4] = { bf2f(u1.x), bf2f(u1.y), bf2f(u1.z), bf2f(u1.w) };
    float ro0[4], ro1[4];
#pragma unroll
    for (int t = 0; t < 4; ++t) {
        float f = __expf(-(float)(d0 + t) * LN1E4_OVER_64);
        float sn, c;
        __sincosf((float)s * f, &sn, &c);
        ro0[t] = rv0[t] * c - rv1[t] * sn;
        ro1[t] = rv1[t] * c + rv0[t] * sn;
    }
    *(ushort4*)&kb_re[base + d0]      = (ushort4){ f2bf(ro0[0]), f2bf(ro0[1]), f2bf(ro0[2]), f2bf(ro0[3]) };
    *(ushort4*)&kb_re[base + d0 + 64] = (ushort4){ f2bf(ro1[0]), f2bf(ro1[1]), f2bf(ro1[2]), f2bf(ro1[3]) };
}

// ---------------------------------------------------------------------------
// V transpose: vb [bk][s][128] bf16 -> vt [bk][d][1024] bf16.
// ---------------------------------------------------------------------------
__global__ __launch_bounds__(256)
void vtrans_kernel(const uint16_t* __restrict__ vbr, const uint16_t* __restrict__ vbi,
                   uint16_t* __restrict__ vtr, uint16_t* __restrict__ vti)
{
    __shared__ uint16_t t[32][36];
    const int pl = blockIdx.z & 1, bk = blockIdx.z >> 1;
    const int s0 = blockIdx.x * 32, d0 = blockIdx.y * 32;
    const uint16_t* src = (pl ? vbi : vbr) + ((size_t)bk * S_) * 128;
    uint16_t*       dst = (pl ? vti : vtr) + ((size_t)bk * 128) * S_;
    const int r = threadIdx.x >> 3, c = (threadIdx.x & 7) * 4;
    *(ushort4*)&t[r][c] = *(const ushort4*)&src[(size_t)(s0 + r) * 128 + d0 + c];
    __syncthreads();
    ushort4 o = (ushort4){ t[c][r], t[c + 1][r], t[c + 2][r], t[c + 3][r] };
    *(ushort4*)&dst[(size_t)(d0 + r) * S_ + s0 + c] = o;
}

// ---------------------------------------------------------------------------
// MFMA flash attention (bf16, fp32 accum, online softmax in registers).
// v7: DMA pipeline (r5) + anti-correlated qt pairing. Round-robin dispatch
// puts blocks i and i+256 on the same CU; they differ only in z (batch).
// qt = z ? x : 15-x makes each CU's pair (qt, 15-qt): per-CU kv-iteration
// total = 2(16-x) + 2(x+1) = 34 = UNIFORM (was 64 worst-case when both
// co-resident blocks had the same qt — r7 counters: Occ 11.3% of 25%
// static = drain-idle imbalance signature).
// ---------------------------------------------------------------------------
__global__ __launch_bounds__(256)
void attn_mfma_kernel(const uint16_t* __restrict__ qb_re, const uint16_t* __restrict__ qb_im,
                      const uint16_t* __restrict__ kb_re, const uint16_t* __restrict__ kb_im,
                      const uint16_t* __restrict__ vt_re, const uint16_t* __restrict__ vt_im,
                      float* __restrict__ o_re, float* __restrict__ o_im)
{
    __shared__ alignas(16) uint16_t sbuf[2][16384];   // 2 x 32KB: K [pl][ch16][row32]x8, V [pl][ch4][d128]x8
    __shared__ alignas(16) uint16_t sp[4][16][40];

    const int tid = threadIdx.x;
    const int w = tid >> 6, lane = tid & 63;
    const int r16 = lane & 15, q4 = lane >> 4;
    const int h = blockIdx.y, b = blockIdx.z;
    // Anti-correlated qt across the batch axis: co-resident blocks (same
    // x,y; z=0/1) get complementary work (34 kv-iters total per CU).
    const int qt = b ? blockIdx.x : (gridDim.x - 1 - blockIdx.x);
    const int kvh = h >> 2;
    const int q0 = qt * 64, qw0 = q0 + w * 16;

    bf16x8 qfr[4], qfi[4];
    {
        const size_t qbase = ((size_t)(b * H_ + h) * S_ + qw0 + r16) * 128;
#pragma unroll
        for (int ks = 0; ks < 4; ++ks) {
            const int col = ks * 32 + q4 * 8;
            qfr[ks] = *(const bf16x8*)&qb_re[qbase + col];
            qfi[ks] = *(const bf16x8*)&qb_im[qbase + col];
        }
    }

    f32x4 oa[2][8] = {};
    float m_r[4] = { -3e38f, -3e38f, -3e38f, -3e38f };
    float l_r[4] = { 0.f, 0.f, 0.f, 0.f };

    const size_t kgbase0 = (size_t)(b * KV_ + kvh) * S_ * 128;
    const uint16_t* vre = vt_re + (size_t)(b * KV_ + kvh) * 128 * (size_t)S_;
    const uint16_t* vim = vt_im + (size_t)(b * KV_ + kvh) * 128 * (size_t)S_;

    const uint16_t* kp[4];
    const uint16_t* vp[4];
#pragma unroll
    for (int i = 0; i < 4; ++i) {
        const int kch = (i & 1) * 8 + w * 2 + (lane >> 5);
        kp[i] = ((i >> 1) ? kb_im : kb_re) + kgbase0 + (size_t)(lane & 31) * 128 + kch * 8;
        const int vch = (i & 1) * 2 + (w >> 1);
        const int vd  = ((w & 1) << 6) | lane;
        vp[i] = ((i >> 1) ? vim : vre) + (size_t)vd * S_ + vch * 8;
    }

    auto issue_tile = [&](int kt, int buf) {
#pragma unroll
        for (int i = 0; i < 4; ++i)
            async_copy16(kp[i] + (size_t)kt * 4096, &sbuf[buf][w * 512 + i * 2048]);
#pragma unroll
        for (int i = 0; i < 4; ++i)
            async_copy16(vp[i] + (size_t)kt * 32, &sbuf[buf][8192 + w * 512 + i * 2048]);
    };

    const int nk = (q0 + 64) >> 5;                    // kv tiles of 32, nk >= 2

    issue_tile(0, 0);
    issue_tile(1, 1);

    for (int k = 0; k < nk; ++k) {
        if (k == nk - 1) { asm volatile("s_waitcnt vmcnt(0)" ::: "memory"); }
        else             { asm volatile("s_waitcnt vmcnt(8)" ::: "memory"); }
        asm volatile("s_barrier" ::: "memory");
        const uint16_t* sb = sbuf[k & 1];
        const int c0 = k << 5;

        if (c0 <= qw0 + 15) {
            f32x4 sc[2] = {};
#pragma unroll
            for (int cblk = 0; cblk < 2; ++cblk) {
                const int krow = cblk * 16 + r16;
#pragma unroll
                for (int ks = 0; ks < 4; ++ks) {
                    const int koff = (ks * 4 + q4) * 256 + krow * 8;
                    bf16x8 kr = *(const bf16x8*)&sb[koff];
                    bf16x8 ki = *(const bf16x8*)&sb[4096 + koff];
                    sc[cblk] = __builtin_amdgcn_mfma_f32_16x16x32_bf16(qfr[ks], kr, sc[cblk], 0, 0, 0);
                    sc[cblk] = __builtin_amdgcn_mfma_f32_16x16x32_bf16(qfi[ks], ki, sc[cblk], 0, 0, 0);
                }
            }
#pragma unroll
            for (int cblk = 0; cblk < 2; ++cblk)
#pragma unroll
                for (int reg = 0; reg < 4; ++reg) {
                    float sval = sc[cblk][reg] * 0.08838834764831845f;
                    const int rowg = qw0 + q4 * 4 + reg;
                    const int colg = c0 + cblk * 16 + r16;
                    if (colg > rowg) sval = -3e38f;
                    sc[cblk][reg] = sval;
                }
            float al[4];
#pragma unroll
            for (int reg = 0; reg < 4; ++reg) {
                float mx = fmaxf(sc[0][reg], sc[1][reg]);
#pragma unroll
                for (int msk = 1; msk < 16; msk <<= 1) mx = fmaxf(mx, __shfl_xor(mx, msk));
                const float mn = fmaxf(m_r[reg], mx);
                al[reg] = __expf(m_r[reg] - mn);
                const float p0 = __expf(sc[0][reg] - mn);
                const float p1 = __expf(sc[1][reg] - mn);
                sc[0][reg] = p0; sc[1][reg] = p1;
                float rs = p0 + p1;
#pragma unroll
                for (int msk = 1; msk < 16; msk <<= 1) rs += __shfl_xor(rs, msk);
                l_r[reg] = l_r[reg] * al[reg] + rs;
                m_r[reg] = mn;
            }
#pragma unroll
            for (int cblk = 0; cblk < 2; ++cblk)
#pragma unroll
                for (int reg = 0; reg < 4; ++reg)
                    sp[w][q4 * 4 + reg][cblk * 16 + r16] = f2bf(sc[cblk][reg]);
#pragma unroll
            for (int dblk = 0; dblk < 8; ++dblk)
#pragma unroll
                for (int reg = 0; reg < 4; ++reg) {
                    oa[0][dblk][reg] *= al[reg];
                    oa[1][dblk][reg] *= al[reg];
                }
            bf16x8 pf = *(const bf16x8*)&sp[w][r16][q4 * 8];
#pragma unroll
            for (int dblk = 0; dblk < 8; ++dblk) {
                const int voff = 8192 + q4 * 1024 + (dblk * 16 + r16) * 8;
                bf16x8 vr = *(const bf16x8*)&sb[voff];
                bf16x8 vi = *(const bf16x8*)&sb[4096 + voff];
                oa[0][dblk] = __builtin_amdgcn_mfma_f32_16x16x32_bf16(pf, vr, oa[0][dblk], 0, 0, 0);
                oa[1][dblk] = __builtin_amdgcn_mfma_f32_16x16x32_bf16(pf, vi, oa[1][dblk], 0, 0, 0);
            }
        }

        asm volatile("s_barrier" ::: "memory");       // all reads of buf done
        if (k + 2 < nk) issue_tile(k + 2, k & 1);
    }

    float inv[4];
#pragma unroll
    for (int reg = 0; reg < 4; ++reg) inv[reg] = 1.f / l_r[reg];
#pragma unroll
    for (int dblk = 0; dblk < 8; ++dblk) {
        const int col = h * 128 + dblk * 16 + r16;
#pragma unroll
        for (int reg = 0; reg < 4; ++reg) {
            const size_t tok = (size_t)b * S_ + qw0 + q4 * 4 + reg;
            o_re[tok * 2048 + col] = oa[0][dblk][reg] * inv[reg];
            o_im[tok * 2048 + col] = oa[1][dblk][reg] * inv[reg];
        }
    }
}

// ---------------------------------------------------------------------------
extern "C" void kernel_launch(void* const* d_in, const int* in_sizes, int n_in,
                              void* d_out, int out_size, void* d_ws, size_t ws_size,
                              hipStream_t stream)
{
    const float* hr    = (const float*)d_in[0];
    const float* hi    = (const float*)d_in[1];
    const float* wq_re = (const float*)d_in[2];
    const float* wq_im = (const float*)d_in[3];
    const float* wk_re = (const float*)d_in[4];
    const float* wk_im = (const float*)d_in[5];
    const float* wv_re = (const float*)d_in[6];
    const float* wv_im = (const float*)d_in[7];
    const float* wo_re = (const float*)d_in[8];
    const float* wo_im = (const float*)d_in[9];
    float* out = (float*)d_out;
    char*  base = (char*)d_ws;

    const size_t MB4  = (size_t)2048 * 2048;
    const size_t QKVP = (size_t)3072 * 2048;
    const size_t KVE  = (size_t)B_ * KV_ * S_ * 128;

    float*   mags   = (float*)(base);
    float*   invs1  = (float*)(base + 1024);
    float*   invs2  = (float*)(base + 9216);
    int8_t*  xr_q   = (int8_t*)(base + 32768);
    int8_t*  xi_q   = xr_q + MB4;
    int8_t*  qkv_sr = xi_q + MB4;
    int8_t*  qkv_si = qkv_sr + QKVP;
    int8_t*  qkv_ns = qkv_si + QKVP;     // (unused in v3 — bnsi plane dropped)
    int8_t*  wo_sr  = qkv_ns + QKVP;
    int8_t*  wo_si  = wo_sr + MB4;
    int8_t*  wo_ns  = wo_si + MB4;       // (unused)
    float*   q_re   = (float*)(wo_ns + MB4);
    float*   q_im   = q_re + MB4;
    uint16_t* kb_re = (uint16_t*)(q_im + MB4);
    uint16_t* kb_im = kb_re + KVE;
    uint16_t* vb_re = kb_im + KVE;
    uint16_t* vb_im = vb_re + KVE;
    uint16_t* vt_re = (uint16_t*)xr_q;
    uint16_t* vt_im = (uint16_t*)xi_q;
    uint16_t* qb_re = (uint16_t*)qkv_sr;
    uint16_t* qb_im = (uint16_t*)(qkv_sr + 8388608);

    hipMemsetAsync(mags, 0, 16, stream);

    decode_kernel<<<dim3(32, 32), 256, 0, stream>>>(wq_re, wq_im, 2048, qkv_sr, qkv_si, 0,    mags + 0);
    decode_kernel<<<dim3(8, 32),  256, 0, stream>>>(wk_re, wk_im, 512,  qkv_sr, qkv_si, 2048, mags + 1);
    decode_kernel<<<dim3(8, 32),  256, 0, stream>>>(wv_re, wv_im, 512,  qkv_sr, qkv_si, 2560, mags + 2);
    decode_kernel<<<dim3(32, 32), 256, 0, stream>>>(wo_re, wo_im, 2048, wo_sr, wo_si, 0,      mags + 3);

    act_quant_i8_kernel<<<NTOK, 256, 0, stream>>>(hr, hi, xr_q, xi_q, invs1);

    gemm_i8_kernel<0><<<dim3(24, 32), 256, 0, stream>>>(
        xr_q, xi_q, qkv_sr, qkv_si, 0, invs1, mags,
        1.0f / (float)((size_t)D_ * QD), 1.0f / (float)((size_t)D_ * KD), 1.0f / (float)((size_t)D_ * KD),
        q_re, q_im, kb_re, kb_im, vb_re, vb_im);

    rope_q_kernel<<<NTOK * H_ * 16 / 256, 256, 0, stream>>>(q_re, q_im, qb_re, qb_im);
    rope_k_kernel<<<NTOK * KV_ * 16 / 256, 256, 0, stream>>>(kb_re);
    vtrans_kernel<<<dim3(S_ / 32, 128 / 32, B_ * KV_ * 2), 256, 0, stream>>>(vb_re, vb_im, vt_re, vt_im);

    attn_mfma_kernel<<<dim3(S_ / 64, H_, B_), 256, 0, stream>>>(
        qb_re, qb_im, kb_re, kb_im, vt_re, vt_im, q_re, q_im);

    act_quant_i8_kernel<<<NTOK, 256, 0, stream>>>(q_re, q_im, xr_q, xi_q, invs2);

    gemm_i8_kernel<1><<<dim3(16, 32), 256, 0, stream>>>(
        xr_q, xi_q, wo_sr, wo_si, 2048, invs2, mags + 3,
        1.0f / (float)((size_t)QD * D_), 0.f, 0.f,
        out, out + MB4, nullptr, nullptr, nullptr, nullptr);
}

// Round 9
// 464.223 us; speedup vs baseline: 1.2391x; 1.0065x over previous
//
#include <hip/hip_runtime.h>
#include <stdint.h>

#define B_   2
#define S_   1024
#define D_   2048
#define H_   16
#define KV_  4
#define HD_  128
#define NTOK (B_ * S_)        /* 2048 tokens */
#define QD   (H_ * HD_)       /* 2048 */
#define KD   (KV_ * HD_)      /* 512  */

using i32x4  = __attribute__((ext_vector_type(4)))  int;
using i32x16 = __attribute__((ext_vector_type(16))) int;
using f32x4  = __attribute__((ext_vector_type(4)))  float;
using bf16x8 = __attribute__((ext_vector_type(8)))  short;

#define LN1E4_OVER_64 0.14391156831212725f

// ---------------- bf16 helpers ---------------------------------------------
__device__ __forceinline__ float bf2f(uint16_t u) { return __uint_as_float((uint32_t)u << 16); }
__device__ __forceinline__ uint16_t f2bf(float f) {
    uint32_t u = __float_as_uint(f);
    return (uint16_t)((u + 0x7FFFu + ((u >> 16) & 1u)) >> 16);   // RNE
}

// Exact per-byte int8 negate (SWAR). Bytes in {-1,0,1}; no cross-byte carry:
// (~x & 0x7F..) + 0x01.. stays within each byte, sign bit patched by XOR.
__device__ __forceinline__ i32x4 neg_i8x16(i32x4 x) {
    i32x4 r;
#pragma unroll
    for (int i = 0; i < 4; ++i) {
        uint32_t nx = ~(uint32_t)x[i];
        r[i] = (int)(((nx & 0x7F7F7F7Fu) + 0x01010101u) ^ (nx & 0x80808080u));
    }
    return r;
}

// ---------------------------------------------------------------------------
// Per-token joint absmax int8 quantization (dim = 2048 fixed).
// ---------------------------------------------------------------------------
__global__ __launch_bounds__(256)
void act_quant_i8_kernel(const float* __restrict__ xr, const float* __restrict__ xi,
                         int8_t* __restrict__ qr, int8_t* __restrict__ qi,
                         float* __restrict__ invs)
{
    const int tok = blockIdx.x, t = threadIdx.x;
    const float* pr = xr + (size_t)tok * 2048 + t * 8;
    const float* pi = xi + (size_t)tok * 2048 + t * 8;
    float4 r0 = *(const float4*)pr, r1 = *(const float4*)(pr + 4);
    float4 i0 = *(const float4*)pi, i1 = *(const float4*)(pi + 4);
    float am = fmaxf(fmaxf(fmaxf(fabsf(r0.x), fabsf(r0.y)), fmaxf(fabsf(r0.z), fabsf(r0.w))),
                     fmaxf(fmaxf(fabsf(r1.x), fabsf(r1.y)), fmaxf(fabsf(r1.z), fabsf(r1.w))));
    am = fmaxf(am, fmaxf(fmaxf(fmaxf(fabsf(i0.x), fabsf(i0.y)), fmaxf(fabsf(i0.z), fabsf(i0.w))),
                         fmaxf(fmaxf(fabsf(i1.x), fabsf(i1.y)), fmaxf(fabsf(i1.z), fabsf(i1.w)))));
    __shared__ float red[256];
    red[t] = am;
    __syncthreads();
    for (int st = 128; st > 0; st >>= 1) {
        if (t < st) red[t] = fmaxf(red[t], red[t + st]);
        __syncthreads();
    }
    const float s = 127.0f / fmaxf(red[0], 1e-5f);
    if (t == 0) invs[tok] = 1.0f / s;
#define Q8(x) ((uint32_t)(uint8_t)(int8_t)(int)fminf(fmaxf(rintf((x) * s), -128.f), 127.f))
    uint32_t a0 = Q8(r0.x) | (Q8(r0.y) << 8) | (Q8(r0.z) << 16) | (Q8(r0.w) << 24);
    uint32_t a1 = Q8(r1.x) | (Q8(r1.y) << 8) | (Q8(r1.z) << 16) | (Q8(r1.w) << 24);
    uint32_t b0 = Q8(i0.x) | (Q8(i0.y) << 8) | (Q8(i0.z) << 16) | (Q8(i0.w) << 24);
    uint32_t b1 = Q8(i1.x) | (Q8(i1.y) << 8) | (Q8(i1.z) << 16) | (Q8(i1.w) << 24);
#undef Q8
    *(uint32_t*)(qr + (size_t)tok * 2048 + t * 8)     = a0;
    *(uint32_t*)(qr + (size_t)tok * 2048 + t * 8 + 4) = a1;
    *(uint32_t*)(qi + (size_t)tok * 2048 + t * 8)     = b0;
    *(uint32_t*)(qi + (size_t)tok * 2048 + t * 8 + 4) = b1;
}

// ---------------------------------------------------------------------------
// Weight decode + transpose + fused mag reduction. (2 planes: sr, si)
// ---------------------------------------------------------------------------
__global__ __launch_bounds__(256)
void decode_kernel(const float* __restrict__ wr, const float* __restrict__ wi,
                   int N, int8_t* __restrict__ psr, int8_t* __restrict__ psi,
                   int n_off, float* __restrict__ mag_out)
{
    __shared__ alignas(16) int8_t tr[2][64][80];
    __shared__ float red[256];
    const int n0 = blockIdx.x * 64, k0 = blockIdx.y * 64;
    float msum = 0.f;
    for (int idx = threadIdx.x; idx < 4096; idx += 256) {
        int j = idx & 63, i = idx >> 6;                 // j = n, i = k
        size_t g = (size_t)(k0 + i) * N + n0 + j;
        float a = wr[g], b = wi[g];
        msum += sqrtf(a * a + b * b);
        int8_t sr, si;
        if (fabsf(a) >= fabsf(b)) {
            sr = (a > 0.f) ? 1 : ((a < 0.f) ? -1 : 0);
            si = 0;
        } else {
            sr = 0;
            si = (b > 0.f) ? 1 : ((b < 0.f) ? -1 : 0);
        }
        tr[0][j][i] = sr;
        tr[1][j][i] = si;
    }
    red[threadIdx.x] = msum;
    __syncthreads();
    for (int st = 128; st > 0; st >>= 1) {
        if (threadIdx.x < st) red[threadIdx.x] += red[threadIdx.x + st];
        __syncthreads();
    }
    if (threadIdx.x == 0) atomicAdd(mag_out, red[0]);
    int8_t* planes[2] = { psr, psi };
    for (int idx = threadIdx.x; idx < 512; idx += 256) {
        int p = idx >> 8, rem = idx & 255, n = rem >> 2, c = rem & 3;
        int4 v = *(const int4*)&tr[p][n][c * 16];
        *(int4*)(planes[p] + (size_t)(n_off + n0 + n) * 2048 + k0 + c * 16) = v;
    }
}

// ---------------------------------------------------------------------------
// int8 MFMA complex GEMM — DMA double-buffer pipeline, v4.
// v4: 2 accumulator planes (was 3). re needs Sum(xr*br) - Sum(xi*bi);
// instead of a separate p2 accumulator, negate the fbi fragment in VALU
// (exact SWAR byte negate) and accumulate xi*(-bi) into acc_re directly.
// AGPR 96 -> 64, total regs/wave ~176 -> ~148: NOW 3 waves/SIMD fit
// (r8 counters: Occ 28.5% = 2.3 blocks/CU showed the old kernel was
// register-capped at 2 blocks despite 48 KB LDS and launch_bounds(256,3);
// grid 768 at 2/CU = 1.5 rounds of fill imbalance).
// ---------------------------------------------------------------------------
__device__ __forceinline__ void async_copy16(const void* g, void* l) {
    __builtin_amdgcn_global_load_lds((const __attribute__((address_space(1))) void*)g,
                                     (__attribute__((address_space(3))) void*)l, 16, 0, 0);
}

template <int MODE>
__global__ __launch_bounds__(256, 3)
void gemm_i8_kernel(const int8_t* __restrict__ axr, const int8_t* __restrict__ axi,
                    const int8_t* __restrict__ bsr, const int8_t* __restrict__ bsi,
                    int Nout, const float* __restrict__ invs,
                    const float* __restrict__ mag_sums,
                    float magc0, float magc1, float magc2,
                    float* o_re, float* o_im,
                    uint16_t* kbr, uint16_t* kbi, uint16_t* vbr, uint16_t* vbi)
{
    // Stage layout (bytes): A0 [c4][row64][16] @0, A1 @4096,
    //                       B0 [c4][row128][16] @8192, B1 @16384. 24 KB.
    __shared__ alignas(16) int8_t smem[2][24576];
    const int tid = threadIdx.x;
    const int wav = tid >> 6, lane = tid & 63;         // wav 0..3 = N-block
    const int tileM = blockIdx.y * 64, tileN = blockIdx.x * 128;
    const int K = 2048;

    i32x16 pre[2] = {};   // xr*br + xi*(-bi)
    i32x16 pim[2] = {};   // xr*bi + xi*br

    auto issue_tile = [&](int k0, int buf) {
#pragma unroll
        for (int i = 0; i < 6; ++i) {
            int q = wav + 4 * i;            // 24 lds-dma per tile, 6 per wave
            const int8_t* g;
            int8_t* l;
            if (q < 8) {                    // A planes: 2 x 4 chunks x 64 rows
                int pl = q >> 2, c = q & 3;
                g = (pl ? axi : axr) + (size_t)(tileM + lane) * K + k0 + c * 16;
                l = &smem[buf][pl * 4096 + (c * 64 + lane) * 16];
            } else {                        // B planes: 2 x 4 chunks x 128 rows
                int r = q - 8;
                int pl = r >> 3, s = r & 7, c = s >> 1, m0 = (s & 1) << 6;
                g = (pl ? bsi : bsr) + (size_t)(tileN + m0 + lane) * K + k0 + c * 16;
                l = &smem[buf][8192 + pl * 8192 + (c * 128 + m0 + lane) * 16];
            }
            async_copy16(g, l);
        }
    };

    issue_tile(0, 0);
    issue_tile(64, 1);

    for (int k = 0; k < 32; ++k) {
        if (k == 31) { asm volatile("s_waitcnt vmcnt(0)" ::: "memory"); }
        else         { asm volatile("s_waitcnt vmcnt(6)" ::: "memory"); }
        asm volatile("s_barrier" ::: "memory");
        const int8_t* sb = smem[k & 1];
#pragma unroll
        for (int s = 0; s < 2; ++s) {
            const int cc = 2 * s + (lane >> 5);
            const int rA = lane & 31;
            const int rB = wav * 32 + (lane & 31);
            i32x4 fxr[2], fxi[2];
#pragma unroll
            for (int mb = 0; mb < 2; ++mb) {
                int off = (cc * 64 + rA + mb * 32) * 16;
                fxr[mb] = *(const i32x4*)&sb[off];
                fxi[mb] = *(const i32x4*)&sb[4096 + off];
            }
            i32x4 fbr, fbi;
            {
                int off = (cc * 128 + rB) * 16;
                fbr = *(const i32x4*)&sb[8192 + off];
                fbi = *(const i32x4*)&sb[16384 + off];
            }
            const i32x4 fbin = neg_i8x16(fbi);
#pragma unroll
            for (int mb = 0; mb < 2; ++mb) {
                pre[mb] = __builtin_amdgcn_mfma_i32_32x32x32_i8(fxr[mb], fbr,  pre[mb], 0, 0, 0);
                pre[mb] = __builtin_amdgcn_mfma_i32_32x32x32_i8(fxi[mb], fbin, pre[mb], 0, 0, 0);
                pim[mb] = __builtin_amdgcn_mfma_i32_32x32x32_i8(fxr[mb], fbi,  pim[mb], 0, 0, 0);
                pim[mb] = __builtin_amdgcn_mfma_i32_32x32x32_i8(fxi[mb], fbr,  pim[mb], 0, 0, 0);
            }
        }
        asm volatile("s_barrier" ::: "memory");       // all reads of buf done
        if (k + 2 < 32) issue_tile((k + 2) * 64, k & 1);
    }

    const int ln31 = lane & 31, lq = lane >> 5;
    const int gn = tileN + wav * 32 + ln31;
    float mag;
    if (MODE == 0)
        mag = (gn < 2048) ? mag_sums[0] * magc0
            : (gn < 2560) ? mag_sums[1] * magc1
                          : mag_sums[2] * magc2;
    else
        mag = mag_sums[0] * magc0;
#pragma unroll
    for (int mb = 0; mb < 2; ++mb) {
#pragma unroll
        for (int r = 0; r < 16; ++r) {
            const int row = (r & 3) + 8 * (r >> 2) + 4 * lq;
            const int gm = tileM + mb * 32 + row;
            const float sc = mag * invs[gm];
            const float re = (float)pre[mb][r] * sc;
            const float im = (float)pim[mb][r] * sc;
            if (MODE == 1) {
                o_re[(size_t)gm * Nout + gn] = re;
                o_im[(size_t)gm * Nout + gn] = im;
            } else {
                const int s = gm & (S_ - 1), bb = gm >> 10;
                if (gn < 2048) {
                    o_re[(size_t)gm * 2048 + gn] = re;
                    o_im[(size_t)gm * 2048 + gn] = im;
                } else if (gn < 2560) {
                    int c = gn - 2048, kvh = c >> 7, d = c & 127;
                    size_t off = ((size_t)(bb * KV_ + kvh) * S_ + s) * 128 + d;
                    kbr[off] = f2bf(re);
                    kbi[off] = f2bf(im);
                } else {
                    int c = gn - 2560, kvh = c >> 7, d = c & 127;
                    size_t off = ((size_t)(bb * KV_ + kvh) * S_ + s) * 128 + d;
                    vbr[off] = f2bf(re);
                    vbi[off] = f2bf(im);
                }
            }
        }
    }
}

// ---------------------------------------------------------------------------
// RoPE + bf16 convert + head-major rearrange for Q.
// ---------------------------------------------------------------------------
__global__ __launch_bounds__(256)
void rope_q_kernel(const float* __restrict__ q_re, const float* __restrict__ q_im,
                   uint16_t* __restrict__ qb_re, uint16_t* __restrict__ qb_im)
{
    int gidx = blockIdx.x * 256 + threadIdx.x;      // tok*256 + h*16 + j
    int j = gidx & 15, h = (gidx >> 4) & 15, tok = gidx >> 8;
    int s = tok & (S_ - 1), b = tok >> 10;
    int d0 = j * 4;
    size_t ib = (size_t)tok * 2048 + h * 128;
    float4 r0 = *(const float4*)&q_re[ib + d0];
    float4 r1 = *(const float4*)&q_re[ib + d0 + 64];
    float4 i0 = *(const float4*)&q_im[ib + d0];
    float4 i1 = *(const float4*)&q_im[ib + d0 + 64];
    float ro0[4], ro1[4];
    float rv0[4] = { r0.x, r0.y, r0.z, r0.w };
    float rv1[4] = { r1.x, r1.y, r1.z, r1.w };
#pragma unroll
    for (int t = 0; t < 4; ++t) {
        float f = __expf(-(float)(d0 + t) * LN1E4_OVER_64);
        float sn, c;
        __sincosf((float)s * f, &sn, &c);
        ro0[t] = rv0[t] * c - rv1[t] * sn;
        ro1[t] = rv1[t] * c + rv0[t] * sn;
    }
    size_t ob = ((size_t)(b * H_ + h) * S_ + s) * 128;
    ushort4 w;
    w = (ushort4){ f2bf(ro0[0]), f2bf(ro0[1]), f2bf(ro0[2]), f2bf(ro0[3]) };
    *(ushort4*)&qb_re[ob + d0] = w;
    w = (ushort4){ f2bf(ro1[0]), f2bf(ro1[1]), f2bf(ro1[2]), f2bf(ro1[3]) };
    *(ushort4*)&qb_re[ob + d0 + 64] = w;
    w = (ushort4){ f2bf(i0.x), f2bf(i0.y), f2bf(i0.z), f2bf(i0.w) };
    *(ushort4*)&qb_im[ob + d0] = w;
    w = (ushort4){ f2bf(i1.x), f2bf(i1.y), f2bf(i1.z), f2bf(i1.w) };
    *(ushort4*)&qb_im[ob + d0 + 64] = w;
}

// RoPE in place on K real bf16 plane [b][kv][s][128].
__global__ __launch_bounds__(256)
void rope_k_kernel(uint16_t* __restrict__ kb_re)
{
    int gidx = blockIdx.x * 256 + threadIdx.x;
    int j = gidx & 15, kvh = (gidx >> 4) & 3;
    int rest = gidx >> 6;
    int s = rest & (S_ - 1), b = rest >> 10;
    int d0 = j * 4;
    size_t base = ((size_t)(b * KV_ + kvh) * S_ + s) * 128;
    ushort4 u0 = *(const ushort4*)&kb_re[base + d0];
    ushort4 u1 = *(const ushort4*)&kb_re[base + d0 + 64];
    float rv0[4] = { bf2f(u0.x), bf2f(u0.y), bf2f(u0.z), bf2f(u0.w) };
    float rv1[4] = { bf2f(u1.x), bf2f(u1.y), bf2f(u1.z), bf2f(u1.w) };
    float ro0[4], ro1[4];
#pragma unroll
    for (int t = 0; t < 4; ++t) {
        float f = __expf(-(float)(d0 + t) * LN1E4_OVER_64);
        float sn, c;
        __sincosf((float)s * f, &sn, &c);
        ro0[t] = rv0[t] * c - rv1[t] * sn;
        ro1[t] = rv1[t] * c + rv0[t] * sn;
    }
    *(ushort4*)&kb_re[base + d0]      = (ushort4){ f2bf(ro0[0]), f2bf(ro0[1]), f2bf(ro0[2]), f2bf(ro0[3]) };
    *(ushort4*)&kb_re[base + d0 + 64] = (ushort4){ f2bf(ro1[0]), f2bf(ro1[1]), f2bf(ro1[2]), f2bf(ro1[3]) };
}

// ---------------------------------------------------------------------------
// V transpose: vb [bk][s][128] bf16 -> vt [bk][d][1024] bf16.
// ---------------------------------------------------------------------------
__global__ __launch_bounds__(256)
void vtrans_kernel(const uint16_t* __restrict__ vbr, const uint16_t* __restrict__ vbi,
                   uint16_t* __restrict__ vtr, uint16_t* __restrict__ vti)
{
    __shared__ uint16_t t[32][36];
    const int pl = blockIdx.z & 1, bk = blockIdx.z >> 1;
    const int s0 = blockIdx.x * 32, d0 = blockIdx.y * 32;
    const uint16_t* src = (pl ? vbi : vbr) + ((size_t)bk * S_) * 128;
    uint16_t*       dst = (pl ? vti : vtr) + ((size_t)bk * 128) * S_;
    const int r = threadIdx.x >> 3, c = (threadIdx.x & 7) * 4;
    *(ushort4*)&t[r][c] = *(const ushort4*)&src[(size_t)(s0 + r) * 128 + d0 + c];
    __syncthreads();
    ushort4 o = (ushort4){ t[c][r], t[c + 1][r], t[c + 2][r], t[c + 3][r] };
    *(ushort4*)&dst[(size_t)(d0 + r) * S_ + s0 + c] = o;
}

// ---------------------------------------------------------------------------
// MFMA flash attention (bf16, fp32 accum, online softmax in registers).
// v7: DMA pipeline (r5) + anti-correlated qt pairing (r8). Unchanged.
// ---------------------------------------------------------------------------
__global__ __launch_bounds__(256)
void attn_mfma_kernel(const uint16_t* __restrict__ qb_re, const uint16_t* __restrict__ qb_im,
                      const uint16_t* __restrict__ kb_re, const uint16_t* __restrict__ kb_im,
                      const uint16_t* __restrict__ vt_re, const uint16_t* __restrict__ vt_im,
                      float* __restrict__ o_re, float* __restrict__ o_im)
{
    __shared__ alignas(16) uint16_t sbuf[2][16384];   // 2 x 32KB: K [pl][ch16][row32]x8, V [pl][ch4][d128]x8
    __shared__ alignas(16) uint16_t sp[4][16][40];

    const int tid = threadIdx.x;
    const int w = tid >> 6, lane = tid & 63;
    const int r16 = lane & 15, q4 = lane >> 4;
    const int h = blockIdx.y, b = blockIdx.z;
    // Anti-correlated qt across the batch axis: co-resident blocks (same
    // x,y; z=0/1) get complementary work (34 kv-iters total per CU).
    const int qt = b ? blockIdx.x : (gridDim.x - 1 - blockIdx.x);
    const int kvh = h >> 2;
    const int q0 = qt * 64, qw0 = q0 + w * 16;

    bf16x8 qfr[4], qfi[4];
    {
        const size_t qbase = ((size_t)(b * H_ + h) * S_ + qw0 + r16) * 128;
#pragma unroll
        for (int ks = 0; ks < 4; ++ks) {
            const int col = ks * 32 + q4 * 8;
            qfr[ks] = *(const bf16x8*)&qb_re[qbase + col];
            qfi[ks] = *(const bf16x8*)&qb_im[qbase + col];
        }
    }

    f32x4 oa[2][8] = {};
    float m_r[4] = { -3e38f, -3e38f, -3e38f, -3e38f };
    float l_r[4] = { 0.f, 0.f, 0.f, 0.f };

    const size_t kgbase0 = (size_t)(b * KV_ + kvh) * S_ * 128;
    const uint16_t* vre = vt_re + (size_t)(b * KV_ + kvh) * 128 * (size_t)S_;
    const uint16_t* vim = vt_im + (size_t)(b * KV_ + kvh) * 128 * (size_t)S_;

    const uint16_t* kp[4];
    const uint16_t* vp[4];
#pragma unroll
    for (int i = 0; i < 4; ++i) {
        const int kch = (i & 1) * 8 + w * 2 + (lane >> 5);
        kp[i] = ((i >> 1) ? kb_im : kb_re) + kgbase0 + (size_t)(lane & 31) * 128 + kch * 8;
        const int vch = (i & 1) * 2 + (w >> 1);
        const int vd  = ((w & 1) << 6) | lane;
        vp[i] = ((i >> 1) ? vim : vre) + (size_t)vd * S_ + vch * 8;
    }

    auto issue_tile = [&](int kt, int buf) {
#pragma unroll
        for (int i = 0; i < 4; ++i)
            async_copy16(kp[i] + (size_t)kt * 4096, &sbuf[buf][w * 512 + i * 2048]);
#pragma unroll
        for (int i = 0; i < 4; ++i)
            async_copy16(vp[i] + (size_t)kt * 32, &sbuf[buf][8192 + w * 512 + i * 2048]);
    };

    const int nk = (q0 + 64) >> 5;                    // kv tiles of 32, nk >= 2

    issue_tile(0, 0);
    issue_tile(1, 1);

    for (int k = 0; k < nk; ++k) {
        if (k == nk - 1) { asm volatile("s_waitcnt vmcnt(0)" ::: "memory"); }
        else             { asm volatile("s_waitcnt vmcnt(8)" ::: "memory"); }
        asm volatile("s_barrier" ::: "memory");
        const uint16_t* sb = sbuf[k & 1];
        const int c0 = k << 5;

        if (c0 <= qw0 + 15) {
            f32x4 sc[2] = {};
#pragma unroll
            for (int cblk = 0; cblk < 2; ++cblk) {
                const int krow = cblk * 16 + r16;
#pragma unroll
                for (int ks = 0; ks < 4; ++ks) {
                    const int koff = (ks * 4 + q4) * 256 + krow * 8;
                    bf16x8 kr = *(const bf16x8*)&sb[koff];
                    bf16x8 ki = *(const bf16x8*)&sb[4096 + koff];
                    sc[cblk] = __builtin_amdgcn_mfma_f32_16x16x32_bf16(qfr[ks], kr, sc[cblk], 0, 0, 0);
                    sc[cblk] = __builtin_amdgcn_mfma_f32_16x16x32_bf16(qfi[ks], ki, sc[cblk], 0, 0, 0);
                }
            }
#pragma unroll
            for (int cblk = 0; cblk < 2; ++cblk)
#pragma unroll
                for (int reg = 0; reg < 4; ++reg) {
                    float sval = sc[cblk][reg] * 0.08838834764831845f;
                    const int rowg = qw0 + q4 * 4 + reg;
                    const int colg = c0 + cblk * 16 + r16;
                    if (colg > rowg) sval = -3e38f;
                    sc[cblk][reg] = sval;
                }
            float al[4];
#pragma unroll
            for (int reg = 0; reg < 4; ++reg) {
                float mx = fmaxf(sc[0][reg], sc[1][reg]);
#pragma unroll
                for (int msk = 1; msk < 16; msk <<= 1) mx = fmaxf(mx, __shfl_xor(mx, msk));
                const float mn = fmaxf(m_r[reg], mx);
                al[reg] = __expf(m_r[reg] - mn);
                const float p0 = __expf(sc[0][reg] - mn);
                const float p1 = __expf(sc[1][reg] - mn);
                sc[0][reg] = p0; sc[1][reg] = p1;
                float rs = p0 + p1;
#pragma unroll
                for (int msk = 1; msk < 16; msk <<= 1) rs += __shfl_xor(rs, msk);
                l_r[reg] = l_r[reg] * al[reg] + rs;
                m_r[reg] = mn;
            }
#pragma unroll
            for (int cblk = 0; cblk < 2; ++cblk)
#pragma unroll
                for (int reg = 0; reg < 4; ++reg)
                    sp[w][q4 * 4 + reg][cblk * 16 + r16] = f2bf(sc[cblk][reg]);
#pragma unroll
            for (int dblk = 0; dblk < 8; ++dblk)
#pragma unroll
                for (int reg = 0; reg < 4; ++reg) {
                    oa[0][dblk][reg] *= al[reg];
                    oa[1][dblk][reg] *= al[reg];
                }
            bf16x8 pf = *(const bf16x8*)&sp[w][r16][q4 * 8];
#pragma unroll
            for (int dblk = 0; dblk < 8; ++dblk) {
                const int voff = 8192 + q4 * 1024 + (dblk * 16 + r16) * 8;
                bf16x8 vr = *(const bf16x8*)&sb[voff];
                bf16x8 vi = *(const bf16x8*)&sb[4096 + voff];
                oa[0][dblk] = __builtin_amdgcn_mfma_f32_16x16x32_bf16(pf, vr, oa[0][dblk], 0, 0, 0);
                oa[1][dblk] = __builtin_amdgcn_mfma_f32_16x16x32_bf16(pf, vi, oa[1][dblk], 0, 0, 0);
            }
        }

        asm volatile("s_barrier" ::: "memory");       // all reads of buf done
        if (k + 2 < nk) issue_tile(k + 2, k & 1);
    }

    float inv[4];
#pragma unroll
    for (int reg = 0; reg < 4; ++reg) inv[reg] = 1.f / l_r[reg];
#pragma unroll
    for (int dblk = 0; dblk < 8; ++dblk) {
        const int col = h * 128 + dblk * 16 + r16;
#pragma unroll
        for (int reg = 0; reg < 4; ++reg) {
            const size_t tok = (size_t)b * S_ + qw0 + q4 * 4 + reg;
            o_re[tok * 2048 + col] = oa[0][dblk][reg] * inv[reg];
            o_im[tok * 2048 + col] = oa[1][dblk][reg] * inv[reg];
        }
    }
}

// ---------------------------------------------------------------------------
extern "C" void kernel_launch(void* const* d_in, const int* in_sizes, int n_in,
                              void* d_out, int out_size, void* d_ws, size_t ws_size,
                              hipStream_t stream)
{
    const float* hr    = (const float*)d_in[0];
    const float* hi    = (const float*)d_in[1];
    const float* wq_re = (const float*)d_in[2];
    const float* wq_im = (const float*)d_in[3];
    const float* wk_re = (const float*)d_in[4];
    const float* wk_im = (const float*)d_in[5];
    const float* wv_re = (const float*)d_in[6];
    const float* wv_im = (const float*)d_in[7];
    const float* wo_re = (const float*)d_in[8];
    const float* wo_im = (const float*)d_in[9];
    float* out = (float*)d_out;
    char*  base = (char*)d_ws;

    const size_t MB4  = (size_t)2048 * 2048;
    const size_t QKVP = (size_t)3072 * 2048;
    const size_t KVE  = (size_t)B_ * KV_ * S_ * 128;

    float*   mags   = (float*)(base);
    float*   invs1  = (float*)(base + 1024);
    float*   invs2  = (float*)(base + 9216);
    int8_t*  xr_q   = (int8_t*)(base + 32768);
    int8_t*  xi_q   = xr_q + MB4;
    int8_t*  qkv_sr = xi_q + MB4;
    int8_t*  qkv_si = qkv_sr + QKVP;
    int8_t*  qkv_ns = qkv_si + QKVP;     // (unused — bnsi plane dropped)
    int8_t*  wo_sr  = qkv_ns + QKVP;
    int8_t*  wo_si  = wo_sr + MB4;
    int8_t*  wo_ns  = wo_si + MB4;       // (unused)
    float*   q_re   = (float*)(wo_ns + MB4);
    float*   q_im   = q_re + MB4;
    uint16_t* kb_re = (uint16_t*)(q_im + MB4);
    uint16_t* kb_im = kb_re + KVE;
    uint16_t* vb_re = kb_im + KVE;
    uint16_t* vb_im = vb_re + KVE;
    uint16_t* vt_re = (uint16_t*)xr_q;
    uint16_t* vt_im = (uint16_t*)xi_q;
    uint16_t* qb_re = (uint16_t*)qkv_sr;
    uint16_t* qb_im = (uint16_t*)(qkv_sr + 8388608);

    hipMemsetAsync(mags, 0, 16, stream);

    decode_kernel<<<dim3(32, 32), 256, 0, stream>>>(wq_re, wq_im, 2048, qkv_sr, qkv_si, 0,    mags + 0);
    decode_kernel<<<dim3(8, 32),  256, 0, stream>>>(wk_re, wk_im, 512,  qkv_sr, qkv_si, 2048, mags + 1);
    decode_kernel<<<dim3(8, 32),  256, 0, stream>>>(wv_re, wv_im, 512,  qkv_sr, qkv_si, 2560, mags + 2);
    decode_kernel<<<dim3(32, 32), 256, 0, stream>>>(wo_re, wo_im, 2048, wo_sr, wo_si, 0,      mags + 3);

    act_quant_i8_kernel<<<NTOK, 256, 0, stream>>>(hr, hi, xr_q, xi_q, invs1);

    gemm_i8_kernel<0><<<dim3(24, 32), 256, 0, stream>>>(
        xr_q, xi_q, qkv_sr, qkv_si, 0, invs1, mags,
        1.0f / (float)((size_t)D_ * QD), 1.0f / (float)((size_t)D_ * KD), 1.0f / (float)((size_t)D_ * KD),
        q_re, q_im, kb_re, kb_im, vb_re, vb_im);

    rope_q_kernel<<<NTOK * H_ * 16 / 256, 256, 0, stream>>>(q_re, q_im, qb_re, qb_im);
    rope_k_kernel<<<NTOK * KV_ * 16 / 256, 256, 0, stream>>>(kb_re);
    vtrans_kernel<<<dim3(S_ / 32, 128 / 32, B_ * KV_ * 2), 256, 0, stream>>>(vb_re, vb_im, vt_re, vt_im);

    attn_mfma_kernel<<<dim3(S_ / 64, H_, B_), 256, 0, stream>>>(
        qb_re, qb_im, kb_re, kb_im, vt_re, vt_im, q_re, q_im);

    act_quant_i8_kernel<<<NTOK, 256, 0, stream>>>(q_re, q_im, xr_q, xi_q, invs2);

    gemm_i8_kernel<1><<<dim3(16, 32), 256, 0, stream>>>(
        xr_q, xi_q, wo_sr, wo_si, 2048, invs2, mags + 3,
        1.0f / (float)((size_t)QD * D_), 0.f, 0.f,
        out, out + MB4, nullptr, nullptr, nullptr, nullptr);
}

// Round 10
// 449.191 us; speedup vs baseline: 1.2806x; 1.0335x over previous
//
#include <hip/hip_runtime.h>
#include <stdint.h>

#define B_   2
#define S_   1024
#define D_   2048
#define H_   16
#define KV_  4
#define HD_  128
#define NTOK (B_ * S_)        /* 2048 tokens */
#define QD   (H_ * HD_)       /* 2048 */
#define KD   (KV_ * HD_)      /* 512  */

using i32x4  = __attribute__((ext_vector_type(4)))  int;
using i32x16 = __attribute__((ext_vector_type(16))) int;
using f32x4  = __attribute__((ext_vector_type(4)))  float;
using bf16x8 = __attribute__((ext_vector_type(8)))  short;

#define LN1E4_OVER_64 0.14391156831212725f

// ---------------- bf16 helpers ---------------------------------------------
__device__ __forceinline__ float bf2f(uint16_t u) { return __uint_as_float((uint32_t)u << 16); }
__device__ __forceinline__ uint16_t f2bf(float f) {
    uint32_t u = __float_as_uint(f);
    return (uint16_t)((u + 0x7FFFu + ((u >> 16) & 1u)) >> 16);   // RNE
}

// Exact per-byte int8 negate (SWAR). Bytes in {-1,0,1}; no cross-byte carry.
__device__ __forceinline__ i32x4 neg_i8x16(i32x4 x) {
    i32x4 r;
#pragma unroll
    for (int i = 0; i < 4; ++i) {
        uint32_t nx = ~(uint32_t)x[i];
        r[i] = (int)(((nx & 0x7F7F7F7Fu) + 0x01010101u) ^ (nx & 0x80808080u));
    }
    return r;
}

// ---------------------------------------------------------------------------
// Per-token joint absmax int8 quantization (dim = 2048 fixed), f32 input.
// ---------------------------------------------------------------------------
__global__ __launch_bounds__(256)
void act_quant_i8_kernel(const float* __restrict__ xr, const float* __restrict__ xi,
                         int8_t* __restrict__ qr, int8_t* __restrict__ qi,
                         float* __restrict__ invs)
{
    const int tok = blockIdx.x, t = threadIdx.x;
    const float* pr = xr + (size_t)tok * 2048 + t * 8;
    const float* pi = xi + (size_t)tok * 2048 + t * 8;
    float4 r0 = *(const float4*)pr, r1 = *(const float4*)(pr + 4);
    float4 i0 = *(const float4*)pi, i1 = *(const float4*)(pi + 4);
    float am = fmaxf(fmaxf(fmaxf(fabsf(r0.x), fabsf(r0.y)), fmaxf(fabsf(r0.z), fabsf(r0.w))),
                     fmaxf(fmaxf(fabsf(r1.x), fabsf(r1.y)), fmaxf(fabsf(r1.z), fabsf(r1.w))));
    am = fmaxf(am, fmaxf(fmaxf(fmaxf(fabsf(i0.x), fabsf(i0.y)), fmaxf(fabsf(i0.z), fabsf(i0.w))),
                         fmaxf(fmaxf(fabsf(i1.x), fabsf(i1.y)), fmaxf(fabsf(i1.z), fabsf(i1.w)))));
    __shared__ float red[256];
    red[t] = am;
    __syncthreads();
    for (int st = 128; st > 0; st >>= 1) {
        if (t < st) red[t] = fmaxf(red[t], red[t + st]);
        __syncthreads();
    }
    const float s = 127.0f / fmaxf(red[0], 1e-5f);
    if (t == 0) invs[tok] = 1.0f / s;
#define Q8(x) ((uint32_t)(uint8_t)(int8_t)(int)fminf(fmaxf(rintf((x) * s), -128.f), 127.f))
    uint32_t a0 = Q8(r0.x) | (Q8(r0.y) << 8) | (Q8(r0.z) << 16) | (Q8(r0.w) << 24);
    uint32_t a1 = Q8(r1.x) | (Q8(r1.y) << 8) | (Q8(r1.z) << 16) | (Q8(r1.w) << 24);
    uint32_t b0 = Q8(i0.x) | (Q8(i0.y) << 8) | (Q8(i0.z) << 16) | (Q8(i0.w) << 24);
    uint32_t b1 = Q8(i1.x) | (Q8(i1.y) << 8) | (Q8(i1.z) << 16) | (Q8(i1.w) << 24);
#undef Q8
    *(uint32_t*)(qr + (size_t)tok * 2048 + t * 8)     = a0;
    *(uint32_t*)(qr + (size_t)tok * 2048 + t * 8 + 4) = a1;
    *(uint32_t*)(qi + (size_t)tok * 2048 + t * 8)     = b0;
    *(uint32_t*)(qi + (size_t)tok * 2048 + t * 8 + 4) = b1;
}

// Same, but bf16 input (attn output path — halves the read traffic).
__global__ __launch_bounds__(256)
void act_quant_bf16_kernel(const uint16_t* __restrict__ xr, const uint16_t* __restrict__ xi,
                           int8_t* __restrict__ qr, int8_t* __restrict__ qi,
                           float* __restrict__ invs)
{
    const int tok = blockIdx.x, t = threadIdx.x;
    uint4 rv = *(const uint4*)(xr + (size_t)tok * 2048 + t * 8);
    uint4 iv = *(const uint4*)(xi + (size_t)tok * 2048 + t * 8);
    float fr[8], fi[8];
    const uint32_t* ru = (const uint32_t*)&rv;
    const uint32_t* iu = (const uint32_t*)&iv;
#pragma unroll
    for (int i = 0; i < 4; ++i) {
        fr[2 * i]     = __uint_as_float(ru[i] << 16);
        fr[2 * i + 1] = __uint_as_float(ru[i] & 0xFFFF0000u);
        fi[2 * i]     = __uint_as_float(iu[i] << 16);
        fi[2 * i + 1] = __uint_as_float(iu[i] & 0xFFFF0000u);
    }
    float am = 0.f;
#pragma unroll
    for (int i = 0; i < 8; ++i) am = fmaxf(am, fmaxf(fabsf(fr[i]), fabsf(fi[i])));
    __shared__ float red[256];
    red[t] = am;
    __syncthreads();
    for (int st = 128; st > 0; st >>= 1) {
        if (t < st) red[t] = fmaxf(red[t], red[t + st]);
        __syncthreads();
    }
    const float s = 127.0f / fmaxf(red[0], 1e-5f);
    if (t == 0) invs[tok] = 1.0f / s;
#define Q8(x) ((uint32_t)(uint8_t)(int8_t)(int)fminf(fmaxf(rintf((x) * s), -128.f), 127.f))
    uint32_t a0 = Q8(fr[0]) | (Q8(fr[1]) << 8) | (Q8(fr[2]) << 16) | (Q8(fr[3]) << 24);
    uint32_t a1 = Q8(fr[4]) | (Q8(fr[5]) << 8) | (Q8(fr[6]) << 16) | (Q8(fr[7]) << 24);
    uint32_t b0 = Q8(fi[0]) | (Q8(fi[1]) << 8) | (Q8(fi[2]) << 16) | (Q8(fi[3]) << 24);
    uint32_t b1 = Q8(fi[4]) | (Q8(fi[5]) << 8) | (Q8(fi[6]) << 16) | (Q8(fi[7]) << 24);
#undef Q8
    *(uint32_t*)(qr + (size_t)tok * 2048 + t * 8)     = a0;
    *(uint32_t*)(qr + (size_t)tok * 2048 + t * 8 + 4) = a1;
    *(uint32_t*)(qi + (size_t)tok * 2048 + t * 8)     = b0;
    *(uint32_t*)(qi + (size_t)tok * 2048 + t * 8 + 4) = b1;
}

// ---------------------------------------------------------------------------
// Weight decode + transpose + fused mag reduction. (2 planes: sr, si)
// ---------------------------------------------------------------------------
__global__ __launch_bounds__(256)
void decode_kernel(const float* __restrict__ wr, const float* __restrict__ wi,
                   int N, int8_t* __restrict__ psr, int8_t* __restrict__ psi,
                   int n_off, float* __restrict__ mag_out)
{
    __shared__ alignas(16) int8_t tr[2][64][80];
    __shared__ float red[256];
    const int n0 = blockIdx.x * 64, k0 = blockIdx.y * 64;
    float msum = 0.f;
    for (int idx = threadIdx.x; idx < 4096; idx += 256) {
        int j = idx & 63, i = idx >> 6;                 // j = n, i = k
        size_t g = (size_t)(k0 + i) * N + n0 + j;
        float a = wr[g], b = wi[g];
        msum += sqrtf(a * a + b * b);
        int8_t sr, si;
        if (fabsf(a) >= fabsf(b)) {
            sr = (a > 0.f) ? 1 : ((a < 0.f) ? -1 : 0);
            si = 0;
        } else {
            sr = 0;
            si = (b > 0.f) ? 1 : ((b < 0.f) ? -1 : 0);
        }
        tr[0][j][i] = sr;
        tr[1][j][i] = si;
    }
    red[threadIdx.x] = msum;
    __syncthreads();
    for (int st = 128; st > 0; st >>= 1) {
        if (threadIdx.x < st) red[threadIdx.x] += red[threadIdx.x + st];
        __syncthreads();
    }
    if (threadIdx.x == 0) atomicAdd(mag_out, red[0]);
    int8_t* planes[2] = { psr, psi };
    for (int idx = threadIdx.x; idx < 512; idx += 256) {
        int p = idx >> 8, rem = idx & 255, n = rem >> 2, c = rem & 3;
        int4 v = *(const int4*)&tr[p][n][c * 16];
        *(int4*)(planes[p] + (size_t)(n_off + n0 + n) * 2048 + k0 + c * 16) = v;
    }
}

// ---------------------------------------------------------------------------
// int8 MFMA complex GEMM — DMA double-buffer pipeline, v5.
// v5: fused RoPE epilogue (MODE 0, Q/K tiles). Each 128-wide N-tile is one
// head; the rotation partner (d <-> d^64) lives in another wave, so the
// scaled re plane is exchanged through LDS (reuse of the stage buffer,
// [128][65] f32 pad = conflict-free) and RoPE applied before the single
// bf16 rounding. Eliminates rope_q/rope_k kernels and the 33.5 MB x2
// q_re/q_im f32 round-trip. Q numerics identical; K slightly closer to ref
// (one fewer bf16 rounding).
// ---------------------------------------------------------------------------
__device__ __forceinline__ void async_copy16(const void* g, void* l) {
    __builtin_amdgcn_global_load_lds((const __attribute__((address_space(1))) void*)g,
                                     (__attribute__((address_space(3))) void*)l, 16, 0, 0);
}

template <int MODE>
__global__ __launch_bounds__(256, 3)
void gemm_i8_kernel(const int8_t* __restrict__ axr, const int8_t* __restrict__ axi,
                    const int8_t* __restrict__ bsr, const int8_t* __restrict__ bsi,
                    int Nout, const float* __restrict__ invs,
                    const float* __restrict__ mag_sums,
                    float magc0, float magc1, float magc2,
                    float* o_re, float* o_im,
                    uint16_t* qbr, uint16_t* qbi,
                    uint16_t* kbr, uint16_t* kbi, uint16_t* vbr, uint16_t* vbi)
{
    // Stage layout (bytes): A0 [c4][row64][16] @0, A1 @4096,
    //                       B0 [c4][row128][16] @8192, B1 @16384. 24 KB.
    __shared__ alignas(16) int8_t smem[2][24576];
    const int tid = threadIdx.x;
    const int wav = tid >> 6, lane = tid & 63;         // wav 0..3 = N-block
    const int tileM = blockIdx.y * 64, tileN = blockIdx.x * 128;
    const int K = 2048;

    i32x16 pre[2] = {};   // xr*br + xi*(-bi)
    i32x16 pim[2] = {};   // xr*bi + xi*br

    auto issue_tile = [&](int k0, int buf) {
#pragma unroll
        for (int i = 0; i < 6; ++i) {
            int q = wav + 4 * i;            // 24 lds-dma per tile, 6 per wave
            const int8_t* g;
            int8_t* l;
            if (q < 8) {                    // A planes: 2 x 4 chunks x 64 rows
                int pl = q >> 2, c = q & 3;
                g = (pl ? axi : axr) + (size_t)(tileM + lane) * K + k0 + c * 16;
                l = &smem[buf][pl * 4096 + (c * 64 + lane) * 16];
            } else {                        // B planes: 2 x 4 chunks x 128 rows
                int r = q - 8;
                int pl = r >> 3, s = r & 7, c = s >> 1, m0 = (s & 1) << 6;
                g = (pl ? bsi : bsr) + (size_t)(tileN + m0 + lane) * K + k0 + c * 16;
                l = &smem[buf][8192 + pl * 8192 + (c * 128 + m0 + lane) * 16];
            }
            async_copy16(g, l);
        }
    };

    issue_tile(0, 0);
    issue_tile(64, 1);

    for (int k = 0; k < 32; ++k) {
        if (k == 31) { asm volatile("s_waitcnt vmcnt(0)" ::: "memory"); }
        else         { asm volatile("s_waitcnt vmcnt(6)" ::: "memory"); }
        asm volatile("s_barrier" ::: "memory");
        const int8_t* sb = smem[k & 1];
#pragma unroll
        for (int s = 0; s < 2; ++s) {
            const int cc = 2 * s + (lane >> 5);
            const int rA = lane & 31;
            const int rB = wav * 32 + (lane & 31);
            i32x4 fxr[2], fxi[2];
#pragma unroll
            for (int mb = 0; mb < 2; ++mb) {
                int off = (cc * 64 + rA + mb * 32) * 16;
                fxr[mb] = *(const i32x4*)&sb[off];
                fxi[mb] = *(const i32x4*)&sb[4096 + off];
            }
            i32x4 fbr, fbi;
            {
                int off = (cc * 128 + rB) * 16;
                fbr = *(const i32x4*)&sb[8192 + off];
                fbi = *(const i32x4*)&sb[16384 + off];
            }
            const i32x4 fbin = neg_i8x16(fbi);
#pragma unroll
            for (int mb = 0; mb < 2; ++mb) {
                pre[mb] = __builtin_amdgcn_mfma_i32_32x32x32_i8(fxr[mb], fbr,  pre[mb], 0, 0, 0);
                pre[mb] = __builtin_amdgcn_mfma_i32_32x32x32_i8(fxi[mb], fbin, pre[mb], 0, 0, 0);
                pim[mb] = __builtin_amdgcn_mfma_i32_32x32x32_i8(fxr[mb], fbi,  pim[mb], 0, 0, 0);
                pim[mb] = __builtin_amdgcn_mfma_i32_32x32x32_i8(fxi[mb], fbr,  pim[mb], 0, 0, 0);
            }
        }
        asm volatile("s_barrier" ::: "memory");       // all reads of buf done
        if (k + 2 < 32) issue_tile((k + 2) * 64, k & 1);
    }

    const int ln31 = lane & 31, lq = lane >> 5;
    const int gn = tileN + wav * 32 + ln31;
    float mag;
    if (MODE == 0)
        mag = (gn < 2048) ? mag_sums[0] * magc0
            : (gn < 2560) ? mag_sums[1] * magc1
                          : mag_sums[2] * magc2;
    else
        mag = mag_sums[0] * magc0;

    if (MODE == 0 && tileN < 2560) {
        // ---- Fused RoPE epilogue (Q and K tiles; one head per tile) ----
        float* lds_ex = (float*)smem;              // [128][65] f32, 33.3 KB
        const int d = wav * 32 + ln31;             // column within head
        __syncthreads();                           // drain all k-loop LDS reads
#pragma unroll
        for (int mb = 0; mb < 2; ++mb)
#pragma unroll
            for (int r = 0; r < 16; ++r) {
                const int row = mb * 32 + (r & 3) + 8 * (r >> 2) + 4 * lq;
                lds_ex[d * 65 + row] = (float)pre[mb][r] * (mag * invs[tileM + row]);
            }
        __syncthreads();
        const float fd = __expf(-(float)(d & 63) * LN1E4_OVER_64);
#pragma unroll
        for (int mb = 0; mb < 2; ++mb)
#pragma unroll
            for (int r = 0; r < 16; ++r) {
                const int row = mb * 32 + (r & 3) + 8 * (r >> 2) + 4 * lq;
                const int gm = tileM + row;
                const int s = gm & (S_ - 1), bb = gm >> 10;
                const float sc = mag * invs[gm];
                const float re = (float)pre[mb][r] * sc;
                const float im = (float)pim[mb][r] * sc;
                const float prt = lds_ex[(d ^ 64) * 65 + row];
                float sn, cs;
                __sincosf((float)s * fd, &sn, &cs);
                const float ro = (d < 64) ? (re * cs - prt * sn) : (re * cs + prt * sn);
                if (tileN < 2048) {
                    const int hh = tileN >> 7;
                    const size_t off = ((size_t)(bb * H_ + hh) * S_ + s) * 128 + d;
                    qbr[off] = f2bf(ro);
                    qbi[off] = f2bf(im);
                } else {
                    const int kvh = (tileN - 2048) >> 7;
                    const size_t off = ((size_t)(bb * KV_ + kvh) * S_ + s) * 128 + d;
                    kbr[off] = f2bf(ro);
                    kbi[off] = f2bf(im);
                }
            }
    } else {
        // MODE 1 output, or MODE 0 V-region (no RoPE).
#pragma unroll
        for (int mb = 0; mb < 2; ++mb)
#pragma unroll
            for (int r = 0; r < 16; ++r) {
                const int row = (r & 3) + 8 * (r >> 2) + 4 * lq;
                const int gm = tileM + mb * 32 + row;
                const float sc = mag * invs[gm];
                const float re = (float)pre[mb][r] * sc;
                const float im = (float)pim[mb][r] * sc;
                if (MODE == 1) {
                    o_re[(size_t)gm * Nout + gn] = re;
                    o_im[(size_t)gm * Nout + gn] = im;
                } else {
                    const int s = gm & (S_ - 1), bb = gm >> 10;
                    const int c = gn - 2560, kvh = c >> 7, dd = c & 127;
                    const size_t off = ((size_t)(bb * KV_ + kvh) * S_ + s) * 128 + dd;
                    vbr[off] = f2bf(re);
                    vbi[off] = f2bf(im);
                }
            }
    }
}

// ---------------------------------------------------------------------------
// V transpose: vb [bk][s][128] bf16 -> vt [bk][d][1024] bf16.
// ---------------------------------------------------------------------------
__global__ __launch_bounds__(256)
void vtrans_kernel(const uint16_t* __restrict__ vbr, const uint16_t* __restrict__ vbi,
                   uint16_t* __restrict__ vtr, uint16_t* __restrict__ vti)
{
    __shared__ uint16_t t[32][36];
    const int pl = blockIdx.z & 1, bk = blockIdx.z >> 1;
    const int s0 = blockIdx.x * 32, d0 = blockIdx.y * 32;
    const uint16_t* src = (pl ? vbi : vbr) + ((size_t)bk * S_) * 128;
    uint16_t*       dst = (pl ? vti : vtr) + ((size_t)bk * 128) * S_;
    const int r = threadIdx.x >> 3, c = (threadIdx.x & 7) * 4;
    *(ushort4*)&t[r][c] = *(const ushort4*)&src[(size_t)(s0 + r) * 128 + d0 + c];
    __syncthreads();
    ushort4 o = (ushort4){ t[c][r], t[c + 1][r], t[c + 2][r], t[c + 3][r] };
    *(ushort4*)&dst[(size_t)(d0 + r) * S_ + s0 + c] = o;
}

// ---------------------------------------------------------------------------
// MFMA flash attention (bf16, fp32 accum, online softmax in registers).
// v8: DMA pipeline (r5) + anti-correlated qt pairing (r8) + bf16 output
// (halves output write + downstream quant read traffic).
// ---------------------------------------------------------------------------
__global__ __launch_bounds__(256)
void attn_mfma_kernel(const uint16_t* __restrict__ qb_re, const uint16_t* __restrict__ qb_im,
                      const uint16_t* __restrict__ kb_re, const uint16_t* __restrict__ kb_im,
                      const uint16_t* __restrict__ vt_re, const uint16_t* __restrict__ vt_im,
                      uint16_t* __restrict__ ob_re, uint16_t* __restrict__ ob_im)
{
    __shared__ alignas(16) uint16_t sbuf[2][16384];   // 2 x 32KB: K [pl][ch16][row32]x8, V [pl][ch4][d128]x8
    __shared__ alignas(16) uint16_t sp[4][16][40];

    const int tid = threadIdx.x;
    const int w = tid >> 6, lane = tid & 63;
    const int r16 = lane & 15, q4 = lane >> 4;
    const int h = blockIdx.y, b = blockIdx.z;
    // Anti-correlated qt across the batch axis: co-resident blocks (same
    // x,y; z=0/1) get complementary work (34 kv-iters total per CU).
    const int qt = b ? blockIdx.x : (gridDim.x - 1 - blockIdx.x);
    const int kvh = h >> 2;
    const int q0 = qt * 64, qw0 = q0 + w * 16;

    bf16x8 qfr[4], qfi[4];
    {
        const size_t qbase = ((size_t)(b * H_ + h) * S_ + qw0 + r16) * 128;
#pragma unroll
        for (int ks = 0; ks < 4; ++ks) {
            const int col = ks * 32 + q4 * 8;
            qfr[ks] = *(const bf16x8*)&qb_re[qbase + col];
            qfi[ks] = *(const bf16x8*)&qb_im[qbase + col];
        }
    }

    f32x4 oa[2][8] = {};
    float m_r[4] = { -3e38f, -3e38f, -3e38f, -3e38f };
    float l_r[4] = { 0.f, 0.f, 0.f, 0.f };

    const size_t kgbase0 = (size_t)(b * KV_ + kvh) * S_ * 128;
    const uint16_t* vre = vt_re + (size_t)(b * KV_ + kvh) * 128 * (size_t)S_;
    const uint16_t* vim = vt_im + (size_t)(b * KV_ + kvh) * 128 * (size_t)S_;

    const uint16_t* kp[4];
    const uint16_t* vp[4];
#pragma unroll
    for (int i = 0; i < 4; ++i) {
        const int kch = (i & 1) * 8 + w * 2 + (lane >> 5);
        kp[i] = ((i >> 1) ? kb_im : kb_re) + kgbase0 + (size_t)(lane & 31) * 128 + kch * 8;
        const int vch = (i & 1) * 2 + (w >> 1);
        const int vd  = ((w & 1) << 6) | lane;
        vp[i] = ((i >> 1) ? vim : vre) + (size_t)vd * S_ + vch * 8;
    }

    auto issue_tile = [&](int kt, int buf) {
#pragma unroll
        for (int i = 0; i < 4; ++i)
            async_copy16(kp[i] + (size_t)kt * 4096, &sbuf[buf][w * 512 + i * 2048]);
#pragma unroll
        for (int i = 0; i < 4; ++i)
            async_copy16(vp[i] + (size_t)kt * 32, &sbuf[buf][8192 + w * 512 + i * 2048]);
    };

    const int nk = (q0 + 64) >> 5;                    // kv tiles of 32, nk >= 2

    issue_tile(0, 0);
    issue_tile(1, 1);

    for (int k = 0; k < nk; ++k) {
        if (k == nk - 1) { asm volatile("s_waitcnt vmcnt(0)" ::: "memory"); }
        else             { asm volatile("s_waitcnt vmcnt(8)" ::: "memory"); }
        asm volatile("s_barrier" ::: "memory");
        const uint16_t* sb = sbuf[k & 1];
        const int c0 = k << 5;

        if (c0 <= qw0 + 15) {
            f32x4 sc[2] = {};
#pragma unroll
            for (int cblk = 0; cblk < 2; ++cblk) {
                const int krow = cblk * 16 + r16;
#pragma unroll
                for (int ks = 0; ks < 4; ++ks) {
                    const int koff = (ks * 4 + q4) * 256 + krow * 8;
                    bf16x8 kr = *(const bf16x8*)&sb[koff];
                    bf16x8 ki = *(const bf16x8*)&sb[4096 + koff];
                    sc[cblk] = __builtin_amdgcn_mfma_f32_16x16x32_bf16(qfr[ks], kr, sc[cblk], 0, 0, 0);
                    sc[cblk] = __builtin_amdgcn_mfma_f32_16x16x32_bf16(qfi[ks], ki, sc[cblk], 0, 0, 0);
                }
            }
#pragma unroll
            for (int cblk = 0; cblk < 2; ++cblk)
#pragma unroll
                for (int reg = 0; reg < 4; ++reg) {
                    float sval = sc[cblk][reg] * 0.08838834764831845f;
                    const int rowg = qw0 + q4 * 4 + reg;
                    const int colg = c0 + cblk * 16 + r16;
                    if (colg > rowg) sval = -3e38f;
                    sc[cblk][reg] = sval;
                }
            float al[4];
#pragma unroll
            for (int reg = 0; reg < 4; ++reg) {
                float mx = fmaxf(sc[0][reg], sc[1][reg]);
#pragma unroll
                for (int msk = 1; msk < 16; msk <<= 1) mx = fmaxf(mx, __shfl_xor(mx, msk));
                const float mn = fmaxf(m_r[reg], mx);
                al[reg] = __expf(m_r[reg] - mn);
                const float p0 = __expf(sc[0][reg] - mn);
                const float p1 = __expf(sc[1][reg] - mn);
                sc[0][reg] = p0; sc[1][reg] = p1;
                float rs = p0 + p1;
#pragma unroll
                for (int msk = 1; msk < 16; msk <<= 1) rs += __shfl_xor(rs, msk);
                l_r[reg] = l_r[reg] * al[reg] + rs;
                m_r[reg] = mn;
            }
#pragma unroll
            for (int cblk = 0; cblk < 2; ++cblk)
#pragma unroll
                for (int reg = 0; reg < 4; ++reg)
                    sp[w][q4 * 4 + reg][cblk * 16 + r16] = f2bf(sc[cblk][reg]);
#pragma unroll
            for (int dblk = 0; dblk < 8; ++dblk)
#pragma unroll
                for (int reg = 0; reg < 4; ++reg) {
                    oa[0][dblk][reg] *= al[reg];
                    oa[1][dblk][reg] *= al[reg];
                }
            bf16x8 pf = *(const bf16x8*)&sp[w][r16][q4 * 8];
#pragma unroll
            for (int dblk = 0; dblk < 8; ++dblk) {
                const int voff = 8192 + q4 * 1024 + (dblk * 16 + r16) * 8;
                bf16x8 vr = *(const bf16x8*)&sb[voff];
                bf16x8 vi = *(const bf16x8*)&sb[4096 + voff];
                oa[0][dblk] = __builtin_amdgcn_mfma_f32_16x16x32_bf16(pf, vr, oa[0][dblk], 0, 0, 0);
                oa[1][dblk] = __builtin_amdgcn_mfma_f32_16x16x32_bf16(pf, vi, oa[1][dblk], 0, 0, 0);
            }
        }

        asm volatile("s_barrier" ::: "memory");       // all reads of buf done
        if (k + 2 < nk) issue_tile(k + 2, k & 1);
    }

    float inv[4];
#pragma unroll
    for (int reg = 0; reg < 4; ++reg) inv[reg] = 1.f / l_r[reg];
#pragma unroll
    for (int dblk = 0; dblk < 8; ++dblk) {
        const int col = h * 128 + dblk * 16 + r16;
#pragma unroll
        for (int reg = 0; reg < 4; ++reg) {
            const size_t tok = (size_t)b * S_ + qw0 + q4 * 4 + reg;
            ob_re[tok * 2048 + col] = f2bf(oa[0][dblk][reg] * inv[reg]);
            ob_im[tok * 2048 + col] = f2bf(oa[1][dblk][reg] * inv[reg]);
        }
    }
}

// ---------------------------------------------------------------------------
extern "C" void kernel_launch(void* const* d_in, const int* in_sizes, int n_in,
                              void* d_out, int out_size, void* d_ws, size_t ws_size,
                              hipStream_t stream)
{
    const float* hr    = (const float*)d_in[0];
    const float* hi    = (const float*)d_in[1];
    const float* wq_re = (const float*)d_in[2];
    const float* wq_im = (const float*)d_in[3];
    const float* wk_re = (const float*)d_in[4];
    const float* wk_im = (const float*)d_in[5];
    const float* wv_re = (const float*)d_in[6];
    const float* wv_im = (const float*)d_in[7];
    const float* wo_re = (const float*)d_in[8];
    const float* wo_im = (const float*)d_in[9];
    float* out = (float*)d_out;
    char*  base = (char*)d_ws;

    const size_t MB4  = (size_t)2048 * 2048;
    const size_t QKVP = (size_t)3072 * 2048;
    const size_t KVE  = (size_t)B_ * KV_ * S_ * 128;

    float*   mags   = (float*)(base);
    float*   invs1  = (float*)(base + 1024);
    float*   invs2  = (float*)(base + 9216);
    int8_t*  xr_q   = (int8_t*)(base + 32768);
    int8_t*  xi_q   = xr_q + MB4;
    int8_t*  qkv_sr = xi_q + MB4;
    int8_t*  qkv_si = qkv_sr + QKVP;
    int8_t*  qkv_ns = qkv_si + QKVP;     // (unused — bnsi plane dropped)
    int8_t*  wo_sr  = qkv_ns + QKVP;
    int8_t*  wo_si  = wo_sr + MB4;
    int8_t*  wo_ns  = wo_si + MB4;       // (unused)
    float*   q_re   = (float*)(wo_ns + MB4);
    float*   q_im   = q_re + MB4;
    uint16_t* kb_re = (uint16_t*)(q_im + MB4);
    uint16_t* kb_im = kb_re + KVE;
    uint16_t* vb_re = kb_im + KVE;
    uint16_t* vb_im = vb_re + KVE;
    uint16_t* vt_re = (uint16_t*)xr_q;
    uint16_t* vt_im = (uint16_t*)xi_q;
    // qb lives in the (now unused for f32 Q) q_re/q_im regions.
    uint16_t* qb_re = (uint16_t*)q_re;
    uint16_t* qb_im = (uint16_t*)q_im;
    // attn bf16 output lives in the dead QKV weight region.
    uint16_t* ob_re = (uint16_t*)qkv_sr;
    uint16_t* ob_im = (uint16_t*)(qkv_sr + 8388608);

    hipMemsetAsync(mags, 0, 16, stream);

    decode_kernel<<<dim3(32, 32), 256, 0, stream>>>(wq_re, wq_im, 2048, qkv_sr, qkv_si, 0,    mags + 0);
    decode_kernel<<<dim3(8, 32),  256, 0, stream>>>(wk_re, wk_im, 512,  qkv_sr, qkv_si, 2048, mags + 1);
    decode_kernel<<<dim3(8, 32),  256, 0, stream>>>(wv_re, wv_im, 512,  qkv_sr, qkv_si, 2560, mags + 2);
    decode_kernel<<<dim3(32, 32), 256, 0, stream>>>(wo_re, wo_im, 2048, wo_sr, wo_si, 0,      mags + 3);

    act_quant_i8_kernel<<<NTOK, 256, 0, stream>>>(hr, hi, xr_q, xi_q, invs1);

    gemm_i8_kernel<0><<<dim3(24, 32), 256, 0, stream>>>(
        xr_q, xi_q, qkv_sr, qkv_si, 0, invs1, mags,
        1.0f / (float)((size_t)D_ * QD), 1.0f / (float)((size_t)D_ * KD), 1.0f / (float)((size_t)D_ * KD),
        nullptr, nullptr, qb_re, qb_im, kb_re, kb_im, vb_re, vb_im);

    vtrans_kernel<<<dim3(S_ / 32, 128 / 32, B_ * KV_ * 2), 256, 0, stream>>>(vb_re, vb_im, vt_re, vt_im);

    attn_mfma_kernel<<<dim3(S_ / 64, H_, B_), 256, 0, stream>>>(
        qb_re, qb_im, kb_re, kb_im, vt_re, vt_im, ob_re, ob_im);

    act_quant_bf16_kernel<<<NTOK, 256, 0, stream>>>(ob_re, ob_im, xr_q, xi_q, invs2);

    gemm_i8_kernel<1><<<dim3(16, 32), 256, 0, stream>>>(
        xr_q, xi_q, wo_sr, wo_si, 2048, invs2, mags + 3,
        1.0f / (float)((size_t)QD * D_), 0.f, 0.f,
        out, out + MB4, nullptr, nullptr, nullptr, nullptr, nullptr, nullptr);
}